// Round 6
// baseline (242.793 us; speedup 1.0000x reference)
//
#include <hip/hip_runtime.h>

#define BB 2
#define CC 256
#define CQ 64
#define DD 32
#define HH 64
#define WW 192
#define HW (HH*WW)     // 12288
#define NPIX (BB*HW)   // 24576

typedef __attribute__((ext_vector_type(8))) short bf16x8;
typedef __attribute__((ext_vector_type(4))) float f32x4;

__device__ __forceinline__ float b2f(ushort s){ return __uint_as_float(((uint)s)<<16); }
__device__ __forceinline__ ushort f2b(float f){
    uint u = __float_as_uint(f);
    return (ushort)((u + 0x7fffu + ((u>>16)&1u)) >> 16);
}
__device__ __forceinline__ float eluf(float v){ return v > 0.f ? v : (__expf(v)-1.f); }

// ---------- prep: f32 NCHW -> bf16 pixel-major [B*HW][256] ----------
__global__ __launch_bounds__(256) void k_prep_feat(
    const float* __restrict__ t_feat, const float* __restrict__ s_feat,
    ushort* __restrict__ Tt, ushort* __restrict__ Ts)
{
    int n = blockIdx.x*256 + threadIdx.x;   // B*HW*32
    int p  = n % HW;
    int r  = n / HW;
    int c8 = r % 32;
    int b  = r / 32;
    const float* tp = t_feat + ((size_t)(b*CC + c8*8))*HW + p;
    const float* sp = s_feat + ((size_t)(b*CC + c8*8))*HW + p;
    uint tu[4], su[4];
    #pragma unroll
    for (int j2=0;j2<4;++j2){
        tu[j2] = (uint)f2b(tp[(size_t)(2*j2)*HW])   | ((uint)f2b(tp[(size_t)(2*j2+1)*HW])<<16);
        su[j2] = (uint)f2b(sp[(size_t)(2*j2)*HW])   | ((uint)f2b(sp[(size_t)(2*j2+1)*HW])<<16);
    }
    size_t dst = ((size_t)(b*HW + p))*CC + c8*8;
    uint4 t4; t4.x=tu[0]; t4.y=tu[1]; t4.z=tu[2]; t4.w=tu[3];
    uint4 s4; s4.x=su[0]; s4.y=su[1]; s4.z=su[2]; s4.w=su[3];
    *(uint4*)(Tt + dst) = t4;
    *(uint4*)(Ts + dst) = s4;
}

// ---------- prep: weights -> bf16 GEMM-A layouts ----------
__global__ __launch_bounds__(256) void k_prep_w(
    const float* __restrict__ qw, const float* __restrict__ qb,
    const float* __restrict__ kw, const float* __restrict__ kb,
    const float* __restrict__ vw, const float* __restrict__ vb,
    const float* __restrict__ p1w, const float* __restrict__ p2w,
    const float* __restrict__ rw,
    ushort* __restrict__ Wqkv, float* __restrict__ bqkv,
    ushort* __restrict__ A1, ushort* __restrict__ A2, ushort* __restrict__ Ar)
{
    int id = blockIdx.x*256 + threadIdx.x;
    if (id < 49152) {                      // Wqkv [192][256]
        int o = id / 256, c = id % 256;
        float v = (o<64)? qw[o*256+c] : (o<128)? kw[(o-64)*256+c] : vw[(o-128)*256+c];
        Wqkv[id] = f2b(v);
    } else if (id < 49344) {               // bqkv [192]
        int o = id - 49152;
        bqkv[o] = (o<64)? qb[o] : (o<128)? kb[o-64] : vb[o-128];
    } else if (id < 49344+73728) {         // A1 [64][9*128], k = t*128+ci
        int i = id - 49344;
        int o = i/1152, r = i%1152, t = r/128, ci = r%128;
        A1[i] = f2b(p1w[(size_t)(o*128+ci)*9 + t]);
    } else if (id < 49344+73728+18432) {   // A2 [32][9*64]
        int i = id - (49344+73728);
        int o = i/576, r = i%576, t = r/64, ci = r%64;
        A2[i] = f2b(p2w[(size_t)(o*64+ci)*9 + t]);
    } else if (id < 49344+73728+18432+73728) {  // Ar [256][288]
        int i = id - (49344+73728+18432);
        Ar[i] = f2b(rw[i]);
    }
}

// ---------- G1: qkv conv1x1 as MFMA GEMM ----------
__global__ __launch_bounds__(256) void g_qkv(
    const ushort* __restrict__ Tt, const ushort* __restrict__ Ts,
    const ushort* __restrict__ Wqkv, const float* __restrict__ bqkv,
    ushort* __restrict__ X1, ushort* __restrict__ Vb)
{
    int wv = threadIdx.x >> 6;
    int lane = threadIdx.x & 63;
    int lm = lane & 15, lk = lane >> 4;
    int g  = blockIdx.x / 384;
    int n0 = (blockIdx.x % 384) * 64;
    const ushort* Bsrc = (g==0) ? Tt : Ts;
    const ushort* Ap = Wqkv + (size_t)(g*64 + wv*16 + lm)*CC + lk*8;
    const ushort* Bp = Bsrc + (size_t)n0*CC + lk*8;
    f32x4 acc[4];
    #pragma unroll
    for (int i=0;i<4;++i) acc[i] = (f32x4){0.f,0.f,0.f,0.f};
    for (int k0=0; k0<CC; k0+=32){
        bf16x8 a = *(const bf16x8*)(Ap + k0);
        #pragma unroll
        for (int nt=0; nt<4; ++nt){
            bf16x8 bb = *(const bf16x8*)(Bp + (size_t)(nt*16+lm)*CC + k0);
            acc[nt] = __builtin_amdgcn_mfma_f32_16x16x32_bf16(a, bb, acc[nt], 0,0,0);
        }
    }
    int ob = g*64 + wv*16 + lk*4;   // bias index base
    int ol = wv*16 + lk*4;          // channel within 64
    #pragma unroll
    for (int nt=0; nt<4; ++nt){
        int p = n0 + nt*16 + lm;
        uint u0 = (uint)f2b(acc[nt][0]+bqkv[ob])   | ((uint)f2b(acc[nt][1]+bqkv[ob+1])<<16);
        uint u1 = (uint)f2b(acc[nt][2]+bqkv[ob+2]) | ((uint)f2b(acc[nt][3]+bqkv[ob+3])<<16);
        ushort* dst;
        if (g==0)      dst = X1 + (size_t)p*128 + ol;        // q half
        else if (g==1) dst = X1 + (size_t)p*128 + 64 + ol;   // K half (persistent)
        else           dst = Vb + (size_t)p*64 + ol;
        *(uint2*)dst = make_uint2(u0, u1);
    }
}

// ---------- k_ca: cost + softmax + aggV ----------
// No LDS. 8 threads/pixel (oct = 8 channels each); K/V read straight from
// L1/L2 (X1+Vb = 9.4 MB, L2-resident); softmax via 3-step shfl_xor butterfly.
__global__ __launch_bounds__(256, 5) void k_ca(
    const ushort* __restrict__ X1, const ushort* __restrict__ Vb,
    const float* __restrict__ directs, const int* __restrict__ img_w_p,
    float* __restrict__ C1, ushort* __restrict__ Agg)
{
    int gid = blockIdx.x*256 + threadIdx.x;   // 196608 total
    int n   = gid >> 3;                       // pixel
    int oct = gid & 7;                        // channel oct
    int b   = n / HW;
    int pl  = n % HW;
    int h   = pl / WW;
    int w   = pl % WW;
    size_t rowbase = (size_t)b*HW + (size_t)h*WW;

    int imw = img_w_p[0];
    float rel = (imw != 640) ? (640.0f/(float)imw) : 1.0f;
    float sf = 0.01f * rel * directs[b] * 191.0f;
    float wf = (float)w;

    // Q chunk (8 channels)
    float qf[8];
    {
        bf16x8 qv = *(const bf16x8*)(X1 + (size_t)n*128 + oct*8);
        #pragma unroll
        for (int j=0;j<8;++j) qf[j] = b2f((ushort)qv[j]);
    }

    // ---- phase A: partial cost over my 8 channels, all 32 d ----
    float cost[DD];
    #pragma unroll
    for (int d=0; d<DD; ++d){
        float srcx = fminf(fmaxf(wf + (float)d*sf, 0.f), 191.0f);
        int x0 = (int)floorf(srcx);
        int x1 = min(x0+1, 191);
        float fr = srcx - (float)x0;
        bf16x8 k0v = *(const bf16x8*)(X1 + (rowbase + x0)*128 + 64 + oct*8);
        bf16x8 k1v = *(const bf16x8*)(X1 + (rowbase + x1)*128 + 64 + oct*8);
        float s0 = 0.f, s1 = 0.f;
        #pragma unroll
        for (int j=0;j<8;++j){
            s0 += qf[j]*b2f((ushort)k0v[j]);
            s1 += qf[j]*b2f((ushort)k1v[j]);
        }
        cost[d] = s0 + fr*(s1-s0);
    }
    // butterfly over the 8 lanes of this pixel
    #pragma unroll
    for (int d=0; d<DD; ++d){
        float v = cost[d];
        v += __shfl_xor(v, 1);
        v += __shfl_xor(v, 2);
        v += __shfl_xor(v, 4);
        cost[d] = v * 0.125f;
    }
    // raw cost write: lane oct writes d = oct*4 .. +4 (16B, coalesced)
    {
        f32x4 t4;
        #pragma unroll
        for (int j=0;j<4;++j) t4[j] = cost[oct*4+j];
        *(f32x4*)(C1 + (size_t)n*DD + oct*4) = t4;
    }
    // softmax (thread-local, all lanes have full vector)
    float m = cost[0];
    #pragma unroll
    for (int d=1; d<DD; ++d) m = fmaxf(m, cost[d]);
    float s = 0.f;
    #pragma unroll
    for (int d=0; d<DD; ++d){ cost[d] = __expf(cost[d]-m); s += cost[d]; }
    float inv = 1.f/s;

    // ---- phase C: agg over my 8 channels ----
    float agg[8];
    #pragma unroll
    for (int j=0;j<8;++j) agg[j]=0.f;
    #pragma unroll
    for (int d=0; d<DD; ++d){
        float pd = cost[d]*inv;
        float srcx = fminf(fmaxf(wf + (float)d*sf, 0.f), 191.0f);
        int x0 = (int)floorf(srcx);
        int x1 = min(x0+1, 191);
        float fr = srcx - (float)x0;
        float a1 = pd*fr, a0 = pd - a1;
        bf16x8 v0v = *(const bf16x8*)(Vb + (rowbase + x0)*64 + oct*8);
        bf16x8 v1v = *(const bf16x8*)(Vb + (rowbase + x1)*64 + oct*8);
        #pragma unroll
        for (int j=0;j<8;++j)
            agg[j] += a0*b2f((ushort)v0v[j]) + a1*b2f((ushort)v1v[j]);
    }
    {
        uint u[4];
        #pragma unroll
        for (int j2=0;j2<4;++j2)
            u[j2] = (uint)f2b(agg[j2*2]) | ((uint)f2b(agg[j2*2+1])<<16);
        uint4 q4; q4.x=u[0]; q4.y=u[1]; q4.z=u[2]; q4.w=u[3];
        *(uint4*)(Agg + (size_t)n*64 + oct*8) = q4;
    }
}

// ---------- G2: conv3x3 p1 as LDS-staged implicit GEMM, ELU ----------
// 768 blocks x 256 thr; stage 3 rows x 34 px x 128 ch chunk-major; wave = 32m x 16n
__global__ __launch_bounds__(256) void g_conv1(
    const ushort* __restrict__ X1, const ushort* __restrict__ Agg,
    const ushort* __restrict__ A1, const float* __restrict__ p1b,
    ushort* __restrict__ X2)
{
    __shared__ ushort sB[3*16*34*8];   // 26.1 KiB  [(dh*16+c16)*34 + x]*8
    int tid = threadIdx.x;
    int wv = tid >> 6, lane = tid & 63;
    int lm = lane & 15, lk = lane >> 4;
    int n0 = blockIdx.x * 32;
    int b  = n0 / HW;
    int pl = n0 % HW;
    int h  = pl / WW, w0 = pl % WW;

    for (int i = tid; i < 1632; i += 256){
        int dh = i / 544, rem2 = i % 544;
        int c16 = rem2 / 34, x = rem2 % 34;
        int hh = h + dh - 1, wx = w0 + x - 1;
        uint4 val = make_uint4(0,0,0,0);
        if (hh >= 0 && hh < HH && wx >= 0 && wx < WW){
            size_t pix = (size_t)b*HW + (size_t)hh*WW + wx;
            val = (c16 < 8) ? *(const uint4*)(X1 + pix*128 + c16*8)
                            : *(const uint4*)(Agg + pix*64 + (c16-8)*8);
        }
        *(uint4*)&sB[((dh*16 + c16)*34 + x)*8] = val;
    }
    __syncthreads();

    int mw = wv & 1, nw = wv >> 1;
    const ushort* Ap = A1 + (size_t)(mw*32 + lm)*1152 + lk*8;
    f32x4 acc0 = {0.f,0.f,0.f,0.f}, acc1 = {0.f,0.f,0.f,0.f};
    int xb = nw*16 + lm;
    #pragma unroll
    for (int t=0; t<9; ++t){
        int dh = t/3, dw = t%3;
        #pragma unroll
        for (int c0=0; c0<128; c0+=32){
            bf16x8 bb = *(const bf16x8*)&sB[((dh*16 + (c0>>3)+lk)*34 + xb + dw)*8];
            bf16x8 a0 = *(const bf16x8*)(Ap + t*128 + c0);
            bf16x8 a1 = *(const bf16x8*)(Ap + (size_t)16*1152 + t*128 + c0);
            acc0 = __builtin_amdgcn_mfma_f32_16x16x32_bf16(a0, bb, acc0, 0,0,0);
            acc1 = __builtin_amdgcn_mfma_f32_16x16x32_bf16(a1, bb, acc1, 0,0,0);
        }
    }
    int pg = n0 + nw*16 + lm;
    int o0 = mw*32 + lk*4;
    {
        uint u0 = (uint)f2b(eluf(acc0[0]+p1b[o0]))   | ((uint)f2b(eluf(acc0[1]+p1b[o0+1]))<<16);
        uint u1 = (uint)f2b(eluf(acc0[2]+p1b[o0+2])) | ((uint)f2b(eluf(acc0[3]+p1b[o0+3]))<<16);
        *(uint2*)(X2 + (size_t)pg*64 + o0) = make_uint2(u0, u1);
        int o1 = o0 + 16;
        uint u2 = (uint)f2b(eluf(acc1[0]+p1b[o1]))   | ((uint)f2b(eluf(acc1[1]+p1b[o1+1]))<<16);
        uint u3 = (uint)f2b(eluf(acc1[2]+p1b[o1+2])) | ((uint)f2b(eluf(acc1[3]+p1b[o1+3]))<<16);
        *(uint2*)(X2 + (size_t)pg*64 + o1) = make_uint2(u2, u3);
    }
}

// ---------- G3: conv3x3 p2 + residual avg -> cost_out (LDS-staged) ----------
__global__ __launch_bounds__(256) void g_conv2(
    const ushort* __restrict__ X2, const ushort* __restrict__ A2,
    const float* __restrict__ p2b, const float* __restrict__ C1,
    float* __restrict__ cost_out)
{
    __shared__ ushort sB[3*8*34*8];   // 13 KiB
    int tid = threadIdx.x;
    int wv = tid >> 6, lane = tid & 63;
    int lm = lane & 15, lk = lane >> 4;
    int n0 = blockIdx.x * 32;
    int b  = n0 / HW;
    int pl = n0 % HW;
    int h  = pl / WW, w0 = pl % WW;

    for (int i = tid; i < 816; i += 256){
        int dh = i / 272, rem2 = i % 272;
        int c16 = rem2 / 34, x = rem2 % 34;
        int hh = h + dh - 1, wx = w0 + x - 1;
        uint4 val = make_uint4(0,0,0,0);
        if (hh >= 0 && hh < HH && wx >= 0 && wx < WW)
            val = *(const uint4*)(X2 + ((size_t)b*HW + (size_t)hh*WW + wx)*64 + c16*8);
        *(uint4*)&sB[((dh*8 + c16)*34 + x)*8] = val;
    }
    __syncthreads();

    int mw = wv & 1, nw = wv >> 1;
    const ushort* Ap = A2 + (size_t)(mw*16 + lm)*576 + lk*8;
    f32x4 acc = {0.f,0.f,0.f,0.f};
    int xb = nw*16 + lm;
    #pragma unroll
    for (int t=0; t<9; ++t){
        int dh = t/3, dw = t%3;
        #pragma unroll
        for (int c0=0; c0<64; c0+=32){
            bf16x8 bb = *(const bf16x8*)&sB[((dh*8 + (c0>>3)+lk)*34 + xb + dw)*8];
            bf16x8 a  = *(const bf16x8*)(Ap + t*64 + c0);
            acc = __builtin_amdgcn_mfma_f32_16x16x32_bf16(a, bb, acc, 0,0,0);
        }
    }
    int pg = n0 + nw*16 + lm;
    int pll = pg % HW;
    int o = mw*16 + lk*4;
    f32x4 cv = *(const f32x4*)(C1 + (size_t)pg*DD + o);
    #pragma unroll
    for (int j=0;j<4;++j)
        cost_out[((size_t)(b*DD + o + j))*HW + pll] = (cv[j] + acc[j] + p2b[o+j]) * 0.5f;
}

// ---------- softmax over D -> NC (bf16 pixel-major) ----------
__global__ __launch_bounds__(256) void k_sm2(
    const float* __restrict__ cost_out, ushort* __restrict__ NC)
{
    int n = blockIdx.x*256 + threadIdx.x;   // 24576
    int b = n / HW, pl = n % HW;
    const float* cp = cost_out + (size_t)b*DD*HW + pl;
    float v[DD]; float m = -1e30f;
    #pragma unroll
    for (int d=0; d<DD; ++d){ v[d] = cp[(size_t)d*HW]; m = fmaxf(m, v[d]); }
    float s = 0.f;
    #pragma unroll
    for (int d=0; d<DD; ++d){ v[d] = __expf(v[d]-m); s += v[d]; }
    float inv = 1.f/s;
    ushort* op = NC + (size_t)n*DD;
    #pragma unroll
    for (int d8=0; d8<4; ++d8){
        uint u[4];
        #pragma unroll
        for (int j2=0;j2<4;++j2)
            u[j2] = (uint)f2b(v[d8*8+j2*2]*inv) | ((uint)f2b(v[d8*8+j2*2+1]*inv)<<16);
        uint4 q4; q4.x=u[0]; q4.y=u[1]; q4.z=u[2]; q4.w=u[3];
        *(uint4*)(op + d8*8) = q4;
    }
}

// ---------- G4: final conv1x1 on concat(t_feat, nc2), ELU ----------
__global__ __launch_bounds__(256) void g_final(
    const ushort* __restrict__ Tt, const ushort* __restrict__ NC,
    const ushort* __restrict__ Ar, const float* __restrict__ rb,
    float* __restrict__ xout)
{
    int wv = threadIdx.x >> 6;
    int lane = threadIdx.x & 63;
    int lm = lane & 15, lk = lane >> 4;
    int mg = blockIdx.x / 384;
    int n0 = (blockIdx.x % 384) * 64;
    const ushort* Ap = Ar + (size_t)(mg*64 + wv*16 + lm)*288 + lk*8;
    f32x4 acc[4];
    #pragma unroll
    for (int i=0;i<4;++i) acc[i] = (f32x4){0.f,0.f,0.f,0.f};
    for (int k0=0; k0<288; k0+=32){
        bf16x8 a = *(const bf16x8*)(Ap + k0);
        #pragma unroll
        for (int nt=0; nt<4; ++nt){
            int p = n0 + nt*16 + lm;
            const ushort* src = (k0 < 256) ? (Tt + (size_t)p*CC + k0 + lk*8)
                                           : (NC + (size_t)p*DD + lk*8);
            bf16x8 bb = *(const bf16x8*)src;
            acc[nt] = __builtin_amdgcn_mfma_f32_16x16x32_bf16(a, bb, acc[nt], 0,0,0);
        }
    }
    int o = mg*64 + wv*16 + lk*4;
    #pragma unroll
    for (int nt=0; nt<4; ++nt){
        int p = n0 + nt*16 + lm;
        int b = p / HW, pl = p % HW;
        #pragma unroll
        for (int j=0;j<4;++j)
            xout[((size_t)(b*CC + o + j))*HW + pl] = eluf(acc[nt][j] + rb[o+j]);
    }
}

extern "C" void kernel_launch(void* const* d_in, const int* in_sizes, int n_in,
                              void* d_out, int out_size, void* d_ws, size_t ws_size,
                              hipStream_t stream)
{
    const float* t_feat = (const float*)d_in[0];
    const float* s_feat = (const float*)d_in[1];
    const float* directs= (const float*)d_in[2];
    const float* qw = (const float*)d_in[3];
    const float* qb = (const float*)d_in[4];
    const float* kw = (const float*)d_in[5];
    const float* kb = (const float*)d_in[6];
    const float* vw = (const float*)d_in[7];
    const float* vb = (const float*)d_in[8];
    const float* p1w= (const float*)d_in[9];
    const float* p1b= (const float*)d_in[10];
    const float* p2w= (const float*)d_in[11];
    const float* p2b= (const float*)d_in[12];
    const float* rw = (const float*)d_in[13];
    const float* rb = (const float*)d_in[14];
    const int* img_w= (const int*)d_in[15];

    // workspace layout (byte offsets, lifetime-aliased)
    char* wsb = (char*)d_ws;
    ushort* Tt   = (ushort*)(wsb + 0);           // 12,582,912 B  [NPIX][256] bf16
    char*  tsreg = wsb + 12582912;               // 12,582,912 B region
    ushort* Ts   = (ushort*)tsreg;               //   Ts (dead after g_qkv)
    ushort* X2   = (ushort*)tsreg;               //   X2 [NPIX][64] bf16 (3,145,728) aliases Ts
    float*  C1   = (float*)(tsreg + 3145728);    //   C1 [NPIX][32] f32 (3,145,728)
    ushort* Agg  = (ushort*)(tsreg + 6291456);   //   Agg [NPIX][64] bf16 (3,145,728)
    ushort* X1   = (ushort*)(wsb + 25165824);    // 6,291,456 B [NPIX][128] bf16 (q | K)
    ushort* Vb   = (ushort*)(wsb + 31457280);    // 3,145,728 B [NPIX][64] bf16
    ushort* NC   = (ushort*)(wsb + 31457280);    // aliases Vb after k_ca
    ushort* Wqkv = (ushort*)(wsb + 34603008);    // 98,304 B
    float*  bqkv = (float*) (wsb + 34701312);    // 768 B (pad to 1024)
    ushort* A1   = (ushort*)(wsb + 34702336);    // 147,456 B
    ushort* A2   = (ushort*)(wsb + 34849792);    // 36,864 B
    ushort* Ar   = (ushort*)(wsb + 34886656);    // 147,456 B -> end 35,034,112
    if (ws_size < 35034112) return;

    float* xout     = (float*)d_out;                 // [B,256,H,W] f32
    float* cost_out = xout + (size_t)BB*CC*HW;       // [B,32,H,W] f32

    k_prep_feat<<<3072, 256, 0, stream>>>(t_feat, s_feat, Tt, Ts);
    k_prep_w  <<<841,  256, 0, stream>>>(qw,qb,kw,kb,vw,vb,p1w,p2w,rw, Wqkv,bqkv,A1,A2,Ar);
    g_qkv     <<<1152, 256, 0, stream>>>(Tt, Ts, Wqkv, bqkv, X1, Vb);
    k_ca      <<<768,  256, 0, stream>>>(X1, Vb, directs, img_w, C1, Agg);
    g_conv1   <<<768,  256, 0, stream>>>(X1, Agg, A1, p1b, X2);
    g_conv2   <<<768,  256, 0, stream>>>(X2, A2, p2b, C1, cost_out);
    k_sm2     <<<96,   256, 0, stream>>>(cost_out, NC);
    g_final   <<<1536, 256, 0, stream>>>(Tt, NC, Ar, rb, xout);
}

// Round 7
// 141.031 us; speedup vs baseline: 1.7216x; 1.7216x over previous
//
#include <hip/hip_runtime.h>

#define BB 2
#define CC 256
#define CQ 64
#define DD 32
#define HH 64
#define WW 192
#define HW (HH*WW)     // 12288
#define NPIX (BB*HW)   // 24576

typedef __attribute__((ext_vector_type(8))) short bf16x8;
typedef __attribute__((ext_vector_type(4))) float f32x4;

__device__ __forceinline__ float b2f(ushort s){ return __uint_as_float(((uint)s)<<16); }
__device__ __forceinline__ ushort f2b(float f){
    uint u = __float_as_uint(f);
    return (ushort)((u + 0x7fffu + ((u>>16)&1u)) >> 16);
}
__device__ __forceinline__ float eluf(float v){ return v > 0.f ? v : (__expf(v)-1.f); }

// ---------- prep: f32 NCHW -> bf16 pixel-major [B*HW][256] ----------
__global__ __launch_bounds__(256) void k_prep_feat(
    const float* __restrict__ t_feat, const float* __restrict__ s_feat,
    ushort* __restrict__ Tt, ushort* __restrict__ Ts)
{
    int n = blockIdx.x*256 + threadIdx.x;   // B*HW*32
    int p  = n % HW;
    int r  = n / HW;
    int c8 = r % 32;
    int b  = r / 32;
    const float* tp = t_feat + ((size_t)(b*CC + c8*8))*HW + p;
    const float* sp = s_feat + ((size_t)(b*CC + c8*8))*HW + p;
    uint tu[4], su[4];
    #pragma unroll
    for (int j2=0;j2<4;++j2){
        tu[j2] = (uint)f2b(tp[(size_t)(2*j2)*HW])   | ((uint)f2b(tp[(size_t)(2*j2+1)*HW])<<16);
        su[j2] = (uint)f2b(sp[(size_t)(2*j2)*HW])   | ((uint)f2b(sp[(size_t)(2*j2+1)*HW])<<16);
    }
    size_t dst = ((size_t)(b*HW + p))*CC + c8*8;
    uint4 t4; t4.x=tu[0]; t4.y=tu[1]; t4.z=tu[2]; t4.w=tu[3];
    uint4 s4; s4.x=su[0]; s4.y=su[1]; s4.z=su[2]; s4.w=su[3];
    *(uint4*)(Tt + dst) = t4;
    *(uint4*)(Ts + dst) = s4;
}

// ---------- prep: weights -> bf16 GEMM-A layouts ----------
__global__ __launch_bounds__(256) void k_prep_w(
    const float* __restrict__ qw, const float* __restrict__ qb,
    const float* __restrict__ kw, const float* __restrict__ kb,
    const float* __restrict__ vw, const float* __restrict__ vb,
    const float* __restrict__ p1w, const float* __restrict__ p2w,
    const float* __restrict__ rw,
    ushort* __restrict__ Wqkv, float* __restrict__ bqkv,
    ushort* __restrict__ A1, ushort* __restrict__ A2, ushort* __restrict__ Ar)
{
    int id = blockIdx.x*256 + threadIdx.x;
    if (id < 49152) {                      // Wqkv [192][256]
        int o = id / 256, c = id % 256;
        float v = (o<64)? qw[o*256+c] : (o<128)? kw[(o-64)*256+c] : vw[(o-128)*256+c];
        Wqkv[id] = f2b(v);
    } else if (id < 49344) {               // bqkv [192]
        int o = id - 49152;
        bqkv[o] = (o<64)? qb[o] : (o<128)? kb[o-64] : vb[o-128];
    } else if (id < 49344+73728) {         // A1 [64][9*128], k = t*128+ci
        int i = id - 49344;
        int o = i/1152, r = i%1152, t = r/128, ci = r%128;
        A1[i] = f2b(p1w[(size_t)(o*128+ci)*9 + t]);
    } else if (id < 49344+73728+18432) {   // A2 [32][9*64]
        int i = id - (49344+73728);
        int o = i/576, r = i%576, t = r/64, ci = r%64;
        A2[i] = f2b(p2w[(size_t)(o*64+ci)*9 + t]);
    } else if (id < 49344+73728+18432+73728) {  // Ar [256][288]
        int i = id - (49344+73728+18432);
        Ar[i] = f2b(rw[i]);
    }
}

// ---------- G1: qkv conv1x1 as MFMA GEMM ----------
__global__ __launch_bounds__(256) void g_qkv(
    const ushort* __restrict__ Tt, const ushort* __restrict__ Ts,
    const ushort* __restrict__ Wqkv, const float* __restrict__ bqkv,
    ushort* __restrict__ X1, ushort* __restrict__ Vb)
{
    int wv = threadIdx.x >> 6;
    int lane = threadIdx.x & 63;
    int lm = lane & 15, lk = lane >> 4;
    int g  = blockIdx.x / 384;
    int n0 = (blockIdx.x % 384) * 64;
    const ushort* Bsrc = (g==0) ? Tt : Ts;
    const ushort* Ap = Wqkv + (size_t)(g*64 + wv*16 + lm)*CC + lk*8;
    const ushort* Bp = Bsrc + (size_t)n0*CC + lk*8;
    f32x4 acc[4];
    #pragma unroll
    for (int i=0;i<4;++i) acc[i] = (f32x4){0.f,0.f,0.f,0.f};
    for (int k0=0; k0<CC; k0+=32){
        bf16x8 a = *(const bf16x8*)(Ap + k0);
        #pragma unroll
        for (int nt=0; nt<4; ++nt){
            bf16x8 bb = *(const bf16x8*)(Bp + (size_t)(nt*16+lm)*CC + k0);
            acc[nt] = __builtin_amdgcn_mfma_f32_16x16x32_bf16(a, bb, acc[nt], 0,0,0);
        }
    }
    int ob = g*64 + wv*16 + lk*4;   // bias index base
    int ol = wv*16 + lk*4;          // channel within 64
    #pragma unroll
    for (int nt=0; nt<4; ++nt){
        int p = n0 + nt*16 + lm;
        uint u0 = (uint)f2b(acc[nt][0]+bqkv[ob])   | ((uint)f2b(acc[nt][1]+bqkv[ob+1])<<16);
        uint u1 = (uint)f2b(acc[nt][2]+bqkv[ob+2]) | ((uint)f2b(acc[nt][3]+bqkv[ob+3])<<16);
        ushort* dst;
        if (g==0)      dst = X1 + (size_t)p*128 + ol;        // q half
        else if (g==1) dst = X1 + (size_t)p*128 + 64 + ol;   // K half (persistent)
        else           dst = Vb + (size_t)p*64 + ol;
        *(uint2*)dst = make_uint2(u0, u1);
    }
}

// ---------- k_ca: cost + softmax + aggV ----------
// 768 blocks = (b, h, sixth); 512 thr = 32 px x (8 oct x 2 dhalf).
// Full K/V row staged once per block, chunk-major [c8][SVS] (conflict-free);
// all reductions via shfl within the 16 lanes of a pixel; no phase barriers.
#define SVS 194   // padded x-stride in 16B chunks: c8 groups 8 banks apart
__global__ __launch_bounds__(512) void k_ca(
    const ushort* __restrict__ X1, const ushort* __restrict__ Vb,
    const float* __restrict__ directs, const int* __restrict__ img_w_p,
    float* __restrict__ C1, ushort* __restrict__ Agg)
{
    __shared__ ushort sK[8*SVS*8];   // 24.25 KiB
    __shared__ ushort sV[8*SVS*8];   // 24.25 KiB
    int tid = threadIdx.x;
    int blk = blockIdx.x;
    int b   = blk / 384;
    int rem = blk % 384;
    int h   = rem / 6;
    int sx  = rem % 6;
    int w0  = sx * 32;
    size_t rowbase = (size_t)b*HW + (size_t)h*WW;

    for (int i = tid; i < 1536; i += 512){   // full row: 192 px x 8 octs
        int c8 = i & 7, x = i >> 3;
        *(uint4*)&sK[(c8*SVS + x)*8] = *(const uint4*)(X1 + (rowbase+x)*128 + 64 + c8*8);
        *(uint4*)&sV[(c8*SVS + x)*8] = *(const uint4*)(Vb + (rowbase+x)*64 + c8*8);
    }
    __syncthreads();

    int px  = tid >> 4;        // 0..31
    int l16 = tid & 15;
    int oct = l16 >> 1;        // tid bits 1..3  -> shfl masks 2,4,8
    int dh  = l16 & 1;         // tid bit 0      -> shfl mask 1
    int w   = w0 + px;
    size_t n = rowbase + w;

    int imw = img_w_p[0];
    float rel = (imw != 640) ? (640.0f/(float)imw) : 1.0f;
    float sf = 0.01f * rel * directs[b] * 191.0f;
    float wf = (float)w;

    float qf[8];
    {
        bf16x8 qv = *(const bf16x8*)(X1 + n*128 + oct*8);
        #pragma unroll
        for (int j=0;j<8;++j) qf[j] = b2f((ushort)qv[j]);
    }

    // ---- phase A: partial cost (my 8 ch) for my 16 d's ----
    float cost[16]; int x0k[16]; float frk[16];
    #pragma unroll
    for (int k=0;k<16;++k){
        int d = dh*16 + k;
        float srcx = fminf(fmaxf(wf + (float)d*sf, 0.f), 191.0f);
        int x0 = (int)floorf(srcx);
        int x1 = min(x0+1, 191);
        float fr = srcx - (float)x0;
        x0k[k] = x0; frk[k] = fr;
        bf16x8 k0v = *(const bf16x8*)&sK[(oct*SVS + x0)*8];
        bf16x8 k1v = *(const bf16x8*)&sK[(oct*SVS + x1)*8];
        float s0 = 0.f, s1 = 0.f;
        #pragma unroll
        for (int j=0;j<8;++j){
            s0 += qf[j]*b2f((ushort)k0v[j]);
            s1 += qf[j]*b2f((ushort)k1v[j]);
        }
        cost[k] = s0 + fr*(s1-s0);
    }
    // complete over channels: butterfly across the 8 octs
    #pragma unroll
    for (int k=0;k<16;++k){
        float v = cost[k];
        v += __shfl_xor(v, 2);
        v += __shfl_xor(v, 4);
        v += __shfl_xor(v, 8);
        cost[k] = v * 0.125f;
    }
    // raw cost write: lanes with oct==0 write their contiguous 16-d range
    if (oct == 0){
        float* cp = C1 + n*DD + dh*16;
        #pragma unroll
        for (int q=0;q<4;++q){
            f32x4 t4; t4[0]=cost[q*4]; t4[1]=cost[q*4+1]; t4[2]=cost[q*4+2]; t4[3]=cost[q*4+3];
            *(f32x4*)(cp + q*4) = t4;
        }
    }
    // ---- softmax across 32 d (16 local + partner via shfl mask 1) ----
    float mm = cost[0];
    #pragma unroll
    for (int k=1;k<16;++k) mm = fmaxf(mm, cost[k]);
    mm = fmaxf(mm, __shfl_xor(mm, 1));
    float ss = 0.f;
    #pragma unroll
    for (int k=0;k<16;++k){ cost[k] = __expf(cost[k]-mm); ss += cost[k]; }
    ss += __shfl_xor(ss, 1);
    float inv = 1.f/ss;

    // ---- phase C: agg over my 16 d's for my 8 ch ----
    float agg[8];
    #pragma unroll
    for (int j=0;j<8;++j) agg[j]=0.f;
    #pragma unroll
    for (int k=0;k<16;++k){
        float pd = cost[k]*inv;
        int x0 = x0k[k];
        int x1 = min(x0+1, 191);
        float fr = frk[k];
        float a1 = pd*fr, a0 = pd - a1;
        bf16x8 v0v = *(const bf16x8*)&sV[(oct*SVS + x0)*8];
        bf16x8 v1v = *(const bf16x8*)&sV[(oct*SVS + x1)*8];
        #pragma unroll
        for (int j=0;j<8;++j)
            agg[j] += a0*b2f((ushort)v0v[j]) + a1*b2f((ushort)v1v[j]);
    }
    #pragma unroll
    for (int j=0;j<8;++j) agg[j] += __shfl_xor(agg[j], 1);
    if (dh == 0){
        uint u[4];
        #pragma unroll
        for (int j2=0;j2<4;++j2)
            u[j2] = (uint)f2b(agg[j2*2]) | ((uint)f2b(agg[j2*2+1])<<16);
        uint4 q4; q4.x=u[0]; q4.y=u[1]; q4.z=u[2]; q4.w=u[3];
        *(uint4*)(Agg + n*64 + oct*8) = q4;
    }
}

// ---------- G2: conv3x3 p1 as LDS-staged implicit GEMM, ELU ----------
__global__ __launch_bounds__(256) void g_conv1(
    const ushort* __restrict__ X1, const ushort* __restrict__ Agg,
    const ushort* __restrict__ A1, const float* __restrict__ p1b,
    ushort* __restrict__ X2)
{
    __shared__ ushort sB[3*16*34*8];   // 26.1 KiB
    int tid = threadIdx.x;
    int wv = tid >> 6, lane = tid & 63;
    int lm = lane & 15, lk = lane >> 4;
    int n0 = blockIdx.x * 32;
    int b  = n0 / HW;
    int pl = n0 % HW;
    int h  = pl / WW, w0 = pl % WW;

    for (int i = tid; i < 1632; i += 256){
        int dh = i / 544, rem2 = i % 544;
        int c16 = rem2 / 34, x = rem2 % 34;
        int hh = h + dh - 1, wx = w0 + x - 1;
        uint4 val = make_uint4(0,0,0,0);
        if (hh >= 0 && hh < HH && wx >= 0 && wx < WW){
            size_t pix = (size_t)b*HW + (size_t)hh*WW + wx;
            val = (c16 < 8) ? *(const uint4*)(X1 + pix*128 + c16*8)
                            : *(const uint4*)(Agg + pix*64 + (c16-8)*8);
        }
        *(uint4*)&sB[((dh*16 + c16)*34 + x)*8] = val;
    }
    __syncthreads();

    int mw = wv & 1, nw = wv >> 1;
    const ushort* Ap = A1 + (size_t)(mw*32 + lm)*1152 + lk*8;
    f32x4 acc0 = {0.f,0.f,0.f,0.f}, acc1 = {0.f,0.f,0.f,0.f};
    int xb = nw*16 + lm;
    #pragma unroll
    for (int t=0; t<9; ++t){
        int dh = t/3, dw = t%3;
        #pragma unroll
        for (int c0=0; c0<128; c0+=32){
            bf16x8 bb = *(const bf16x8*)&sB[((dh*16 + (c0>>3)+lk)*34 + xb + dw)*8];
            bf16x8 a0 = *(const bf16x8*)(Ap + t*128 + c0);
            bf16x8 a1 = *(const bf16x8*)(Ap + (size_t)16*1152 + t*128 + c0);
            acc0 = __builtin_amdgcn_mfma_f32_16x16x32_bf16(a0, bb, acc0, 0,0,0);
            acc1 = __builtin_amdgcn_mfma_f32_16x16x32_bf16(a1, bb, acc1, 0,0,0);
        }
    }
    int pg = n0 + nw*16 + lm;
    int o0 = mw*32 + lk*4;
    {
        uint u0 = (uint)f2b(eluf(acc0[0]+p1b[o0]))   | ((uint)f2b(eluf(acc0[1]+p1b[o0+1]))<<16);
        uint u1 = (uint)f2b(eluf(acc0[2]+p1b[o0+2])) | ((uint)f2b(eluf(acc0[3]+p1b[o0+3]))<<16);
        *(uint2*)(X2 + (size_t)pg*64 + o0) = make_uint2(u0, u1);
        int o1 = o0 + 16;
        uint u2 = (uint)f2b(eluf(acc1[0]+p1b[o1]))   | ((uint)f2b(eluf(acc1[1]+p1b[o1+1]))<<16);
        uint u3 = (uint)f2b(eluf(acc1[2]+p1b[o1+2])) | ((uint)f2b(eluf(acc1[3]+p1b[o1+3]))<<16);
        *(uint2*)(X2 + (size_t)pg*64 + o1) = make_uint2(u2, u3);
    }
}

// ---------- G3: conv3x3 p2 + residual avg -> cost_out (LDS-staged) ----------
__global__ __launch_bounds__(256) void g_conv2(
    const ushort* __restrict__ X2, const ushort* __restrict__ A2,
    const float* __restrict__ p2b, const float* __restrict__ C1,
    float* __restrict__ cost_out)
{
    __shared__ ushort sB[3*8*34*8];   // 13 KiB
    int tid = threadIdx.x;
    int wv = tid >> 6, lane = tid & 63;
    int lm = lane & 15, lk = lane >> 4;
    int n0 = blockIdx.x * 32;
    int b  = n0 / HW;
    int pl = n0 % HW;
    int h  = pl / WW, w0 = pl % WW;

    for (int i = tid; i < 816; i += 256){
        int dh = i / 272, rem2 = i % 272;
        int c16 = rem2 / 34, x = rem2 % 34;
        int hh = h + dh - 1, wx = w0 + x - 1;
        uint4 val = make_uint4(0,0,0,0);
        if (hh >= 0 && hh < HH && wx >= 0 && wx < WW)
            val = *(const uint4*)(X2 + ((size_t)b*HW + (size_t)hh*WW + wx)*64 + c16*8);
        *(uint4*)&sB[((dh*8 + c16)*34 + x)*8] = val;
    }
    __syncthreads();

    int mw = wv & 1, nw = wv >> 1;
    const ushort* Ap = A2 + (size_t)(mw*16 + lm)*576 + lk*8;
    f32x4 acc = {0.f,0.f,0.f,0.f};
    int xb = nw*16 + lm;
    #pragma unroll
    for (int t=0; t<9; ++t){
        int dh = t/3, dw = t%3;
        #pragma unroll
        for (int c0=0; c0<64; c0+=32){
            bf16x8 bb = *(const bf16x8*)&sB[((dh*8 + (c0>>3)+lk)*34 + xb + dw)*8];
            bf16x8 a  = *(const bf16x8*)(Ap + t*64 + c0);
            acc = __builtin_amdgcn_mfma_f32_16x16x32_bf16(a, bb, acc, 0,0,0);
        }
    }
    int pg = n0 + nw*16 + lm;
    int pll = pg % HW;
    int o = mw*16 + lk*4;
    f32x4 cv = *(const f32x4*)(C1 + (size_t)pg*DD + o);
    #pragma unroll
    for (int j=0;j<4;++j)
        cost_out[((size_t)(b*DD + o + j))*HW + pll] = (cv[j] + acc[j] + p2b[o+j]) * 0.5f;
}

// ---------- softmax over D -> NC (bf16 pixel-major) ----------
__global__ __launch_bounds__(256) void k_sm2(
    const float* __restrict__ cost_out, ushort* __restrict__ NC)
{
    int n = blockIdx.x*256 + threadIdx.x;   // 24576
    int b = n / HW, pl = n % HW;
    const float* cp = cost_out + (size_t)b*DD*HW + pl;
    float v[DD]; float m = -1e30f;
    #pragma unroll
    for (int d=0; d<DD; ++d){ v[d] = cp[(size_t)d*HW]; m = fmaxf(m, v[d]); }
    float s = 0.f;
    #pragma unroll
    for (int d=0; d<DD; ++d){ v[d] = __expf(v[d]-m); s += v[d]; }
    float inv = 1.f/s;
    ushort* op = NC + (size_t)n*DD;
    #pragma unroll
    for (int d8=0; d8<4; ++d8){
        uint u[4];
        #pragma unroll
        for (int j2=0;j2<4;++j2)
            u[j2] = (uint)f2b(v[d8*8+j2*2]*inv) | ((uint)f2b(v[d8*8+j2*2+1]*inv)<<16);
        uint4 q4; q4.x=u[0]; q4.y=u[1]; q4.z=u[2]; q4.w=u[3];
        *(uint4*)(op + d8*8) = q4;
    }
}

// ---------- G4: final conv1x1 on concat(t_feat, nc2), ELU ----------
__global__ __launch_bounds__(256) void g_final(
    const ushort* __restrict__ Tt, const ushort* __restrict__ NC,
    const ushort* __restrict__ Ar, const float* __restrict__ rb,
    float* __restrict__ xout)
{
    int wv = threadIdx.x >> 6;
    int lane = threadIdx.x & 63;
    int lm = lane & 15, lk = lane >> 4;
    int mg = blockIdx.x / 384;
    int n0 = (blockIdx.x % 384) * 64;
    const ushort* Ap = Ar + (size_t)(mg*64 + wv*16 + lm)*288 + lk*8;
    f32x4 acc[4];
    #pragma unroll
    for (int i=0;i<4;++i) acc[i] = (f32x4){0.f,0.f,0.f,0.f};
    for (int k0=0; k0<288; k0+=32){
        bf16x8 a = *(const bf16x8*)(Ap + k0);
        #pragma unroll
        for (int nt=0; nt<4; ++nt){
            int p = n0 + nt*16 + lm;
            const ushort* src = (k0 < 256) ? (Tt + (size_t)p*CC + k0 + lk*8)
                                           : (NC + (size_t)p*DD + lk*8);
            bf16x8 bb = *(const bf16x8*)src;
            acc[nt] = __builtin_amdgcn_mfma_f32_16x16x32_bf16(a, bb, acc[nt], 0,0,0);
        }
    }
    int o = mg*64 + wv*16 + lk*4;
    #pragma unroll
    for (int nt=0; nt<4; ++nt){
        int p = n0 + nt*16 + lm;
        int b = p / HW, pl = p % HW;
        #pragma unroll
        for (int j=0;j<4;++j)
            xout[((size_t)(b*CC + o + j))*HW + pl] = eluf(acc[nt][j] + rb[o+j]);
    }
}

extern "C" void kernel_launch(void* const* d_in, const int* in_sizes, int n_in,
                              void* d_out, int out_size, void* d_ws, size_t ws_size,
                              hipStream_t stream)
{
    const float* t_feat = (const float*)d_in[0];
    const float* s_feat = (const float*)d_in[1];
    const float* directs= (const float*)d_in[2];
    const float* qw = (const float*)d_in[3];
    const float* qb = (const float*)d_in[4];
    const float* kw = (const float*)d_in[5];
    const float* kb = (const float*)d_in[6];
    const float* vw = (const float*)d_in[7];
    const float* vb = (const float*)d_in[8];
    const float* p1w= (const float*)d_in[9];
    const float* p1b= (const float*)d_in[10];
    const float* p2w= (const float*)d_in[11];
    const float* p2b= (const float*)d_in[12];
    const float* rw = (const float*)d_in[13];
    const float* rb = (const float*)d_in[14];
    const int* img_w= (const int*)d_in[15];

    // workspace layout (byte offsets, lifetime-aliased)
    char* wsb = (char*)d_ws;
    ushort* Tt   = (ushort*)(wsb + 0);           // 12,582,912 B  [NPIX][256] bf16
    char*  tsreg = wsb + 12582912;               // 12,582,912 B region
    ushort* Ts   = (ushort*)tsreg;               //   Ts (dead after g_qkv)
    ushort* X2   = (ushort*)tsreg;               //   X2 [NPIX][64] bf16 aliases Ts
    float*  C1   = (float*)(tsreg + 3145728);    //   C1 [NPIX][32] f32
    ushort* Agg  = (ushort*)(tsreg + 6291456);   //   Agg [NPIX][64] bf16
    ushort* X1   = (ushort*)(wsb + 25165824);    // 6,291,456 B [NPIX][128] bf16 (q | K)
    ushort* Vb   = (ushort*)(wsb + 31457280);    // 3,145,728 B [NPIX][64] bf16
    ushort* NC   = (ushort*)(wsb + 31457280);    // aliases Vb after k_ca
    ushort* Wqkv = (ushort*)(wsb + 34603008);    // 98,304 B
    float*  bqkv = (float*) (wsb + 34701312);    // 768 B (pad to 1024)
    ushort* A1   = (ushort*)(wsb + 34702336);    // 147,456 B
    ushort* A2   = (ushort*)(wsb + 34849792);    // 36,864 B
    ushort* Ar   = (ushort*)(wsb + 34886656);    // 147,456 B -> end 35,034,112
    if (ws_size < 35034112) return;

    float* xout     = (float*)d_out;                 // [B,256,H,W] f32
    float* cost_out = xout + (size_t)BB*CC*HW;       // [B,32,H,W] f32

    k_prep_feat<<<3072, 256, 0, stream>>>(t_feat, s_feat, Tt, Ts);
    k_prep_w  <<<841,  256, 0, stream>>>(qw,qb,kw,kb,vw,vb,p1w,p2w,rw, Wqkv,bqkv,A1,A2,Ar);
    g_qkv     <<<1152, 256, 0, stream>>>(Tt, Ts, Wqkv, bqkv, X1, Vb);
    k_ca      <<<768,  512, 0, stream>>>(X1, Vb, directs, img_w, C1, Agg);
    g_conv1   <<<768,  256, 0, stream>>>(X1, Agg, A1, p1b, X2);
    g_conv2   <<<768,  256, 0, stream>>>(X2, A2, p2b, C1, cost_out);
    k_sm2     <<<96,   256, 0, stream>>>(cost_out, NC);
    g_final   <<<1536, 256, 0, stream>>>(Tt, NC, Ar, rb, xout);
}

// Round 8
// 138.570 us; speedup vs baseline: 1.7521x; 1.0178x over previous
//
#include <hip/hip_runtime.h>

#define BB 2
#define CC 256
#define CQ 64
#define DD 32
#define HH 64
#define WW 192
#define HW (HH*WW)     // 12288
#define NPIX (BB*HW)   // 24576

typedef __attribute__((ext_vector_type(8))) short bf16x8;
typedef __attribute__((ext_vector_type(4))) float f32x4;

__device__ __forceinline__ float b2f(ushort s){ return __uint_as_float(((uint)s)<<16); }
__device__ __forceinline__ ushort f2b(float f){
    uint u = __float_as_uint(f);
    return (ushort)((u + 0x7fffu + ((u>>16)&1u)) >> 16);
}
__device__ __forceinline__ float eluf(float v){ return v > 0.f ? v : (__expf(v)-1.f); }

// ---------- prep: f32 NCHW -> bf16 pixel-major via LDS tile transpose ----------
// 768 blocks = which(2) x b(2) x tile(192 of 64px); coalesced reads AND writes
__global__ __launch_bounds__(256) void k_prep_feat(
    const float* __restrict__ t_feat, const float* __restrict__ s_feat,
    ushort* __restrict__ Tt, ushort* __restrict__ Ts)
{
    __shared__ ushort sT[64*264];   // 33.8 KiB, padded stride 264
    int blk = blockIdx.x;
    int which = blk / 384;
    int rem   = blk % 384;
    int b     = rem / 192;
    int tile  = rem % 192;
    int p0    = tile*64;
    const float* src = which ? s_feat : t_feat;
    ushort* dst      = which ? Ts : Tt;
    int tid = threadIdx.x;

    for (int i = tid; i < 8192; i += 256){      // 128 ch-pairs x 64 px
        int px = i & 63;
        int cp = i >> 6;
        const float* p = src + ((size_t)(b*CC + cp*2))*HW + p0 + px;
        uint u = (uint)f2b(p[0]) | ((uint)f2b(p[HW])<<16);
        *(uint*)&sT[px*264 + cp*2] = u;
    }
    __syncthreads();
    for (int i = tid; i < 2048; i += 256){      // 64 px x 32 chunks(16B)
        int c16 = i & 31;
        int px  = i >> 5;
        uint4 v = *(const uint4*)&sT[px*264 + c16*8];
        *(uint4*)(dst + ((size_t)(b*HW + p0 + px))*CC + c16*8) = v;
    }
}

// ---------- prep: weights -> bf16 GEMM-A layouts ----------
__global__ __launch_bounds__(256) void k_prep_w(
    const float* __restrict__ qw, const float* __restrict__ qb,
    const float* __restrict__ kw, const float* __restrict__ kb,
    const float* __restrict__ vw, const float* __restrict__ vb,
    const float* __restrict__ p1w, const float* __restrict__ p2w,
    const float* __restrict__ rw,
    ushort* __restrict__ Wqkv, float* __restrict__ bqkv,
    ushort* __restrict__ A1, ushort* __restrict__ A2, ushort* __restrict__ Ar)
{
    int id = blockIdx.x*256 + threadIdx.x;
    if (id < 49152) {                      // Wqkv [192][256]
        int o = id / 256, c = id % 256;
        float v = (o<64)? qw[o*256+c] : (o<128)? kw[(o-64)*256+c] : vw[(o-128)*256+c];
        Wqkv[id] = f2b(v);
    } else if (id < 49344) {               // bqkv [192]
        int o = id - 49152;
        bqkv[o] = (o<64)? qb[o] : (o<128)? kb[o-64] : vb[o-128];
    } else if (id < 49344+73728) {         // A1 [64][9*128], k = t*128+ci
        int i = id - 49344;
        int o = i/1152, r = i%1152, t = r/128, ci = r%128;
        A1[i] = f2b(p1w[(size_t)(o*128+ci)*9 + t]);
    } else if (id < 49344+73728+18432) {   // A2 [32][9*64]
        int i = id - (49344+73728);
        int o = i/576, r = i%576, t = r/64, ci = r%64;
        A2[i] = f2b(p2w[(size_t)(o*64+ci)*9 + t]);
    } else if (id < 49344+73728+18432+73728) {  // Ar [256][288]
        int i = id - (49344+73728+18432);
        Ar[i] = f2b(rw[i]);
    }
}

// ---------- G1: qkv conv1x1 as MFMA GEMM ----------
__global__ __launch_bounds__(256) void g_qkv(
    const ushort* __restrict__ Tt, const ushort* __restrict__ Ts,
    const ushort* __restrict__ Wqkv, const float* __restrict__ bqkv,
    ushort* __restrict__ X1, ushort* __restrict__ Vb)
{
    int wv = threadIdx.x >> 6;
    int lane = threadIdx.x & 63;
    int lm = lane & 15, lk = lane >> 4;
    int g  = blockIdx.x / 384;
    int n0 = (blockIdx.x % 384) * 64;
    const ushort* Bsrc = (g==0) ? Tt : Ts;
    const ushort* Ap = Wqkv + (size_t)(g*64 + wv*16 + lm)*CC + lk*8;
    const ushort* Bp = Bsrc + (size_t)n0*CC + lk*8;
    f32x4 acc[4];
    #pragma unroll
    for (int i=0;i<4;++i) acc[i] = (f32x4){0.f,0.f,0.f,0.f};
    for (int k0=0; k0<CC; k0+=32){
        bf16x8 a = *(const bf16x8*)(Ap + k0);
        #pragma unroll
        for (int nt=0; nt<4; ++nt){
            bf16x8 bb = *(const bf16x8*)(Bp + (size_t)(nt*16+lm)*CC + k0);
            acc[nt] = __builtin_amdgcn_mfma_f32_16x16x32_bf16(a, bb, acc[nt], 0,0,0);
        }
    }
    int ob = g*64 + wv*16 + lk*4;   // bias index base
    int ol = wv*16 + lk*4;          // channel within 64
    #pragma unroll
    for (int nt=0; nt<4; ++nt){
        int p = n0 + nt*16 + lm;
        uint u0 = (uint)f2b(acc[nt][0]+bqkv[ob])   | ((uint)f2b(acc[nt][1]+bqkv[ob+1])<<16);
        uint u1 = (uint)f2b(acc[nt][2]+bqkv[ob+2]) | ((uint)f2b(acc[nt][3]+bqkv[ob+3])<<16);
        ushort* dst;
        if (g==0)      dst = X1 + (size_t)p*128 + ol;        // q half
        else if (g==1) dst = X1 + (size_t)p*128 + 64 + ol;   // K half (persistent)
        else           dst = Vb + (size_t)p*64 + ol;
        *(uint2*)dst = make_uint2(u0, u1);
    }
}

// ---------- k_ca: cost + softmax + aggV ----------
// 768 blocks, XCD-swizzled so a row's 6 sub-blocks share one XCD's L2.
// 512 thr = 32 px x (8 oct x 2 dhalf). K/V row chunk-major [c8][SVS=193] (odd
// stride -> uniform 8 lanes/bank-group on all b128 accesses).
#define SVS 193
__global__ __launch_bounds__(512) void k_ca(
    const ushort* __restrict__ X1, const ushort* __restrict__ Vb,
    const float* __restrict__ directs, const int* __restrict__ img_w_p,
    float* __restrict__ C1, ushort* __restrict__ Agg)
{
    __shared__ ushort sK[8*SVS*8];   // 24.1 KiB
    __shared__ ushort sV[8*SVS*8];   // 24.1 KiB
    int tid = threadIdx.x;
    // decode XCD-grouped index: xcd = row%8 for all 6 sub-blocks of a row
    int j   = blockIdx.x;            // 768
    int r8  = j & 7;
    int kk  = j >> 3;                // 0..95
    int sub = kk % 6;
    int rhi = kk / 6;                // 0..15
    int row = rhi*8 + r8;            // 0..127 = b*64 + h
    int b   = row >> 6;
    int h   = row & 63;
    int w0  = sub * 32;
    size_t rowbase = (size_t)b*HW + (size_t)h*WW;

    for (int i = tid; i < 1536; i += 512){   // full row: 192 px x 8 octs
        int c8 = i & 7, x = i >> 3;
        *(uint4*)&sK[(c8*SVS + x)*8] = *(const uint4*)(X1 + (rowbase+x)*128 + 64 + c8*8);
        *(uint4*)&sV[(c8*SVS + x)*8] = *(const uint4*)(Vb + (rowbase+x)*64 + c8*8);
    }
    __syncthreads();

    int px  = tid >> 4;        // 0..31
    int l16 = tid & 15;
    int oct = l16 >> 1;        // shfl masks 2,4,8
    int dh  = l16 & 1;         // shfl mask 1
    int w   = w0 + px;
    size_t n = rowbase + w;

    int imw = img_w_p[0];
    float rel = (imw != 640) ? (640.0f/(float)imw) : 1.0f;
    float sf = 0.01f * rel * directs[b] * 191.0f;
    float wf = (float)w;

    float qf[8];
    {
        bf16x8 qv = *(const bf16x8*)(X1 + n*128 + oct*8);
        #pragma unroll
        for (int j2=0;j2<8;++j2) qf[j2] = b2f((ushort)qv[j2]);
    }

    // ---- phase A: partial cost (my 8 ch) for my 16 d's ----
    float cost[16]; int x0k[16]; float frk[16];
    #pragma unroll
    for (int k=0;k<16;++k){
        int d = dh*16 + k;
        float srcx = fminf(fmaxf(wf + (float)d*sf, 0.f), 191.0f);
        int x0 = (int)floorf(srcx);
        int x1 = min(x0+1, 191);
        float fr = srcx - (float)x0;
        x0k[k] = x0; frk[k] = fr;
        bf16x8 k0v = *(const bf16x8*)&sK[(oct*SVS + x0)*8];
        bf16x8 k1v = *(const bf16x8*)&sK[(oct*SVS + x1)*8];
        float s0 = 0.f, s1 = 0.f;
        #pragma unroll
        for (int j2=0;j2<8;++j2){
            s0 += qf[j2]*b2f((ushort)k0v[j2]);
            s1 += qf[j2]*b2f((ushort)k1v[j2]);
        }
        cost[k] = s0 + fr*(s1-s0);
    }
    #pragma unroll
    for (int k=0;k<16;++k){
        float v = cost[k];
        v += __shfl_xor(v, 2);
        v += __shfl_xor(v, 4);
        v += __shfl_xor(v, 8);
        cost[k] = v * 0.125f;
    }
    if (oct == 0){
        float* cp = C1 + n*DD + dh*16;
        #pragma unroll
        for (int q=0;q<4;++q){
            f32x4 t4; t4[0]=cost[q*4]; t4[1]=cost[q*4+1]; t4[2]=cost[q*4+2]; t4[3]=cost[q*4+3];
            *(f32x4*)(cp + q*4) = t4;
        }
    }
    // ---- softmax across 32 d ----
    float mm = cost[0];
    #pragma unroll
    for (int k=1;k<16;++k) mm = fmaxf(mm, cost[k]);
    mm = fmaxf(mm, __shfl_xor(mm, 1));
    float ss = 0.f;
    #pragma unroll
    for (int k=0;k<16;++k){ cost[k] = __expf(cost[k]-mm); ss += cost[k]; }
    ss += __shfl_xor(ss, 1);
    float inv = 1.f/ss;

    // ---- phase C: agg over my 16 d's for my 8 ch ----
    float agg[8];
    #pragma unroll
    for (int j2=0;j2<8;++j2) agg[j2]=0.f;
    #pragma unroll
    for (int k=0;k<16;++k){
        float pd = cost[k]*inv;
        int x0 = x0k[k];
        int x1 = min(x0+1, 191);
        float fr = frk[k];
        float a1 = pd*fr, a0 = pd - a1;
        bf16x8 v0v = *(const bf16x8*)&sV[(oct*SVS + x0)*8];
        bf16x8 v1v = *(const bf16x8*)&sV[(oct*SVS + x1)*8];
        #pragma unroll
        for (int j2=0;j2<8;++j2)
            agg[j2] += a0*b2f((ushort)v0v[j2]) + a1*b2f((ushort)v1v[j2]);
    }
    #pragma unroll
    for (int j2=0;j2<8;++j2) agg[j2] += __shfl_xor(agg[j2], 1);
    if (dh == 0){
        uint u[4];
        #pragma unroll
        for (int j2=0;j2<4;++j2)
            u[j2] = (uint)f2b(agg[j2*2]) | ((uint)f2b(agg[j2*2+1])<<16);
        uint4 q4; q4.x=u[0]; q4.y=u[1]; q4.z=u[2]; q4.w=u[3];
        *(uint4*)(Agg + n*64 + oct*8) = q4;
    }
}

// ---------- G2: conv3x3 p1 as LDS-staged implicit GEMM, ELU ----------
__global__ __launch_bounds__(256) void g_conv1(
    const ushort* __restrict__ X1, const ushort* __restrict__ Agg,
    const ushort* __restrict__ A1, const float* __restrict__ p1b,
    ushort* __restrict__ X2)
{
    __shared__ ushort sB[3*16*34*8];   // 26.1 KiB
    int tid = threadIdx.x;
    int wv = tid >> 6, lane = tid & 63;
    int lm = lane & 15, lk = lane >> 4;
    int n0 = blockIdx.x * 32;
    int b  = n0 / HW;
    int pl = n0 % HW;
    int h  = pl / WW, w0 = pl % WW;

    for (int i = tid; i < 1632; i += 256){
        int dh = i / 544, rem2 = i % 544;
        int c16 = rem2 / 34, x = rem2 % 34;
        int hh = h + dh - 1, wx = w0 + x - 1;
        uint4 val = make_uint4(0,0,0,0);
        if (hh >= 0 && hh < HH && wx >= 0 && wx < WW){
            size_t pix = (size_t)b*HW + (size_t)hh*WW + wx;
            val = (c16 < 8) ? *(const uint4*)(X1 + pix*128 + c16*8)
                            : *(const uint4*)(Agg + pix*64 + (c16-8)*8);
        }
        *(uint4*)&sB[((dh*16 + c16)*34 + x)*8] = val;
    }
    __syncthreads();

    int mw = wv & 1, nw = wv >> 1;
    const ushort* Ap = A1 + (size_t)(mw*32 + lm)*1152 + lk*8;
    f32x4 acc0 = {0.f,0.f,0.f,0.f}, acc1 = {0.f,0.f,0.f,0.f};
    int xb = nw*16 + lm;
    #pragma unroll
    for (int t=0; t<9; ++t){
        int dh = t/3, dw = t%3;
        #pragma unroll
        for (int c0=0; c0<128; c0+=32){
            bf16x8 bb = *(const bf16x8*)&sB[((dh*16 + (c0>>3)+lk)*34 + xb + dw)*8];
            bf16x8 a0 = *(const bf16x8*)(Ap + t*128 + c0);
            bf16x8 a1 = *(const bf16x8*)(Ap + (size_t)16*1152 + t*128 + c0);
            acc0 = __builtin_amdgcn_mfma_f32_16x16x32_bf16(a0, bb, acc0, 0,0,0);
            acc1 = __builtin_amdgcn_mfma_f32_16x16x32_bf16(a1, bb, acc1, 0,0,0);
        }
    }
    int pg = n0 + nw*16 + lm;
    int o0 = mw*32 + lk*4;
    {
        uint u0 = (uint)f2b(eluf(acc0[0]+p1b[o0]))   | ((uint)f2b(eluf(acc0[1]+p1b[o0+1]))<<16);
        uint u1 = (uint)f2b(eluf(acc0[2]+p1b[o0+2])) | ((uint)f2b(eluf(acc0[3]+p1b[o0+3]))<<16);
        *(uint2*)(X2 + (size_t)pg*64 + o0) = make_uint2(u0, u1);
        int o1 = o0 + 16;
        uint u2 = (uint)f2b(eluf(acc1[0]+p1b[o1]))   | ((uint)f2b(eluf(acc1[1]+p1b[o1+1]))<<16);
        uint u3 = (uint)f2b(eluf(acc1[2]+p1b[o1+2])) | ((uint)f2b(eluf(acc1[3]+p1b[o1+3]))<<16);
        *(uint2*)(X2 + (size_t)pg*64 + o1) = make_uint2(u2, u3);
    }
}

// ---------- G3: conv3x3 p2 + residual avg -> cost_out (LDS-staged) ----------
__global__ __launch_bounds__(256) void g_conv2(
    const ushort* __restrict__ X2, const ushort* __restrict__ A2,
    const float* __restrict__ p2b, const float* __restrict__ C1,
    float* __restrict__ cost_out)
{
    __shared__ ushort sB[3*8*34*8];   // 13 KiB
    int tid = threadIdx.x;
    int wv = tid >> 6, lane = tid & 63;
    int lm = lane & 15, lk = lane >> 4;
    int n0 = blockIdx.x * 32;
    int b  = n0 / HW;
    int pl = n0 % HW;
    int h  = pl / WW, w0 = pl % WW;

    for (int i = tid; i < 816; i += 256){
        int dh = i / 272, rem2 = i % 272;
        int c16 = rem2 / 34, x = rem2 % 34;
        int hh = h + dh - 1, wx = w0 + x - 1;
        uint4 val = make_uint4(0,0,0,0);
        if (hh >= 0 && hh < HH && wx >= 0 && wx < WW)
            val = *(const uint4*)(X2 + ((size_t)b*HW + (size_t)hh*WW + wx)*64 + c16*8);
        *(uint4*)&sB[((dh*8 + c16)*34 + x)*8] = val;
    }
    __syncthreads();

    int mw = wv & 1, nw = wv >> 1;
    const ushort* Ap = A2 + (size_t)(mw*16 + lm)*576 + lk*8;
    f32x4 acc = {0.f,0.f,0.f,0.f};
    int xb = nw*16 + lm;
    #pragma unroll
    for (int t=0; t<9; ++t){
        int dh = t/3, dw = t%3;
        #pragma unroll
        for (int c0=0; c0<64; c0+=32){
            bf16x8 bb = *(const bf16x8*)&sB[((dh*8 + (c0>>3)+lk)*34 + xb + dw)*8];
            bf16x8 a  = *(const bf16x8*)(Ap + t*64 + c0);
            acc = __builtin_amdgcn_mfma_f32_16x16x32_bf16(a, bb, acc, 0,0,0);
        }
    }
    int pg = n0 + nw*16 + lm;
    int pll = pg % HW;
    int o = mw*16 + lk*4;
    f32x4 cv = *(const f32x4*)(C1 + (size_t)pg*DD + o);
    #pragma unroll
    for (int j=0;j<4;++j)
        cost_out[((size_t)(b*DD + o + j))*HW + pll] = (cv[j] + acc[j] + p2b[o+j]) * 0.5f;
}

// ---------- softmax over D -> NC (bf16 pixel-major) ----------
__global__ __launch_bounds__(256) void k_sm2(
    const float* __restrict__ cost_out, ushort* __restrict__ NC)
{
    int n = blockIdx.x*256 + threadIdx.x;   // 24576
    int b = n / HW, pl = n % HW;
    const float* cp = cost_out + (size_t)b*DD*HW + pl;
    float v[DD]; float m = -1e30f;
    #pragma unroll
    for (int d=0; d<DD; ++d){ v[d] = cp[(size_t)d*HW]; m = fmaxf(m, v[d]); }
    float s = 0.f;
    #pragma unroll
    for (int d=0; d<DD; ++d){ v[d] = __expf(v[d]-m); s += v[d]; }
    float inv = 1.f/s;
    ushort* op = NC + (size_t)n*DD;
    #pragma unroll
    for (int d8=0; d8<4; ++d8){
        uint u[4];
        #pragma unroll
        for (int j2=0;j2<4;++j2)
            u[j2] = (uint)f2b(v[d8*8+j2*2]*inv) | ((uint)f2b(v[d8*8+j2*2+1]*inv)<<16);
        uint4 q4; q4.x=u[0]; q4.y=u[1]; q4.z=u[2]; q4.w=u[3];
        *(uint4*)(op + d8*8) = q4;
    }
}

// ---------- G4: final conv1x1 on concat(t_feat, nc2), ELU ----------
__global__ __launch_bounds__(256) void g_final(
    const ushort* __restrict__ Tt, const ushort* __restrict__ NC,
    const ushort* __restrict__ Ar, const float* __restrict__ rb,
    float* __restrict__ xout)
{
    int wv = threadIdx.x >> 6;
    int lane = threadIdx.x & 63;
    int lm = lane & 15, lk = lane >> 4;
    int mg = blockIdx.x / 384;
    int n0 = (blockIdx.x % 384) * 64;
    const ushort* Ap = Ar + (size_t)(mg*64 + wv*16 + lm)*288 + lk*8;
    f32x4 acc[4];
    #pragma unroll
    for (int i=0;i<4;++i) acc[i] = (f32x4){0.f,0.f,0.f,0.f};
    for (int k0=0; k0<288; k0+=32){
        bf16x8 a = *(const bf16x8*)(Ap + k0);
        #pragma unroll
        for (int nt=0; nt<4; ++nt){
            int p = n0 + nt*16 + lm;
            const ushort* src = (k0 < 256) ? (Tt + (size_t)p*CC + k0 + lk*8)
                                           : (NC + (size_t)p*DD + lk*8);
            bf16x8 bb = *(const bf16x8*)src;
            acc[nt] = __builtin_amdgcn_mfma_f32_16x16x32_bf16(a, bb, acc[nt], 0,0,0);
        }
    }
    int o = mg*64 + wv*16 + lk*4;
    #pragma unroll
    for (int nt=0; nt<4; ++nt){
        int p = n0 + nt*16 + lm;
        int b = p / HW, pl = p % HW;
        #pragma unroll
        for (int j=0;j<4;++j)
            xout[((size_t)(b*CC + o + j))*HW + pl] = eluf(acc[nt][j] + rb[o+j]);
    }
}

extern "C" void kernel_launch(void* const* d_in, const int* in_sizes, int n_in,
                              void* d_out, int out_size, void* d_ws, size_t ws_size,
                              hipStream_t stream)
{
    const float* t_feat = (const float*)d_in[0];
    const float* s_feat = (const float*)d_in[1];
    const float* directs= (const float*)d_in[2];
    const float* qw = (const float*)d_in[3];
    const float* qb = (const float*)d_in[4];
    const float* kw = (const float*)d_in[5];
    const float* kb = (const float*)d_in[6];
    const float* vw = (const float*)d_in[7];
    const float* vb = (const float*)d_in[8];
    const float* p1w= (const float*)d_in[9];
    const float* p1b= (const float*)d_in[10];
    const float* p2w= (const float*)d_in[11];
    const float* p2b= (const float*)d_in[12];
    const float* rw = (const float*)d_in[13];
    const float* rb = (const float*)d_in[14];
    const int* img_w= (const int*)d_in[15];

    // workspace layout (byte offsets, lifetime-aliased)
    char* wsb = (char*)d_ws;
    ushort* Tt   = (ushort*)(wsb + 0);           // 12,582,912 B  [NPIX][256] bf16
    char*  tsreg = wsb + 12582912;               // 12,582,912 B region
    ushort* Ts   = (ushort*)tsreg;               //   Ts (dead after g_qkv)
    ushort* X2   = (ushort*)tsreg;               //   X2 [NPIX][64] bf16 aliases Ts
    float*  C1   = (float*)(tsreg + 3145728);    //   C1 [NPIX][32] f32
    ushort* Agg  = (ushort*)(tsreg + 6291456);   //   Agg [NPIX][64] bf16
    ushort* X1   = (ushort*)(wsb + 25165824);    // 6,291,456 B [NPIX][128] bf16 (q | K)
    ushort* Vb   = (ushort*)(wsb + 31457280);    // 3,145,728 B [NPIX][64] bf16
    ushort* NC   = (ushort*)(wsb + 31457280);    // aliases Vb after k_ca
    ushort* Wqkv = (ushort*)(wsb + 34603008);    // 98,304 B
    float*  bqkv = (float*) (wsb + 34701312);    // 768 B (pad to 1024)
    ushort* A1   = (ushort*)(wsb + 34702336);    // 147,456 B
    ushort* A2   = (ushort*)(wsb + 34849792);    // 36,864 B
    ushort* Ar   = (ushort*)(wsb + 34886656);    // 147,456 B -> end 35,034,112
    if (ws_size < 35034112) return;

    float* xout     = (float*)d_out;                 // [B,256,H,W] f32
    float* cost_out = xout + (size_t)BB*CC*HW;       // [B,32,H,W] f32

    k_prep_feat<<<768, 256, 0, stream>>>(t_feat, s_feat, Tt, Ts);
    k_prep_w  <<<841,  256, 0, stream>>>(qw,qb,kw,kb,vw,vb,p1w,p2w,rw, Wqkv,bqkv,A1,A2,Ar);
    g_qkv     <<<1152, 256, 0, stream>>>(Tt, Ts, Wqkv, bqkv, X1, Vb);
    k_ca      <<<768,  512, 0, stream>>>(X1, Vb, directs, img_w, C1, Agg);
    g_conv1   <<<768,  256, 0, stream>>>(X1, Agg, A1, p1b, X2);
    g_conv2   <<<768,  256, 0, stream>>>(X2, A2, p2b, C1, cost_out);
    k_sm2     <<<96,   256, 0, stream>>>(cost_out, NC);
    g_final   <<<1536, 256, 0, stream>>>(Tt, NC, Ar, rb, xout);
}

// Round 9
// 113.444 us; speedup vs baseline: 2.1402x; 1.2215x over previous
//
#include <hip/hip_runtime.h>

#define BB 2
#define CC 256
#define CQ 64
#define DD 32
#define HH 64
#define WW 192
#define HW (HH*WW)     // 12288
#define NPIX (BB*HW)   // 24576

typedef __attribute__((ext_vector_type(8))) short bf16x8;
typedef __attribute__((ext_vector_type(4))) float f32x4;

__device__ __forceinline__ float b2f(ushort s){ return __uint_as_float(((uint)s)<<16); }
__device__ __forceinline__ ushort f2b(float f){
    uint u = __float_as_uint(f);
    return (ushort)((u + 0x7fffu + ((u>>16)&1u)) >> 16);
}
__device__ __forceinline__ float eluf(float v){ return v > 0.f ? v : (__expf(v)-1.f); }

// ---------- prep: f32 NCHW -> bf16 pixel-major via LDS tile transpose ----------
__global__ __launch_bounds__(256) void k_prep_feat(
    const float* __restrict__ t_feat, const float* __restrict__ s_feat,
    ushort* __restrict__ Tt, ushort* __restrict__ Ts)
{
    __shared__ ushort sT[64*264];   // 33.8 KiB, padded stride 33 chunks
    int blk = blockIdx.x;
    int which = blk / 384;
    int rem   = blk % 384;
    int b     = rem / 192;
    int tile  = rem % 192;
    int p0    = tile*64;
    const float* src = which ? s_feat : t_feat;
    ushort* dst      = which ? Ts : Tt;
    int tid = threadIdx.x;

    for (int i = tid; i < 2048; i += 256){      // 64 px x 32 ch-chunks, uint4 writes
        int px  = i & 63;
        int c16 = i >> 6;
        const float* p = src + ((size_t)(b*CC + c16*8))*HW + p0 + px;
        uint u[4];
        #pragma unroll
        for (int j2=0;j2<4;++j2)
            u[j2] = (uint)f2b(p[(size_t)(2*j2)*HW]) | ((uint)f2b(p[(size_t)(2*j2+1)*HW])<<16);
        uint4 q4; q4.x=u[0]; q4.y=u[1]; q4.z=u[2]; q4.w=u[3];
        *(uint4*)&sT[(px*33 + c16)*8] = q4;
    }
    __syncthreads();
    for (int i = tid; i < 2048; i += 256){      // coalesced 512B-row writes
        int c16 = i & 31;
        int px  = i >> 5;
        uint4 v = *(const uint4*)&sT[(px*33 + c16)*8];
        *(uint4*)(dst + ((size_t)(b*HW + p0 + px))*CC + c16*8) = v;
    }
}

// ---------- prep: weights -> bf16 GEMM-A layouts ----------
__global__ __launch_bounds__(256) void k_prep_w(
    const float* __restrict__ qw, const float* __restrict__ qb,
    const float* __restrict__ kw, const float* __restrict__ kb,
    const float* __restrict__ vw, const float* __restrict__ vb,
    const float* __restrict__ p1w, const float* __restrict__ p2w,
    const float* __restrict__ rw,
    ushort* __restrict__ Wqkv, float* __restrict__ bqkv,
    ushort* __restrict__ A1, ushort* __restrict__ A2, ushort* __restrict__ Ar)
{
    int id = blockIdx.x*256 + threadIdx.x;
    if (id < 49152) {                      // Wqkv [192][256]
        int o = id / 256, c = id % 256;
        float v = (o<64)? qw[o*256+c] : (o<128)? kw[(o-64)*256+c] : vw[(o-128)*256+c];
        Wqkv[id] = f2b(v);
    } else if (id < 49344) {               // bqkv [192]
        int o = id - 49152;
        bqkv[o] = (o<64)? qb[o] : (o<128)? kb[o-64] : vb[o-128];
    } else if (id < 49344+73728) {         // A1 [64][9*128]
        int i = id - 49344;
        int o = i/1152, r = i%1152, t = r/128, ci = r%128;
        A1[i] = f2b(p1w[(size_t)(o*128+ci)*9 + t]);
    } else if (id < 49344+73728+18432) {   // A2 [32][9*64]
        int i = id - (49344+73728);
        int o = i/576, r = i%576, t = r/64, ci = r%64;
        A2[i] = f2b(p2w[(size_t)(o*64+ci)*9 + t]);
    } else if (id < 49344+73728+18432+73728) {  // Ar [256][288]
        int i = id - (49344+73728+18432);
        Ar[i] = f2b(rw[i]);
    }
}

// ---------- G1: qkv conv1x1, LDS-staged B ----------
// 768 blocks (XCD-swizzled) x 256 thr; tile = 32 px; stage Tt+Ts tiles;
// wave = {q,k,v} m-tiles x 2 n-tiles, 48 MFMA
__global__ __launch_bounds__(256) void g_qkv(
    const ushort* __restrict__ Tt, const ushort* __restrict__ Ts,
    const ushort* __restrict__ Wqkv, const float* __restrict__ bqkv,
    ushort* __restrict__ X1, ushort* __restrict__ Vb)
{
    __shared__ ushort sT[32*264];   // 16.9 KiB each
    __shared__ ushort sS[32*264];
    int tid = threadIdx.x;
    int bid = blockIdx.x;
    int tile = (bid & 7)*96 + (bid >> 3);    // XCD-chunk swizzle (768 = 8x96)
    int p0 = tile * 32;

    for (int i = tid; i < 1024; i += 256){
        int px = i >> 5, c16 = i & 31;
        size_t gsrc = ((size_t)(p0 + px))*CC + c16*8;
        *(uint4*)&sT[(px*33 + c16)*8] = *(const uint4*)(Tt + gsrc);
        *(uint4*)&sS[(px*33 + c16)*8] = *(const uint4*)(Ts + gsrc);
    }
    __syncthreads();

    int wv = tid >> 6, lane = tid & 63;
    int lm = lane & 15, lk = lane >> 4;
    f32x4 acc[3][2];
    #pragma unroll
    for (int g=0;g<3;++g){ acc[g][0]=(f32x4){0.f,0.f,0.f,0.f}; acc[g][1]=(f32x4){0.f,0.f,0.f,0.f}; }
    const ushort* Ap = Wqkv + (size_t)(wv*16 + lm)*CC + lk*8;

    #pragma unroll
    for (int k0=0; k0<CC; k0+=32){
        bf16x8 a0 = *(const bf16x8*)(Ap + k0);              // q row
        bf16x8 a1 = *(const bf16x8*)(Ap + 64*CC + k0);      // k row
        bf16x8 a2 = *(const bf16x8*)(Ap + 128*CC + k0);     // v row
        #pragma unroll
        for (int nt=0; nt<2; ++nt){
            int ch = (nt*16+lm)*33 + (k0>>3) + lk;
            bf16x8 bT = *(const bf16x8*)&sT[ch*8];
            bf16x8 bS = *(const bf16x8*)&sS[ch*8];
            acc[0][nt] = __builtin_amdgcn_mfma_f32_16x16x32_bf16(a0, bT, acc[0][nt], 0,0,0);
            acc[1][nt] = __builtin_amdgcn_mfma_f32_16x16x32_bf16(a1, bS, acc[1][nt], 0,0,0);
            acc[2][nt] = __builtin_amdgcn_mfma_f32_16x16x32_bf16(a2, bS, acc[2][nt], 0,0,0);
        }
    }
    int ol = wv*16 + lk*4;
    #pragma unroll
    for (int g=0;g<3;++g){
        int ob = g*64 + ol;
        #pragma unroll
        for (int nt=0; nt<2; ++nt){
            int p = p0 + nt*16 + lm;
            uint u0 = (uint)f2b(acc[g][nt][0]+bqkv[ob])   | ((uint)f2b(acc[g][nt][1]+bqkv[ob+1])<<16);
            uint u1 = (uint)f2b(acc[g][nt][2]+bqkv[ob+2]) | ((uint)f2b(acc[g][nt][3]+bqkv[ob+3])<<16);
            ushort* dst;
            if (g==0)      dst = X1 + (size_t)p*128 + ol;
            else if (g==1) dst = X1 + (size_t)p*128 + 64 + ol;
            else           dst = Vb + (size_t)p*64 + ol;
            *(uint2*)dst = make_uint2(u0, u1);
        }
    }
}

// ---------- k_ca: cost + softmax + aggV (unchanged from R8) ----------
#define SVS 193
__global__ __launch_bounds__(512) void k_ca(
    const ushort* __restrict__ X1, const ushort* __restrict__ Vb,
    const float* __restrict__ directs, const int* __restrict__ img_w_p,
    float* __restrict__ C1, ushort* __restrict__ Agg)
{
    __shared__ ushort sK[8*SVS*8];
    __shared__ ushort sV[8*SVS*8];
    int tid = threadIdx.x;
    int j   = blockIdx.x;
    int r8  = j & 7;
    int kk  = j >> 3;
    int sub = kk % 6;
    int rhi = kk / 6;
    int row = rhi*8 + r8;
    int b   = row >> 6;
    int h   = row & 63;
    int w0  = sub * 32;
    size_t rowbase = (size_t)b*HW + (size_t)h*WW;

    for (int i = tid; i < 1536; i += 512){
        int c8 = i & 7, x = i >> 3;
        *(uint4*)&sK[(c8*SVS + x)*8] = *(const uint4*)(X1 + (rowbase+x)*128 + 64 + c8*8);
        *(uint4*)&sV[(c8*SVS + x)*8] = *(const uint4*)(Vb + (rowbase+x)*64 + c8*8);
    }
    __syncthreads();

    int px  = tid >> 4;
    int l16 = tid & 15;
    int oct = l16 >> 1;
    int dh  = l16 & 1;
    int w   = w0 + px;
    size_t n = rowbase + w;

    int imw = img_w_p[0];
    float rel = (imw != 640) ? (640.0f/(float)imw) : 1.0f;
    float sf = 0.01f * rel * directs[b] * 191.0f;
    float wf = (float)w;

    float qf[8];
    {
        bf16x8 qv = *(const bf16x8*)(X1 + n*128 + oct*8);
        #pragma unroll
        for (int j2=0;j2<8;++j2) qf[j2] = b2f((ushort)qv[j2]);
    }

    float cost[16]; int x0k[16]; float frk[16];
    #pragma unroll
    for (int k=0;k<16;++k){
        int d = dh*16 + k;
        float srcx = fminf(fmaxf(wf + (float)d*sf, 0.f), 191.0f);
        int x0 = (int)floorf(srcx);
        int x1 = min(x0+1, 191);
        float fr = srcx - (float)x0;
        x0k[k] = x0; frk[k] = fr;
        bf16x8 k0v = *(const bf16x8*)&sK[(oct*SVS + x0)*8];
        bf16x8 k1v = *(const bf16x8*)&sK[(oct*SVS + x1)*8];
        float s0 = 0.f, s1 = 0.f;
        #pragma unroll
        for (int j2=0;j2<8;++j2){
            s0 += qf[j2]*b2f((ushort)k0v[j2]);
            s1 += qf[j2]*b2f((ushort)k1v[j2]);
        }
        cost[k] = s0 + fr*(s1-s0);
    }
    #pragma unroll
    for (int k=0;k<16;++k){
        float v = cost[k];
        v += __shfl_xor(v, 2);
        v += __shfl_xor(v, 4);
        v += __shfl_xor(v, 8);
        cost[k] = v * 0.125f;
    }
    if (oct == 0){
        float* cp = C1 + n*DD + dh*16;
        #pragma unroll
        for (int q=0;q<4;++q){
            f32x4 t4; t4[0]=cost[q*4]; t4[1]=cost[q*4+1]; t4[2]=cost[q*4+2]; t4[3]=cost[q*4+3];
            *(f32x4*)(cp + q*4) = t4;
        }
    }
    float mm = cost[0];
    #pragma unroll
    for (int k=1;k<16;++k) mm = fmaxf(mm, cost[k]);
    mm = fmaxf(mm, __shfl_xor(mm, 1));
    float ss = 0.f;
    #pragma unroll
    for (int k=0;k<16;++k){ cost[k] = __expf(cost[k]-mm); ss += cost[k]; }
    ss += __shfl_xor(ss, 1);
    float inv = 1.f/ss;

    float agg[8];
    #pragma unroll
    for (int j2=0;j2<8;++j2) agg[j2]=0.f;
    #pragma unroll
    for (int k=0;k<16;++k){
        float pd = cost[k]*inv;
        int x0 = x0k[k];
        int x1 = min(x0+1, 191);
        float fr = frk[k];
        float a1 = pd*fr, a0 = pd - a1;
        bf16x8 v0v = *(const bf16x8*)&sV[(oct*SVS + x0)*8];
        bf16x8 v1v = *(const bf16x8*)&sV[(oct*SVS + x1)*8];
        #pragma unroll
        for (int j2=0;j2<8;++j2)
            agg[j2] += a0*b2f((ushort)v0v[j2]) + a1*b2f((ushort)v1v[j2]);
    }
    #pragma unroll
    for (int j2=0;j2<8;++j2) agg[j2] += __shfl_xor(agg[j2], 1);
    if (dh == 0){
        uint u[4];
        #pragma unroll
        for (int j2=0;j2<4;++j2)
            u[j2] = (uint)f2b(agg[j2*2]) | ((uint)f2b(agg[j2*2+1])<<16);
        uint4 q4; q4.x=u[0]; q4.y=u[1]; q4.z=u[2]; q4.w=u[3];
        *(uint4*)(Agg + n*64 + oct*8) = q4;
    }
}

// ---------- G2: conv3x3 p1, LDS-staged implicit GEMM, ELU ----------
__global__ __launch_bounds__(256) void g_conv1(
    const ushort* __restrict__ X1, const ushort* __restrict__ Agg,
    const ushort* __restrict__ A1, const float* __restrict__ p1b,
    ushort* __restrict__ X2)
{
    __shared__ ushort sB[3*16*34*8];   // 26.1 KiB
    int tid = threadIdx.x;
    int wv = tid >> 6, lane = tid & 63;
    int lm = lane & 15, lk = lane >> 4;
    int bid = blockIdx.x;
    int tile = (bid & 7)*96 + (bid >> 3);    // XCD swizzle
    int n0 = tile * 32;
    int b  = n0 / HW;
    int pl = n0 % HW;
    int h  = pl / WW, w0 = pl % WW;

    for (int i = tid; i < 1632; i += 256){
        int dh = i / 544, rem2 = i % 544;
        int c16 = rem2 / 34, x = rem2 % 34;
        int hh = h + dh - 1, wx = w0 + x - 1;
        uint4 val = make_uint4(0,0,0,0);
        if (hh >= 0 && hh < HH && wx >= 0 && wx < WW){
            size_t pix = (size_t)b*HW + (size_t)hh*WW + wx;
            val = (c16 < 8) ? *(const uint4*)(X1 + pix*128 + c16*8)
                            : *(const uint4*)(Agg + pix*64 + (c16-8)*8);
        }
        *(uint4*)&sB[((dh*16 + c16)*34 + x)*8] = val;
    }
    __syncthreads();

    int mw = wv & 1, nw = wv >> 1;
    const ushort* Ap = A1 + (size_t)(mw*32 + lm)*1152 + lk*8;
    f32x4 acc0 = {0.f,0.f,0.f,0.f}, acc1 = {0.f,0.f,0.f,0.f};
    int xb = nw*16 + lm;
    #pragma unroll
    for (int t=0; t<9; ++t){
        int dh = t/3, dw = t%3;
        #pragma unroll
        for (int c0=0; c0<128; c0+=32){
            bf16x8 bb = *(const bf16x8*)&sB[((dh*16 + (c0>>3)+lk)*34 + xb + dw)*8];
            bf16x8 a0 = *(const bf16x8*)(Ap + t*128 + c0);
            bf16x8 a1 = *(const bf16x8*)(Ap + (size_t)16*1152 + t*128 + c0);
            acc0 = __builtin_amdgcn_mfma_f32_16x16x32_bf16(a0, bb, acc0, 0,0,0);
            acc1 = __builtin_amdgcn_mfma_f32_16x16x32_bf16(a1, bb, acc1, 0,0,0);
        }
    }
    int pg = n0 + nw*16 + lm;
    int o0 = mw*32 + lk*4;
    {
        uint u0 = (uint)f2b(eluf(acc0[0]+p1b[o0]))   | ((uint)f2b(eluf(acc0[1]+p1b[o0+1]))<<16);
        uint u1 = (uint)f2b(eluf(acc0[2]+p1b[o0+2])) | ((uint)f2b(eluf(acc0[3]+p1b[o0+3]))<<16);
        *(uint2*)(X2 + (size_t)pg*64 + o0) = make_uint2(u0, u1);
        int o1 = o0 + 16;
        uint u2 = (uint)f2b(eluf(acc1[0]+p1b[o1]))   | ((uint)f2b(eluf(acc1[1]+p1b[o1+1]))<<16);
        uint u3 = (uint)f2b(eluf(acc1[2]+p1b[o1+2])) | ((uint)f2b(eluf(acc1[3]+p1b[o1+3]))<<16);
        *(uint2*)(X2 + (size_t)pg*64 + o1) = make_uint2(u2, u3);
    }
}

// ---------- G3: conv3x3 p2 + residual avg -> cost_out ----------
__global__ __launch_bounds__(256) void g_conv2(
    const ushort* __restrict__ X2, const ushort* __restrict__ A2,
    const float* __restrict__ p2b, const float* __restrict__ C1,
    float* __restrict__ cost_out)
{
    __shared__ ushort sB[3*8*34*8];   // 13 KiB
    int tid = threadIdx.x;
    int wv = tid >> 6, lane = tid & 63;
    int lm = lane & 15, lk = lane >> 4;
    int bid = blockIdx.x;
    int tile = (bid & 7)*96 + (bid >> 3);    // XCD swizzle
    int n0 = tile * 32;
    int b  = n0 / HW;
    int pl = n0 % HW;
    int h  = pl / WW, w0 = pl % WW;

    for (int i = tid; i < 816; i += 256){
        int dh = i / 272, rem2 = i % 272;
        int c16 = rem2 / 34, x = rem2 % 34;
        int hh = h + dh - 1, wx = w0 + x - 1;
        uint4 val = make_uint4(0,0,0,0);
        if (hh >= 0 && hh < HH && wx >= 0 && wx < WW)
            val = *(const uint4*)(X2 + ((size_t)b*HW + (size_t)hh*WW + wx)*64 + c16*8);
        *(uint4*)&sB[((dh*8 + c16)*34 + x)*8] = val;
    }
    __syncthreads();

    int mw = wv & 1, nw = wv >> 1;
    const ushort* Ap = A2 + (size_t)(mw*16 + lm)*576 + lk*8;
    f32x4 acc = {0.f,0.f,0.f,0.f};
    int xb = nw*16 + lm;
    #pragma unroll
    for (int t=0; t<9; ++t){
        int dh = t/3, dw = t%3;
        #pragma unroll
        for (int c0=0; c0<64; c0+=32){
            bf16x8 bb = *(const bf16x8*)&sB[((dh*8 + (c0>>3)+lk)*34 + xb + dw)*8];
            bf16x8 a  = *(const bf16x8*)(Ap + t*64 + c0);
            acc = __builtin_amdgcn_mfma_f32_16x16x32_bf16(a, bb, acc, 0,0,0);
        }
    }
    int pg = n0 + nw*16 + lm;
    int pll = pg % HW;
    int o = mw*16 + lk*4;
    f32x4 cv = *(const f32x4*)(C1 + (size_t)pg*DD + o);
    #pragma unroll
    for (int j=0;j<4;++j)
        cost_out[((size_t)(b*DD + o + j))*HW + pll] = (cv[j] + acc[j] + p2b[o+j]) * 0.5f;
}

// ---------- softmax over D -> NC (bf16 pixel-major) ----------
__global__ __launch_bounds__(256) void k_sm2(
    const float* __restrict__ cost_out, ushort* __restrict__ NC)
{
    int n = blockIdx.x*256 + threadIdx.x;   // 24576
    int b = n / HW, pl = n % HW;
    const float* cp = cost_out + (size_t)b*DD*HW + pl;
    float v[DD]; float m = -1e30f;
    #pragma unroll
    for (int d=0; d<DD; ++d){ v[d] = cp[(size_t)d*HW]; m = fmaxf(m, v[d]); }
    float s = 0.f;
    #pragma unroll
    for (int d=0; d<DD; ++d){ v[d] = __expf(v[d]-m); s += v[d]; }
    float inv = 1.f/s;
    ushort* op = NC + (size_t)n*DD;
    #pragma unroll
    for (int d8=0; d8<4; ++d8){
        uint u[4];
        #pragma unroll
        for (int j2=0;j2<4;++j2)
            u[j2] = (uint)f2b(v[d8*8+j2*2]*inv) | ((uint)f2b(v[d8*8+j2*2+1]*inv)<<16);
        uint4 q4; q4.x=u[0]; q4.y=u[1]; q4.z=u[2]; q4.w=u[3];
        *(uint4*)(op + d8*8) = q4;
    }
}

// ---------- G4: final conv1x1, LDS-staged B, ELU ----------
// 768 blocks (XCD-swizzled) x 256 thr; tile = 32 px; stage Tt + NC tiles;
// wave = 4 m-tiles x 2 n-tiles, 72 MFMA
__global__ __launch_bounds__(256) void g_final(
    const ushort* __restrict__ Tt, const ushort* __restrict__ NC,
    const ushort* __restrict__ Ar, const float* __restrict__ rb,
    float* __restrict__ xout)
{
    __shared__ ushort sT[32*264];   // 16.9 KiB
    __shared__ ushort sN[32*40];    // 2.5 KiB (stride 5 chunks)
    int tid = threadIdx.x;
    int bid = blockIdx.x;
    int tile = (bid & 7)*96 + (bid >> 3);
    int p0 = tile * 32;

    for (int i = tid; i < 1024; i += 256){
        int px = i >> 5, c16 = i & 31;
        *(uint4*)&sT[(px*33 + c16)*8] = *(const uint4*)(Tt + ((size_t)(p0+px))*CC + c16*8);
    }
    if (tid < 128){
        int px = tid >> 2, c4 = tid & 3;
        *(uint4*)&sN[(px*5 + c4)*8] = *(const uint4*)(NC + ((size_t)(p0+px))*DD + c4*8);
    }
    __syncthreads();

    int wv = tid >> 6, lane = tid & 63;
    int lm = lane & 15, lk = lane >> 4;
    f32x4 acc[4][2];
    #pragma unroll
    for (int mi=0;mi<4;++mi){ acc[mi][0]=(f32x4){0.f,0.f,0.f,0.f}; acc[mi][1]=(f32x4){0.f,0.f,0.f,0.f}; }
    const ushort* Ap = Ar + (size_t)(wv*64 + lm)*288 + lk*8;

    #pragma unroll
    for (int k0=0; k0<288; k0+=32){
        bf16x8 a[4];
        #pragma unroll
        for (int mi=0;mi<4;++mi) a[mi] = *(const bf16x8*)(Ap + (size_t)mi*16*288 + k0);
        #pragma unroll
        for (int nt=0; nt<2; ++nt){
            int prow = nt*16 + lm;
            bf16x8 bb = (k0 < 256) ? *(const bf16x8*)&sT[(prow*33 + (k0>>3) + lk)*8]
                                   : *(const bf16x8*)&sN[(prow*5 + lk)*8];
            #pragma unroll
            for (int mi=0;mi<4;++mi)
                acc[mi][nt] = __builtin_amdgcn_mfma_f32_16x16x32_bf16(a[mi], bb, acc[mi][nt], 0,0,0);
        }
    }
    #pragma unroll
    for (int mi=0;mi<4;++mi){
        int o = wv*64 + mi*16 + lk*4;
        #pragma unroll
        for (int nt=0; nt<2; ++nt){
            int p = p0 + nt*16 + lm;
            int b = p / HW, pl = p % HW;
            #pragma unroll
            for (int j=0;j<4;++j)
                xout[((size_t)(b*CC + o + j))*HW + pl] = eluf(acc[mi][nt][j] + rb[o+j]);
        }
    }
}

extern "C" void kernel_launch(void* const* d_in, const int* in_sizes, int n_in,
                              void* d_out, int out_size, void* d_ws, size_t ws_size,
                              hipStream_t stream)
{
    const float* t_feat = (const float*)d_in[0];
    const float* s_feat = (const float*)d_in[1];
    const float* directs= (const float*)d_in[2];
    const float* qw = (const float*)d_in[3];
    const float* qb = (const float*)d_in[4];
    const float* kw = (const float*)d_in[5];
    const float* kb = (const float*)d_in[6];
    const float* vw = (const float*)d_in[7];
    const float* vb = (const float*)d_in[8];
    const float* p1w= (const float*)d_in[9];
    const float* p1b= (const float*)d_in[10];
    const float* p2w= (const float*)d_in[11];
    const float* p2b= (const float*)d_in[12];
    const float* rw = (const float*)d_in[13];
    const float* rb = (const float*)d_in[14];
    const int* img_w= (const int*)d_in[15];

    // workspace layout (byte offsets, lifetime-aliased)
    char* wsb = (char*)d_ws;
    ushort* Tt   = (ushort*)(wsb + 0);           // [NPIX][256] bf16
    char*  tsreg = wsb + 12582912;
    ushort* Ts   = (ushort*)tsreg;               // dead after g_qkv
    ushort* X2   = (ushort*)tsreg;               // aliases Ts
    float*  C1   = (float*)(tsreg + 3145728);
    ushort* Agg  = (ushort*)(tsreg + 6291456);
    ushort* X1   = (ushort*)(wsb + 25165824);    // [NPIX][128] bf16 (q | K)
    ushort* Vb   = (ushort*)(wsb + 31457280);    // [NPIX][64] bf16
    ushort* NC   = (ushort*)(wsb + 31457280);    // aliases Vb after k_ca
    ushort* Wqkv = (ushort*)(wsb + 34603008);
    float*  bqkv = (float*) (wsb + 34701312);
    ushort* A1   = (ushort*)(wsb + 34702336);
    ushort* A2   = (ushort*)(wsb + 34849792);
    ushort* Ar   = (ushort*)(wsb + 34886656);    // -> end 35,034,112
    if (ws_size < 35034112) return;

    float* xout     = (float*)d_out;                 // [B,256,H,W] f32
    float* cost_out = xout + (size_t)BB*CC*HW;       // [B,32,H,W] f32

    k_prep_feat<<<768, 256, 0, stream>>>(t_feat, s_feat, Tt, Ts);
    k_prep_w  <<<841,  256, 0, stream>>>(qw,qb,kw,kb,vw,vb,p1w,p2w,rw, Wqkv,bqkv,A1,A2,Ar);
    g_qkv     <<<768,  256, 0, stream>>>(Tt, Ts, Wqkv, bqkv, X1, Vb);
    k_ca      <<<768,  512, 0, stream>>>(X1, Vb, directs, img_w, C1, Agg);
    g_conv1   <<<768,  256, 0, stream>>>(X1, Agg, A1, p1b, X2);
    g_conv2   <<<768,  256, 0, stream>>>(X2, A2, p2b, C1, cost_out);
    k_sm2     <<<96,   256, 0, stream>>>(cost_out, NC);
    g_final   <<<768,  256, 0, stream>>>(Tt, NC, Ar, rb, xout);
}

// Round 10
// 112.944 us; speedup vs baseline: 2.1497x; 1.0044x over previous
//
#include <hip/hip_runtime.h>

#define BB 2
#define CC 256
#define CQ 64
#define DD 32
#define HH 64
#define WW 192
#define HW (HH*WW)     // 12288
#define NPIX (BB*HW)   // 24576

typedef __attribute__((ext_vector_type(8))) short bf16x8;
typedef __attribute__((ext_vector_type(4))) float f32x4;

__device__ __forceinline__ float b2f(ushort s){ return __uint_as_float(((uint)s)<<16); }
__device__ __forceinline__ ushort f2b(float f){
    uint u = __float_as_uint(f);
    return (ushort)((u + 0x7fffu + ((u>>16)&1u)) >> 16);
}
__device__ __forceinline__ float eluf(float v){ return v > 0.f ? v : (__expf(v)-1.f); }

// ---------- prep: f32 NCHW -> bf16 pixel-major via LDS tile transpose ----------
__global__ __launch_bounds__(256) void k_prep_feat(
    const float* __restrict__ t_feat, const float* __restrict__ s_feat,
    ushort* __restrict__ Tt, ushort* __restrict__ Ts)
{
    __shared__ ushort sT[64*264];
    int blk = blockIdx.x;
    int which = blk / 384;
    int rem   = blk % 384;
    int b     = rem / 192;
    int tile  = rem % 192;
    int p0    = tile*64;
    const float* src = which ? s_feat : t_feat;
    ushort* dst      = which ? Ts : Tt;
    int tid = threadIdx.x;

    for (int i = tid; i < 2048; i += 256){
        int px  = i & 63;
        int c16 = i >> 6;
        const float* p = src + ((size_t)(b*CC + c16*8))*HW + p0 + px;
        uint u[4];
        #pragma unroll
        for (int j2=0;j2<4;++j2)
            u[j2] = (uint)f2b(p[(size_t)(2*j2)*HW]) | ((uint)f2b(p[(size_t)(2*j2+1)*HW])<<16);
        uint4 q4; q4.x=u[0]; q4.y=u[1]; q4.z=u[2]; q4.w=u[3];
        *(uint4*)&sT[(px*33 + c16)*8] = q4;
    }
    __syncthreads();
    for (int i = tid; i < 2048; i += 256){
        int c16 = i & 31;
        int px  = i >> 5;
        uint4 v = *(const uint4*)&sT[(px*33 + c16)*8];
        *(uint4*)(dst + ((size_t)(b*HW + p0 + px))*CC + c16*8) = v;
    }
}

// ---------- prep: weights -> bf16 GEMM-A layouts ----------
__global__ __launch_bounds__(256) void k_prep_w(
    const float* __restrict__ qw, const float* __restrict__ qb,
    const float* __restrict__ kw, const float* __restrict__ kb,
    const float* __restrict__ vw, const float* __restrict__ vb,
    const float* __restrict__ p1w, const float* __restrict__ p2w,
    const float* __restrict__ rw,
    ushort* __restrict__ Wqkv, float* __restrict__ bqkv,
    ushort* __restrict__ A1, ushort* __restrict__ A2, ushort* __restrict__ Ar)
{
    int id = blockIdx.x*256 + threadIdx.x;
    if (id < 49152) {
        int o = id / 256, c = id % 256;
        float v = (o<64)? qw[o*256+c] : (o<128)? kw[(o-64)*256+c] : vw[(o-128)*256+c];
        Wqkv[id] = f2b(v);
    } else if (id < 49344) {
        int o = id - 49152;
        bqkv[o] = (o<64)? qb[o] : (o<128)? kb[o-64] : vb[o-128];
    } else if (id < 49344+73728) {
        int i = id - 49344;
        int o = i/1152, r = i%1152, t = r/128, ci = r%128;
        A1[i] = f2b(p1w[(size_t)(o*128+ci)*9 + t]);
    } else if (id < 49344+73728+18432) {
        int i = id - (49344+73728);
        int o = i/576, r = i%576, t = r/64, ci = r%64;
        A2[i] = f2b(p2w[(size_t)(o*64+ci)*9 + t]);
    } else if (id < 49344+73728+18432+73728) {
        int i = id - (49344+73728+18432);
        Ar[i] = f2b(rw[i]);
    }
}

// ---------- G1: qkv conv1x1, LDS-staged B ----------
__global__ __launch_bounds__(256) void g_qkv(
    const ushort* __restrict__ Tt, const ushort* __restrict__ Ts,
    const ushort* __restrict__ Wqkv, const float* __restrict__ bqkv,
    ushort* __restrict__ X1, ushort* __restrict__ Vb)
{
    __shared__ ushort sT[32*264];
    __shared__ ushort sS[32*264];
    int tid = threadIdx.x;
    int bid = blockIdx.x;
    int tile = (bid & 7)*96 + (bid >> 3);
    int p0 = tile * 32;

    for (int i = tid; i < 1024; i += 256){
        int px = i >> 5, c16 = i & 31;
        size_t gsrc = ((size_t)(p0 + px))*CC + c16*8;
        *(uint4*)&sT[(px*33 + c16)*8] = *(const uint4*)(Tt + gsrc);
        *(uint4*)&sS[(px*33 + c16)*8] = *(const uint4*)(Ts + gsrc);
    }
    __syncthreads();

    int wv = tid >> 6, lane = tid & 63;
    int lm = lane & 15, lk = lane >> 4;
    f32x4 acc[3][2];
    #pragma unroll
    for (int g=0;g<3;++g){ acc[g][0]=(f32x4){0.f,0.f,0.f,0.f}; acc[g][1]=(f32x4){0.f,0.f,0.f,0.f}; }
    const ushort* Ap = Wqkv + (size_t)(wv*16 + lm)*CC + lk*8;

    #pragma unroll
    for (int k0=0; k0<CC; k0+=32){
        bf16x8 a0 = *(const bf16x8*)(Ap + k0);
        bf16x8 a1 = *(const bf16x8*)(Ap + 64*CC + k0);
        bf16x8 a2 = *(const bf16x8*)(Ap + 128*CC + k0);
        #pragma unroll
        for (int nt=0; nt<2; ++nt){
            int ch = (nt*16+lm)*33 + (k0>>3) + lk;
            bf16x8 bT = *(const bf16x8*)&sT[ch*8];
            bf16x8 bS = *(const bf16x8*)&sS[ch*8];
            acc[0][nt] = __builtin_amdgcn_mfma_f32_16x16x32_bf16(a0, bT, acc[0][nt], 0,0,0);
            acc[1][nt] = __builtin_amdgcn_mfma_f32_16x16x32_bf16(a1, bS, acc[1][nt], 0,0,0);
            acc[2][nt] = __builtin_amdgcn_mfma_f32_16x16x32_bf16(a2, bS, acc[2][nt], 0,0,0);
        }
    }
    int ol = wv*16 + lk*4;
    #pragma unroll
    for (int g=0;g<3;++g){
        int ob = g*64 + ol;
        #pragma unroll
        for (int nt=0; nt<2; ++nt){
            int p = p0 + nt*16 + lm;
            uint u0 = (uint)f2b(acc[g][nt][0]+bqkv[ob])   | ((uint)f2b(acc[g][nt][1]+bqkv[ob+1])<<16);
            uint u1 = (uint)f2b(acc[g][nt][2]+bqkv[ob+2]) | ((uint)f2b(acc[g][nt][3]+bqkv[ob+3])<<16);
            ushort* dst;
            if (g==0)      dst = X1 + (size_t)p*128 + ol;
            else if (g==1) dst = X1 + (size_t)p*128 + 64 + ol;
            else           dst = Vb + (size_t)p*64 + ol;
            *(uint2*)dst = make_uint2(u0, u1);
        }
    }
}

// ---------- k_ca: MFMA-banded cost + softmax + aggV ----------
// 768 blocks (XCD-swizzled) x 512 thr; 32 px/block; K/V band of 160 px.
// S = Q.K^T (MFMA) -> LDS f32; gather+lerp -> cost, C1; softmax (8 shfl);
// scatter p into band-coeff PC (LDS atomicAdd); agg = PC.V (MFMA).
#define BAND 160
#define SROW 161   // f32 row stride of S / PCf32
#define PROW 168   // ushort row stride of PC bf16
__global__ __launch_bounds__(512) void k_ca(
    const ushort* __restrict__ X1, const ushort* __restrict__ Vb,
    const float* __restrict__ directs, const int* __restrict__ img_w_p,
    float* __restrict__ C1, ushort* __restrict__ Agg)
{
    __shared__ ushort sQ[32*64];        // 4 KiB   (chunk-swizzled)
    __shared__ ushort sK[BAND*64];      // 20 KiB  (chunk-swizzled)
    __shared__ ushort sV[BAND*64];      // 20 KiB  (chunk-swizzled)
    __shared__ float  sS[32*SROW];      // 20.1 KiB (S, then PC-f32)
    __shared__ ushort sPC[32*PROW];     // 10.5 KiB
    int tid = threadIdx.x;
    int j   = blockIdx.x;
    int r8  = j & 7;
    int kk  = j >> 3;
    int sub = kk % 6;
    int rhi = kk / 6;
    int row = rhi*8 + r8;          // b*64 + h
    int b   = row >> 6;
    int h   = row & 63;
    int w0  = sub * 32;
    size_t rowbase = (size_t)b*HW + (size_t)h*WW;

    // ---- stage K/V band [w0-64, w0+95] and Q tile, chunk-swizzled ----
    for (int i = tid; i < BAND*8; i += 512){
        int x = i >> 3, c8 = i & 7;
        int gx = w0 - 64 + x;
        uint4 kv = make_uint4(0,0,0,0), vv = make_uint4(0,0,0,0);
        if (gx >= 0 && gx < WW){
            kv = *(const uint4*)(X1 + (rowbase+gx)*128 + 64 + c8*8);
            vv = *(const uint4*)(Vb + (rowbase+gx)*64 + c8*8);
        }
        int sw = (x*8 + (c8 ^ (x&7)))*8;
        *(uint4*)&sK[sw] = kv;
        *(uint4*)&sV[sw] = vv;
    }
    if (tid < 256){
        int px = tid >> 3, c8 = tid & 7;
        uint4 qv = *(const uint4*)(X1 + (rowbase + w0 + px)*128 + c8*8);
        *(uint4*)&sQ[(px*8 + (c8 ^ (px&7)))*8] = qv;
    }
    __syncthreads();

    int w8 = tid >> 6, lane = tid & 63;
    int lm = lane & 15, lk = lane >> 4;

    // ---- S = Q . K_band^T via MFMA ----
    {
        int mt = w8 & 1;                      // w-tile
        int qrow = mt*16 + lm;
        for (int nt = (w8 >> 1); nt < 10; nt += 4){
            int xrow = nt*16 + lm;
            f32x4 acc = {0.f,0.f,0.f,0.f};
            #pragma unroll
            for (int kt=0; kt<2; ++kt){
                bf16x8 a = *(const bf16x8*)&sQ[(qrow*8 + ((kt*4+lk) ^ (qrow&7)))*8];
                bf16x8 bbf = *(const bf16x8*)&sK[(xrow*8 + ((kt*4+lk) ^ (xrow&7)))*8];
                acc = __builtin_amdgcn_mfma_f32_16x16x32_bf16(a, bbf, acc, 0,0,0);
            }
            #pragma unroll
            for (int jj=0; jj<4; ++jj)
                sS[(mt*16 + lk*4 + jj)*SROW + xrow] = acc[jj];
        }
    }
    __syncthreads();

    // ---- cost gather + C1 write + softmax (per-pixel, 16 lanes x 2 d) ----
    int px  = tid >> 4;
    int l16 = tid & 15;
    int w   = w0 + px;
    size_t n = rowbase + w;
    int imw = img_w_p[0];
    float rel = (imw != 640) ? (640.0f/(float)imw) : 1.0f;
    float sf = 0.01f * rel * directs[b] * 191.0f;
    float wf = (float)w;

    float cost[2]; int xi0[2], xi1[2]; float frk[2];
    #pragma unroll
    for (int t=0; t<2; ++t){
        int d = l16*2 + t;
        float srcx = fminf(fmaxf(wf + (float)d*sf, 0.f), 191.0f);
        int x0 = (int)floorf(srcx);
        int x1 = min(x0+1, WW-1);
        float fr = srcx - (float)x0;
        int i0 = min(max(x0 - w0 + 64, 0), BAND-1);
        int i1 = min(max(x1 - w0 + 64, 0), BAND-1);
        xi0[t] = i0; xi1[t] = i1; frk[t] = fr;
        float s0 = sS[px*SROW + i0];
        float s1 = sS[px*SROW + i1];
        cost[t] = (s0 + fr*(s1-s0)) * 0.125f;
    }
    *(float2*)(C1 + n*DD + l16*2) = make_float2(cost[0], cost[1]);
    float mm = fmaxf(cost[0], cost[1]);
    mm = fmaxf(mm, __shfl_xor(mm, 1));
    mm = fmaxf(mm, __shfl_xor(mm, 2));
    mm = fmaxf(mm, __shfl_xor(mm, 4));
    mm = fmaxf(mm, __shfl_xor(mm, 8));
    float e0 = __expf(cost[0]-mm), e1 = __expf(cost[1]-mm);
    float ss = e0 + e1;
    ss += __shfl_xor(ss, 1);
    ss += __shfl_xor(ss, 2);
    ss += __shfl_xor(ss, 4);
    ss += __shfl_xor(ss, 8);
    float inv = 1.f/ss;
    float p0 = e0*inv, p1 = e1*inv;
    __syncthreads();   // all S reads done

    // ---- zero PC-f32 (reuse sS) ----
    for (int i = tid; i < 32*SROW; i += 512) sS[i] = 0.f;
    __syncthreads();

    // ---- scatter p into band coefficients ----
    {
        float w1a = p0*frk[0], w0a = p0 - w1a;
        float w1b = p1*frk[1], w0b = p1 - w1b;
        atomicAdd(&sS[px*SROW + xi0[0]], w0a);
        atomicAdd(&sS[px*SROW + xi1[0]], w1a);
        atomicAdd(&sS[px*SROW + xi0[1]], w0b);
        atomicAdd(&sS[px*SROW + xi1[1]], w1b);
    }
    __syncthreads();

    // ---- convert PC to bf16 ----
    #pragma unroll
    for (int q=0; q<10; ++q){
        int xi = l16 + q*16;
        sPC[px*PROW + xi] = f2b(sS[px*SROW + xi]);
    }
    __syncthreads();

    // ---- agg = PC . V via MFMA (A = V^T strided, B = PC rows) ----
    {
        int mi = w8 & 3;            // c-tile
        int ni = w8 >> 2;           // w-tile
        int c  = mi*16 + lm;
        int wr = ni*16 + lm;
        f32x4 acc = {0.f,0.f,0.f,0.f};
        for (int kt=0; kt<5; ++kt){
            bf16x8 a;
            #pragma unroll
            for (int jj=0; jj<8; ++jj){
                int x = kt*32 + lk*8 + jj;
                a[jj] = (short)sV[(x*8 + ((c>>3) ^ (x&7)))*8 + (c&7)];
            }
            bf16x8 bbf = *(const bf16x8*)&sPC[wr*PROW + kt*32 + lk*8];
            acc = __builtin_amdgcn_mfma_f32_16x16x32_bf16(a, bbf, acc, 0,0,0);
        }
        uint u0 = (uint)f2b(acc[0]) | ((uint)f2b(acc[1])<<16);
        uint u1 = (uint)f2b(acc[2]) | ((uint)f2b(acc[3])<<16);
        *(uint2*)(Agg + (rowbase + w0 + wr)*64 + mi*16 + lk*4) = make_uint2(u0, u1);
    }
}

// ---------- G2: conv3x3 p1, LDS-staged implicit GEMM, ELU ----------
__global__ __launch_bounds__(256) void g_conv1(
    const ushort* __restrict__ X1, const ushort* __restrict__ Agg,
    const ushort* __restrict__ A1, const float* __restrict__ p1b,
    ushort* __restrict__ X2)
{
    __shared__ ushort sB[3*16*34*8];
    int tid = threadIdx.x;
    int wv = tid >> 6, lane = tid & 63;
    int lm = lane & 15, lk = lane >> 4;
    int bid = blockIdx.x;
    int tile = (bid & 7)*96 + (bid >> 3);
    int n0 = tile * 32;
    int b  = n0 / HW;
    int pl = n0 % HW;
    int h  = pl / WW, w0 = pl % WW;

    for (int i = tid; i < 1632; i += 256){
        int dh = i / 544, rem2 = i % 544;
        int c16 = rem2 / 34, x = rem2 % 34;
        int hh = h + dh - 1, wx = w0 + x - 1;
        uint4 val = make_uint4(0,0,0,0);
        if (hh >= 0 && hh < HH && wx >= 0 && wx < WW){
            size_t pix = (size_t)b*HW + (size_t)hh*WW + wx;
            val = (c16 < 8) ? *(const uint4*)(X1 + pix*128 + c16*8)
                            : *(const uint4*)(Agg + pix*64 + (c16-8)*8);
        }
        *(uint4*)&sB[((dh*16 + c16)*34 + x)*8] = val;
    }
    __syncthreads();

    int mw = wv & 1, nw = wv >> 1;
    const ushort* Ap = A1 + (size_t)(mw*32 + lm)*1152 + lk*8;
    f32x4 acc0 = {0.f,0.f,0.f,0.f}, acc1 = {0.f,0.f,0.f,0.f};
    int xb = nw*16 + lm;
    #pragma unroll
    for (int t=0; t<9; ++t){
        int dh = t/3, dw = t%3;
        #pragma unroll
        for (int c0=0; c0<128; c0+=32){
            bf16x8 bb = *(const bf16x8*)&sB[((dh*16 + (c0>>3)+lk)*34 + xb + dw)*8];
            bf16x8 a0 = *(const bf16x8*)(Ap + t*128 + c0);
            bf16x8 a1 = *(const bf16x8*)(Ap + (size_t)16*1152 + t*128 + c0);
            acc0 = __builtin_amdgcn_mfma_f32_16x16x32_bf16(a0, bb, acc0, 0,0,0);
            acc1 = __builtin_amdgcn_mfma_f32_16x16x32_bf16(a1, bb, acc1, 0,0,0);
        }
    }
    int pg = n0 + nw*16 + lm;
    int o0 = mw*32 + lk*4;
    {
        uint u0 = (uint)f2b(eluf(acc0[0]+p1b[o0]))   | ((uint)f2b(eluf(acc0[1]+p1b[o0+1]))<<16);
        uint u1 = (uint)f2b(eluf(acc0[2]+p1b[o0+2])) | ((uint)f2b(eluf(acc0[3]+p1b[o0+3]))<<16);
        *(uint2*)(X2 + (size_t)pg*64 + o0) = make_uint2(u0, u1);
        int o1 = o0 + 16;
        uint u2 = (uint)f2b(eluf(acc1[0]+p1b[o1]))   | ((uint)f2b(eluf(acc1[1]+p1b[o1+1]))<<16);
        uint u3 = (uint)f2b(eluf(acc1[2]+p1b[o1+2])) | ((uint)f2b(eluf(acc1[3]+p1b[o1+3]))<<16);
        *(uint2*)(X2 + (size_t)pg*64 + o1) = make_uint2(u2, u3);
    }
}

// ---------- G3: conv3x3 p2 + residual avg -> cost_out ----------
__global__ __launch_bounds__(256) void g_conv2(
    const ushort* __restrict__ X2, const ushort* __restrict__ A2,
    const float* __restrict__ p2b, const float* __restrict__ C1,
    float* __restrict__ cost_out)
{
    __shared__ ushort sB[3*8*34*8];
    int tid = threadIdx.x;
    int wv = tid >> 6, lane = tid & 63;
    int lm = lane & 15, lk = lane >> 4;
    int bid = blockIdx.x;
    int tile = (bid & 7)*96 + (bid >> 3);
    int n0 = tile * 32;
    int b  = n0 / HW;
    int pl = n0 % HW;
    int h  = pl / WW, w0 = pl % WW;

    for (int i = tid; i < 816; i += 256){
        int dh = i / 272, rem2 = i % 272;
        int c16 = rem2 / 34, x = rem2 % 34;
        int hh = h + dh - 1, wx = w0 + x - 1;
        uint4 val = make_uint4(0,0,0,0);
        if (hh >= 0 && hh < HH && wx >= 0 && wx < WW)
            val = *(const uint4*)(X2 + ((size_t)b*HW + (size_t)hh*WW + wx)*64 + c16*8);
        *(uint4*)&sB[((dh*8 + c16)*34 + x)*8] = val;
    }
    __syncthreads();

    int mw = wv & 1, nw = wv >> 1;
    const ushort* Ap = A2 + (size_t)(mw*16 + lm)*576 + lk*8;
    f32x4 acc = {0.f,0.f,0.f,0.f};
    int xb = nw*16 + lm;
    #pragma unroll
    for (int t=0; t<9; ++t){
        int dh = t/3, dw = t%3;
        #pragma unroll
        for (int c0=0; c0<64; c0+=32){
            bf16x8 bb = *(const bf16x8*)&sB[((dh*8 + (c0>>3)+lk)*34 + xb + dw)*8];
            bf16x8 a  = *(const bf16x8*)(Ap + t*64 + c0);
            acc = __builtin_amdgcn_mfma_f32_16x16x32_bf16(a, bb, acc, 0,0,0);
        }
    }
    int pg = n0 + nw*16 + lm;
    int pll = pg % HW;
    int o = mw*16 + lk*4;
    f32x4 cv = *(const f32x4*)(C1 + (size_t)pg*DD + o);
    #pragma unroll
    for (int j=0;j<4;++j)
        cost_out[((size_t)(b*DD + o + j))*HW + pll] = (cv[j] + acc[j] + p2b[o+j]) * 0.5f;
}

// ---------- softmax over D -> NC (bf16 pixel-major) ----------
__global__ __launch_bounds__(256) void k_sm2(
    const float* __restrict__ cost_out, ushort* __restrict__ NC)
{
    int n = blockIdx.x*256 + threadIdx.x;
    int b = n / HW, pl = n % HW;
    const float* cp = cost_out + (size_t)b*DD*HW + pl;
    float v[DD]; float m = -1e30f;
    #pragma unroll
    for (int d=0; d<DD; ++d){ v[d] = cp[(size_t)d*HW]; m = fmaxf(m, v[d]); }
    float s = 0.f;
    #pragma unroll
    for (int d=0; d<DD; ++d){ v[d] = __expf(v[d]-m); s += v[d]; }
    float inv = 1.f/s;
    ushort* op = NC + (size_t)n*DD;
    #pragma unroll
    for (int d8=0; d8<4; ++d8){
        uint u[4];
        #pragma unroll
        for (int j2=0;j2<4;++j2)
            u[j2] = (uint)f2b(v[d8*8+j2*2]*inv) | ((uint)f2b(v[d8*8+j2*2+1]*inv)<<16);
        uint4 q4; q4.x=u[0]; q4.y=u[1]; q4.z=u[2]; q4.w=u[3];
        *(uint4*)(op + d8*8) = q4;
    }
}

// ---------- G4: final conv1x1, LDS-staged B, ELU ----------
__global__ __launch_bounds__(256) void g_final(
    const ushort* __restrict__ Tt, const ushort* __restrict__ NC,
    const ushort* __restrict__ Ar, const float* __restrict__ rb,
    float* __restrict__ xout)
{
    __shared__ ushort sT[32*264];
    __shared__ ushort sN[32*40];
    int tid = threadIdx.x;
    int bid = blockIdx.x;
    int tile = (bid & 7)*96 + (bid >> 3);
    int p0 = tile * 32;

    for (int i = tid; i < 1024; i += 256){
        int px = i >> 5, c16 = i & 31;
        *(uint4*)&sT[(px*33 + c16)*8] = *(const uint4*)(Tt + ((size_t)(p0+px))*CC + c16*8);
    }
    if (tid < 128){
        int px = tid >> 2, c4 = tid & 3;
        *(uint4*)&sN[(px*5 + c4)*8] = *(const uint4*)(NC + ((size_t)(p0+px))*DD + c4*8);
    }
    __syncthreads();

    int wv = tid >> 6, lane = tid & 63;
    int lm = lane & 15, lk = lane >> 4;
    f32x4 acc[4][2];
    #pragma unroll
    for (int mi=0;mi<4;++mi){ acc[mi][0]=(f32x4){0.f,0.f,0.f,0.f}; acc[mi][1]=(f32x4){0.f,0.f,0.f,0.f}; }
    const ushort* Ap = Ar + (size_t)(wv*64 + lm)*288 + lk*8;

    #pragma unroll
    for (int k0=0; k0<288; k0+=32){
        bf16x8 a[4];
        #pragma unroll
        for (int mi=0;mi<4;++mi) a[mi] = *(const bf16x8*)(Ap + (size_t)mi*16*288 + k0);
        #pragma unroll
        for (int nt=0; nt<2; ++nt){
            int prow = nt*16 + lm;
            bf16x8 bb = (k0 < 256) ? *(const bf16x8*)&sT[(prow*33 + (k0>>3) + lk)*8]
                                   : *(const bf16x8*)&sN[(prow*5 + lk)*8];
            #pragma unroll
            for (int mi=0;mi<4;++mi)
                acc[mi][nt] = __builtin_amdgcn_mfma_f32_16x16x32_bf16(a[mi], bb, acc[mi][nt], 0,0,0);
        }
    }
    #pragma unroll
    for (int mi=0;mi<4;++mi){
        int o = wv*64 + mi*16 + lk*4;
        #pragma unroll
        for (int nt=0; nt<2; ++nt){
            int p = p0 + nt*16 + lm;
            int b = p / HW, pl = p % HW;
            #pragma unroll
            for (int j=0;j<4;++j)
                xout[((size_t)(b*CC + o + j))*HW + pl] = eluf(acc[mi][nt][j] + rb[o+j]);
        }
    }
}

extern "C" void kernel_launch(void* const* d_in, const int* in_sizes, int n_in,
                              void* d_out, int out_size, void* d_ws, size_t ws_size,
                              hipStream_t stream)
{
    const float* t_feat = (const float*)d_in[0];
    const float* s_feat = (const float*)d_in[1];
    const float* directs= (const float*)d_in[2];
    const float* qw = (const float*)d_in[3];
    const float* qb = (const float*)d_in[4];
    const float* kw = (const float*)d_in[5];
    const float* kb = (const float*)d_in[6];
    const float* vw = (const float*)d_in[7];
    const float* vb = (const float*)d_in[8];
    const float* p1w= (const float*)d_in[9];
    const float* p1b= (const float*)d_in[10];
    const float* p2w= (const float*)d_in[11];
    const float* p2b= (const float*)d_in[12];
    const float* rw = (const float*)d_in[13];
    const float* rb = (const float*)d_in[14];
    const int* img_w= (const int*)d_in[15];

    char* wsb = (char*)d_ws;
    ushort* Tt   = (ushort*)(wsb + 0);
    char*  tsreg = wsb + 12582912;
    ushort* Ts   = (ushort*)tsreg;
    ushort* X2   = (ushort*)tsreg;
    float*  C1   = (float*)(tsreg + 3145728);
    ushort* Agg  = (ushort*)(tsreg + 6291456);
    ushort* X1   = (ushort*)(wsb + 25165824);
    ushort* Vb   = (ushort*)(wsb + 31457280);
    ushort* NC   = (ushort*)(wsb + 31457280);
    ushort* Wqkv = (ushort*)(wsb + 34603008);
    float*  bqkv = (float*) (wsb + 34701312);
    ushort* A1   = (ushort*)(wsb + 34702336);
    ushort* A2   = (ushort*)(wsb + 34849792);
    ushort* Ar   = (ushort*)(wsb + 34886656);
    if (ws_size < 35034112) return;

    float* xout     = (float*)d_out;
    float* cost_out = xout + (size_t)BB*CC*HW;

    k_prep_feat<<<768, 256, 0, stream>>>(t_feat, s_feat, Tt, Ts);
    k_prep_w  <<<841,  256, 0, stream>>>(qw,qb,kw,kb,vw,vb,p1w,p2w,rw, Wqkv,bqkv,A1,A2,Ar);
    g_qkv     <<<768,  256, 0, stream>>>(Tt, Ts, Wqkv, bqkv, X1, Vb);
    k_ca      <<<768,  512, 0, stream>>>(X1, Vb, directs, img_w, C1, Agg);
    g_conv1   <<<768,  256, 0, stream>>>(X1, Agg, A1, p1b, X2);
    g_conv2   <<<768,  256, 0, stream>>>(X2, A2, p2b, C1, cost_out);
    k_sm2     <<<96,   256, 0, stream>>>(cost_out, NC);
    g_final   <<<768,  256, 0, stream>>>(Tt, NC, Ar, rb, xout);
}

// Round 11
// 110.193 us; speedup vs baseline: 2.2033x; 1.0250x over previous
//
#include <hip/hip_runtime.h>

#define BB 2
#define CC 256
#define CQ 64
#define DD 32
#define HH 64
#define WW 192
#define HW (HH*WW)     // 12288
#define NPIX (BB*HW)   // 24576

typedef __attribute__((ext_vector_type(8))) short bf16x8;
typedef __attribute__((ext_vector_type(4))) float f32x4;

__device__ __forceinline__ float b2f(ushort s){ return __uint_as_float(((uint)s)<<16); }
__device__ __forceinline__ ushort f2b(float f){
    uint u = __float_as_uint(f);
    return (ushort)((u + 0x7fffu + ((u>>16)&1u)) >> 16);
}
__device__ __forceinline__ float eluf(float v){ return v > 0.f ? v : (__expf(v)-1.f); }

// ---------- prep: f32 NCHW -> bf16 pixel-major via LDS tile transpose ----------
__global__ __launch_bounds__(256) void k_prep_feat(
    const float* __restrict__ t_feat, const float* __restrict__ s_feat,
    ushort* __restrict__ Tt, ushort* __restrict__ Ts)
{
    __shared__ ushort sT[64*264];
    int blk = blockIdx.x;
    int which = blk / 384;
    int rem   = blk % 384;
    int b     = rem / 192;
    int tile  = rem % 192;
    int p0    = tile*64;
    const float* src = which ? s_feat : t_feat;
    ushort* dst      = which ? Ts : Tt;
    int tid = threadIdx.x;

    for (int i = tid; i < 2048; i += 256){
        int px  = i & 63;
        int c16 = i >> 6;
        const float* p = src + ((size_t)(b*CC + c16*8))*HW + p0 + px;
        uint u[4];
        #pragma unroll
        for (int j2=0;j2<4;++j2)
            u[j2] = (uint)f2b(p[(size_t)(2*j2)*HW]) | ((uint)f2b(p[(size_t)(2*j2+1)*HW])<<16);
        uint4 q4; q4.x=u[0]; q4.y=u[1]; q4.z=u[2]; q4.w=u[3];
        *(uint4*)&sT[(px*33 + c16)*8] = q4;
    }
    __syncthreads();
    for (int i = tid; i < 2048; i += 256){
        int c16 = i & 31;
        int px  = i >> 5;
        uint4 v = *(const uint4*)&sT[(px*33 + c16)*8];
        *(uint4*)(dst + ((size_t)(b*HW + p0 + px))*CC + c16*8) = v;
    }
}

// ---------- prep: weights -> bf16 GEMM-A layouts ----------
__global__ __launch_bounds__(256) void k_prep_w(
    const float* __restrict__ qw, const float* __restrict__ qb,
    const float* __restrict__ kw, const float* __restrict__ kb,
    const float* __restrict__ vw, const float* __restrict__ vb,
    const float* __restrict__ p1w, const float* __restrict__ p2w,
    const float* __restrict__ rw,
    ushort* __restrict__ Wqkv, float* __restrict__ bqkv,
    ushort* __restrict__ A1, ushort* __restrict__ A2, ushort* __restrict__ Ar)
{
    int id = blockIdx.x*256 + threadIdx.x;
    if (id < 49152) {
        int o = id / 256, c = id % 256;
        float v = (o<64)? qw[o*256+c] : (o<128)? kw[(o-64)*256+c] : vw[(o-128)*256+c];
        Wqkv[id] = f2b(v);
    } else if (id < 49344) {
        int o = id - 49152;
        bqkv[o] = (o<64)? qb[o] : (o<128)? kb[o-64] : vb[o-128];
    } else if (id < 49344+73728) {
        int i = id - 49344;
        int o = i/1152, r = i%1152, t = r/128, ci = r%128;
        A1[i] = f2b(p1w[(size_t)(o*128+ci)*9 + t]);
    } else if (id < 49344+73728+18432) {
        int i = id - (49344+73728);
        int o = i/576, r = i%576, t = r/64, ci = r%64;
        A2[i] = f2b(p2w[(size_t)(o*64+ci)*9 + t]);
    } else if (id < 49344+73728+18432+73728) {
        int i = id - (49344+73728+18432);
        Ar[i] = f2b(rw[i]);
    }
}

// ---------- G1: qkv conv1x1, LDS-staged B; V written TRANSPOSED [64][NPIX] ----------
__global__ __launch_bounds__(256) void g_qkv(
    const ushort* __restrict__ Tt, const ushort* __restrict__ Ts,
    const ushort* __restrict__ Wqkv, const float* __restrict__ bqkv,
    ushort* __restrict__ X1, ushort* __restrict__ VbT)
{
    __shared__ ushort sT[32*264];
    __shared__ ushort sS[32*264];
    int tid = threadIdx.x;
    int bid = blockIdx.x;
    int tile = (bid & 7)*96 + (bid >> 3);
    int p0 = tile * 32;

    for (int i = tid; i < 1024; i += 256){
        int px = i >> 5, c16 = i & 31;
        size_t gsrc = ((size_t)(p0 + px))*CC + c16*8;
        *(uint4*)&sT[(px*33 + c16)*8] = *(const uint4*)(Tt + gsrc);
        *(uint4*)&sS[(px*33 + c16)*8] = *(const uint4*)(Ts + gsrc);
    }
    __syncthreads();

    int wv = tid >> 6, lane = tid & 63;
    int lm = lane & 15, lk = lane >> 4;
    f32x4 acc[3][2];
    #pragma unroll
    for (int g=0;g<3;++g){ acc[g][0]=(f32x4){0.f,0.f,0.f,0.f}; acc[g][1]=(f32x4){0.f,0.f,0.f,0.f}; }
    const ushort* Ap = Wqkv + (size_t)(wv*16 + lm)*CC + lk*8;

    #pragma unroll
    for (int k0=0; k0<CC; k0+=32){
        bf16x8 a0 = *(const bf16x8*)(Ap + k0);
        bf16x8 a1 = *(const bf16x8*)(Ap + 64*CC + k0);
        bf16x8 a2 = *(const bf16x8*)(Ap + 128*CC + k0);
        #pragma unroll
        for (int nt=0; nt<2; ++nt){
            int ch = (nt*16+lm)*33 + (k0>>3) + lk;
            bf16x8 bT = *(const bf16x8*)&sT[ch*8];
            bf16x8 bS = *(const bf16x8*)&sS[ch*8];
            acc[0][nt] = __builtin_amdgcn_mfma_f32_16x16x32_bf16(a0, bT, acc[0][nt], 0,0,0);
            acc[1][nt] = __builtin_amdgcn_mfma_f32_16x16x32_bf16(a1, bS, acc[1][nt], 0,0,0);
            acc[2][nt] = __builtin_amdgcn_mfma_f32_16x16x32_bf16(a2, bS, acc[2][nt], 0,0,0);
        }
    }
    int ol = wv*16 + lk*4;
    #pragma unroll
    for (int nt=0; nt<2; ++nt){
        int p = p0 + nt*16 + lm;
        // q
        {
            int ob = ol;
            uint u0 = (uint)f2b(acc[0][nt][0]+bqkv[ob])   | ((uint)f2b(acc[0][nt][1]+bqkv[ob+1])<<16);
            uint u1 = (uint)f2b(acc[0][nt][2]+bqkv[ob+2]) | ((uint)f2b(acc[0][nt][3]+bqkv[ob+3])<<16);
            *(uint2*)(X1 + (size_t)p*128 + ol) = make_uint2(u0, u1);
        }
        // k
        {
            int ob = 64 + ol;
            uint u0 = (uint)f2b(acc[1][nt][0]+bqkv[ob])   | ((uint)f2b(acc[1][nt][1]+bqkv[ob+1])<<16);
            uint u1 = (uint)f2b(acc[1][nt][2]+bqkv[ob+2]) | ((uint)f2b(acc[1][nt][3]+bqkv[ob+3])<<16);
            *(uint2*)(X1 + (size_t)p*128 + 64 + ol) = make_uint2(u0, u1);
        }
        // v -> transposed [c][pixel]
        #pragma unroll
        for (int j=0;j<4;++j)
            VbT[(size_t)(ol+j)*NPIX + p] = f2b(acc[2][nt][j] + bqkv[128 + ol + j]);
    }
}

// ---------- k_ca: MFMA-banded cost + softmax + aggV (vectorized LDS paths) ----------
// 768 blocks (XCD-swizzled) x 512 thr; 32 px/block; K/V band of 160 px.
#define BAND 160
#define VTS 168    // ushort stride of sVT/sPC rows (21 chunks, 21%8=5 -> spread)
#define STS 36     // f32 stride of S^T rows (9 chunks, aligned + spread)
#define PFS 164    // f32 stride of PC-f32 rows
__global__ __launch_bounds__(512) void k_ca(
    const ushort* __restrict__ X1, const ushort* __restrict__ VbT,
    const float* __restrict__ directs, const int* __restrict__ img_w_p,
    float* __restrict__ C1, ushort* __restrict__ Agg)
{
    __shared__ ushort sQ[32*64];        // 4 KiB (chunk-swizzled)
    __shared__ ushort sK[BAND*64];      // 20 KiB (chunk-swizzled)
    __shared__ ushort sVT[64*VTS];      // 21 KiB  [c][x]
    __shared__ float  sF[BAND*STS];     // 23 KiB  S^T [x][qpx]; then PC-f32 [px][PFS]
    __shared__ ushort sPC[32*VTS];      // 10.5 KiB [px][x]
    int tid = threadIdx.x;
    int j   = blockIdx.x;
    int r8  = j & 7;
    int kk  = j >> 3;
    int sub = kk % 6;
    int rhi = kk / 6;
    int row = rhi*8 + r8;          // b*64 + h
    int b   = row >> 6;
    int h   = row & 63;
    int w0  = sub * 32;
    size_t rowbase = (size_t)b*HW + (size_t)h*WW;

    // ---- stage K band (row-major swizzled), VT band (channel-major), Q ----
    for (int i = tid; i < BAND*8; i += 512){
        int x = i >> 3, c8 = i & 7;
        int gx = w0 - 64 + x;
        uint4 kv = make_uint4(0,0,0,0);
        if (gx >= 0 && gx < WW)
            kv = *(const uint4*)(X1 + (rowbase+gx)*128 + 64 + c8*8);
        *(uint4*)&sK[(x*8 + (c8 ^ (x&7)))*8] = kv;
    }
    for (int i = tid; i < 64*20; i += 512){   // 1280: c x 8px-chunk
        int c = i / 20, k2 = i % 20;
        int gx = w0 - 64 + k2*8;
        uint4 vv = make_uint4(0,0,0,0);
        if (gx >= 0 && gx < WW)
            vv = *(const uint4*)(VbT + (size_t)c*NPIX + rowbase + gx);
        *(uint4*)&sVT[c*VTS + k2*8] = vv;
    }
    if (tid < 256){
        int px = tid >> 3, c8 = tid & 7;
        uint4 qv = *(const uint4*)(X1 + (rowbase + w0 + px)*128 + c8*8);
        *(uint4*)&sQ[(px*8 + (c8 ^ (px&7)))*8] = qv;
    }
    __syncthreads();

    int w8 = tid >> 6, lane = tid & 63;
    int lm = lane & 15, lk = lane >> 4;

    // ---- S^T = (Q . K_band^T)^T via MFMA; store [x][qpx] with f32x4 ----
    {
        int mt = w8 & 1;
        int qrow = mt*16 + lm;
        for (int nt = (w8 >> 1); nt < 10; nt += 4){
            int xrow = nt*16 + lm;
            f32x4 acc = {0.f,0.f,0.f,0.f};
            #pragma unroll
            for (int kt=0; kt<2; ++kt){
                bf16x8 a = *(const bf16x8*)&sQ[(qrow*8 + ((kt*4+lk) ^ (qrow&7)))*8];
                bf16x8 bbf = *(const bf16x8*)&sK[(xrow*8 + ((kt*4+lk) ^ (xrow&7)))*8];
                acc = __builtin_amdgcn_mfma_f32_16x16x32_bf16(a, bbf, acc, 0,0,0);
            }
            *(f32x4*)&sF[xrow*STS + mt*16 + lk*4] = acc;
        }
    }
    __syncthreads();

    // ---- cost gather + C1 write + softmax ----
    int px  = tid >> 4;
    int l16 = tid & 15;
    int w   = w0 + px;
    size_t n = rowbase + w;
    int imw = img_w_p[0];
    float rel = (imw != 640) ? (640.0f/(float)imw) : 1.0f;
    float sf = 0.01f * rel * directs[b] * 191.0f;
    float wf = (float)w;

    float cost[2]; int xi0[2], xi1[2]; float frk[2];
    #pragma unroll
    for (int t=0; t<2; ++t){
        int d = l16*2 + t;
        float srcx = fminf(fmaxf(wf + (float)d*sf, 0.f), 191.0f);
        int x0 = (int)floorf(srcx);
        int x1 = min(x0+1, WW-1);
        float fr = srcx - (float)x0;
        int i0 = x0 - w0 + 64;
        int i1 = x1 - w0 + 64;
        xi0[t] = i0; xi1[t] = i1; frk[t] = fr;
        float s0 = sF[i0*STS + px];
        float s1 = sF[i1*STS + px];
        cost[t] = (s0 + fr*(s1-s0)) * 0.125f;
    }
    *(float2*)(C1 + n*DD + l16*2) = make_float2(cost[0], cost[1]);
    float mm = fmaxf(cost[0], cost[1]);
    mm = fmaxf(mm, __shfl_xor(mm, 1));
    mm = fmaxf(mm, __shfl_xor(mm, 2));
    mm = fmaxf(mm, __shfl_xor(mm, 4));
    mm = fmaxf(mm, __shfl_xor(mm, 8));
    float e0 = __expf(cost[0]-mm), e1 = __expf(cost[1]-mm);
    float ss = e0 + e1;
    ss += __shfl_xor(ss, 1);
    ss += __shfl_xor(ss, 2);
    ss += __shfl_xor(ss, 4);
    ss += __shfl_xor(ss, 8);
    float inv = 1.f/ss;
    float p0 = e0*inv, p1 = e1*inv;
    __syncthreads();   // all S reads done

    // ---- zero PC-f32 (reuse sF as [px][PFS]) ----
    for (int i = tid; i < (32*PFS)/4; i += 512)
        *(f32x4*)&sF[i*4] = (f32x4){0.f,0.f,0.f,0.f};
    __syncthreads();

    // ---- scatter p into band coefficients ----
    {
        float w1a = p0*frk[0], w0a = p0 - w1a;
        float w1b = p1*frk[1], w0b = p1 - w1b;
        atomicAdd(&sF[px*PFS + xi0[0]], w0a);
        atomicAdd(&sF[px*PFS + xi1[0]], w1a);
        atomicAdd(&sF[px*PFS + xi0[1]], w0b);
        atomicAdd(&sF[px*PFS + xi1[1]], w1b);
    }
    __syncthreads();

    // ---- convert PC to bf16 (b64 reads, b32 packed writes) ----
    {
        int base = l16*10;   // 10 entries per thread, 160 total per px
        #pragma unroll
        for (int q=0; q<5; ++q){
            float2 v2 = *(const float2*)&sF[px*PFS + base + q*2];
            *(uint*)&sPC[px*VTS + base + q*2] = (uint)f2b(v2.x) | ((uint)f2b(v2.y)<<16);
        }
    }
    __syncthreads();

    // ---- agg = V^T . PC^T via MFMA (A rows = sVT, B rows = sPC, all b128) ----
    {
        int mi = w8 & 3;            // c-tile
        int ni = w8 >> 2;           // px-tile
        int c  = mi*16 + lm;
        int wr = ni*16 + lm;
        f32x4 acc = {0.f,0.f,0.f,0.f};
        #pragma unroll
        for (int kt=0; kt<5; ++kt){
            bf16x8 a   = *(const bf16x8*)&sVT[c*VTS + kt*32 + lk*8];
            bf16x8 bbf = *(const bf16x8*)&sPC[wr*VTS + kt*32 + lk*8];
            acc = __builtin_amdgcn_mfma_f32_16x16x32_bf16(a, bbf, acc, 0,0,0);
        }
        uint u0 = (uint)f2b(acc[0]) | ((uint)f2b(acc[1])<<16);
        uint u1 = (uint)f2b(acc[2]) | ((uint)f2b(acc[3])<<16);
        *(uint2*)(Agg + (rowbase + w0 + wr)*64 + mi*16 + lk*4) = make_uint2(u0, u1);
    }
}

// ---------- G2: conv3x3 p1, LDS-staged implicit GEMM, ELU ----------
__global__ __launch_bounds__(256) void g_conv1(
    const ushort* __restrict__ X1, const ushort* __restrict__ Agg,
    const ushort* __restrict__ A1, const float* __restrict__ p1b,
    ushort* __restrict__ X2)
{
    __shared__ ushort sB[3*16*34*8];
    int tid = threadIdx.x;
    int wv = tid >> 6, lane = tid & 63;
    int lm = lane & 15, lk = lane >> 4;
    int bid = blockIdx.x;
    int tile = (bid & 7)*96 + (bid >> 3);
    int n0 = tile * 32;
    int b  = n0 / HW;
    int pl = n0 % HW;
    int h  = pl / WW, w0 = pl % WW;

    for (int i = tid; i < 1632; i += 256){
        int dh = i / 544, rem2 = i % 544;
        int c16 = rem2 / 34, x = rem2 % 34;
        int hh = h + dh - 1, wx = w0 + x - 1;
        uint4 val = make_uint4(0,0,0,0);
        if (hh >= 0 && hh < HH && wx >= 0 && wx < WW){
            size_t pix = (size_t)b*HW + (size_t)hh*WW + wx;
            val = (c16 < 8) ? *(const uint4*)(X1 + pix*128 + c16*8)
                            : *(const uint4*)(Agg + pix*64 + (c16-8)*8);
        }
        *(uint4*)&sB[((dh*16 + c16)*34 + x)*8] = val;
    }
    __syncthreads();

    int mw = wv & 1, nw = wv >> 1;
    const ushort* Ap = A1 + (size_t)(mw*32 + lm)*1152 + lk*8;
    f32x4 acc0 = {0.f,0.f,0.f,0.f}, acc1 = {0.f,0.f,0.f,0.f};
    int xb = nw*16 + lm;
    #pragma unroll
    for (int t=0; t<9; ++t){
        int dh = t/3, dw = t%3;
        #pragma unroll
        for (int c0=0; c0<128; c0+=32){
            bf16x8 bb = *(const bf16x8*)&sB[((dh*16 + (c0>>3)+lk)*34 + xb + dw)*8];
            bf16x8 a0 = *(const bf16x8*)(Ap + t*128 + c0);
            bf16x8 a1 = *(const bf16x8*)(Ap + (size_t)16*1152 + t*128 + c0);
            acc0 = __builtin_amdgcn_mfma_f32_16x16x32_bf16(a0, bb, acc0, 0,0,0);
            acc1 = __builtin_amdgcn_mfma_f32_16x16x32_bf16(a1, bb, acc1, 0,0,0);
        }
    }
    int pg = n0 + nw*16 + lm;
    int o0 = mw*32 + lk*4;
    {
        uint u0 = (uint)f2b(eluf(acc0[0]+p1b[o0]))   | ((uint)f2b(eluf(acc0[1]+p1b[o0+1]))<<16);
        uint u1 = (uint)f2b(eluf(acc0[2]+p1b[o0+2])) | ((uint)f2b(eluf(acc0[3]+p1b[o0+3]))<<16);
        *(uint2*)(X2 + (size_t)pg*64 + o0) = make_uint2(u0, u1);
        int o1 = o0 + 16;
        uint u2 = (uint)f2b(eluf(acc1[0]+p1b[o1]))   | ((uint)f2b(eluf(acc1[1]+p1b[o1+1]))<<16);
        uint u3 = (uint)f2b(eluf(acc1[2]+p1b[o1+2])) | ((uint)f2b(eluf(acc1[3]+p1b[o1+3]))<<16);
        *(uint2*)(X2 + (size_t)pg*64 + o1) = make_uint2(u2, u3);
    }
}

// ---------- G3: conv3x3 p2 + residual avg -> cost_out AND fused softmax -> NC ----------
__global__ __launch_bounds__(256) void g_conv2(
    const ushort* __restrict__ X2, const ushort* __restrict__ A2,
    const float* __restrict__ p2b, const float* __restrict__ C1,
    float* __restrict__ cost_out, ushort* __restrict__ NC)
{
    __shared__ ushort sB[3*8*34*8];   // 13 KiB
    __shared__ float  sO[32*36];      // 4.5 KiB [px-local][d]
    int tid = threadIdx.x;
    int wv = tid >> 6, lane = tid & 63;
    int lm = lane & 15, lk = lane >> 4;
    int bid = blockIdx.x;
    int tile = (bid & 7)*96 + (bid >> 3);
    int n0 = tile * 32;
    int b  = n0 / HW;
    int pl = n0 % HW;
    int h  = pl / WW, w0 = pl % WW;

    for (int i = tid; i < 816; i += 256){
        int dh = i / 272, rem2 = i % 272;
        int c16 = rem2 / 34, x = rem2 % 34;
        int hh = h + dh - 1, wx = w0 + x - 1;
        uint4 val = make_uint4(0,0,0,0);
        if (hh >= 0 && hh < HH && wx >= 0 && wx < WW)
            val = *(const uint4*)(X2 + ((size_t)b*HW + (size_t)hh*WW + wx)*64 + c16*8);
        *(uint4*)&sB[((dh*8 + c16)*34 + x)*8] = val;
    }
    __syncthreads();

    int mw = wv & 1, nw = wv >> 1;
    const ushort* Ap = A2 + (size_t)(mw*16 + lm)*576 + lk*8;
    f32x4 acc = {0.f,0.f,0.f,0.f};
    int xb = nw*16 + lm;
    #pragma unroll
    for (int t=0; t<9; ++t){
        int dh = t/3, dw = t%3;
        #pragma unroll
        for (int c0=0; c0<64; c0+=32){
            bf16x8 bb = *(const bf16x8*)&sB[((dh*8 + (c0>>3)+lk)*34 + xb + dw)*8];
            bf16x8 a  = *(const bf16x8*)(Ap + t*64 + c0);
            acc = __builtin_amdgcn_mfma_f32_16x16x32_bf16(a, bb, acc, 0,0,0);
        }
    }
    int pg = n0 + nw*16 + lm;
    int pll = pg % HW;
    int o = mw*16 + lk*4;
    f32x4 cv = *(const f32x4*)(C1 + (size_t)pg*DD + o);
    f32x4 outv;
    #pragma unroll
    for (int j=0;j<4;++j){
        outv[j] = (cv[j] + acc[j] + p2b[o+j]) * 0.5f;
        cost_out[((size_t)(b*DD + o + j))*HW + pll] = outv[j];
    }
    *(f32x4*)&sO[(nw*16 + lm)*36 + o] = outv;
    __syncthreads();

    // fused softmax over d: 8 threads per pixel
    {
        int px = tid >> 3;         // 0..31
        int g  = tid & 7;          // d-quad
        f32x4 v = *(const f32x4*)&sO[px*36 + g*4];
        float m = fmaxf(fmaxf(v[0],v[1]), fmaxf(v[2],v[3]));
        m = fmaxf(m, __shfl_xor(m, 1));
        m = fmaxf(m, __shfl_xor(m, 2));
        m = fmaxf(m, __shfl_xor(m, 4));
        float e[4]; float s = 0.f;
        #pragma unroll
        for (int j=0;j<4;++j){ e[j] = __expf(v[j]-m); s += e[j]; }
        s += __shfl_xor(s, 1);
        s += __shfl_xor(s, 2);
        s += __shfl_xor(s, 4);
        float invs = 1.f/s;
        uint u0 = (uint)f2b(e[0]*invs) | ((uint)f2b(e[1]*invs)<<16);
        uint u1 = (uint)f2b(e[2]*invs) | ((uint)f2b(e[3]*invs)<<16);
        *(uint2*)(NC + (size_t)(n0 + px)*DD + g*4) = make_uint2(u0, u1);
    }
}

// ---------- G4: final conv1x1, LDS-staged B, ELU ----------
__global__ __launch_bounds__(256) void g_final(
    const ushort* __restrict__ Tt, const ushort* __restrict__ NC,
    const ushort* __restrict__ Ar, const float* __restrict__ rb,
    float* __restrict__ xout)
{
    __shared__ ushort sT[32*264];
    __shared__ ushort sN[32*40];
    int tid = threadIdx.x;
    int bid = blockIdx.x;
    int tile = (bid & 7)*96 + (bid >> 3);
    int p0 = tile * 32;

    for (int i = tid; i < 1024; i += 256){
        int px = i >> 5, c16 = i & 31;
        *(uint4*)&sT[(px*33 + c16)*8] = *(const uint4*)(Tt + ((size_t)(p0+px))*CC + c16*8);
    }
    if (tid < 128){
        int px = tid >> 2, c4 = tid & 3;
        *(uint4*)&sN[(px*5 + c4)*8] = *(const uint4*)(NC + ((size_t)(p0+px))*DD + c4*8);
    }
    __syncthreads();

    int wv = tid >> 6, lane = tid & 63;
    int lm = lane & 15, lk = lane >> 4;
    f32x4 acc[4][2];
    #pragma unroll
    for (int mi=0;mi<4;++mi){ acc[mi][0]=(f32x4){0.f,0.f,0.f,0.f}; acc[mi][1]=(f32x4){0.f,0.f,0.f,0.f}; }
    const ushort* Ap = Ar + (size_t)(wv*64 + lm)*288 + lk*8;

    #pragma unroll
    for (int k0=0; k0<288; k0+=32){
        bf16x8 a[4];
        #pragma unroll
        for (int mi=0;mi<4;++mi) a[mi] = *(const bf16x8*)(Ap + (size_t)mi*16*288 + k0);
        #pragma unroll
        for (int nt=0; nt<2; ++nt){
            int prow = nt*16 + lm;
            bf16x8 bb = (k0 < 256) ? *(const bf16x8*)&sT[(prow*33 + (k0>>3) + lk)*8]
                                   : *(const bf16x8*)&sN[(prow*5 + lk)*8];
            #pragma unroll
            for (int mi=0;mi<4;++mi)
                acc[mi][nt] = __builtin_amdgcn_mfma_f32_16x16x32_bf16(a[mi], bb, acc[mi][nt], 0,0,0);
        }
    }
    #pragma unroll
    for (int mi=0;mi<4;++mi){
        int o = wv*64 + mi*16 + lk*4;
        #pragma unroll
        for (int nt=0; nt<2; ++nt){
            int p = p0 + nt*16 + lm;
            int b = p / HW, pl = p % HW;
            #pragma unroll
            for (int j=0;j<4;++j)
                xout[((size_t)(b*CC + o + j))*HW + pl] = eluf(acc[mi][nt][j] + rb[o+j]);
        }
    }
}

extern "C" void kernel_launch(void* const* d_in, const int* in_sizes, int n_in,
                              void* d_out, int out_size, void* d_ws, size_t ws_size,
                              hipStream_t stream)
{
    const float* t_feat = (const float*)d_in[0];
    const float* s_feat = (const float*)d_in[1];
    const float* directs= (const float*)d_in[2];
    const float* qw = (const float*)d_in[3];
    const float* qb = (const float*)d_in[4];
    const float* kw = (const float*)d_in[5];
    const float* kb = (const float*)d_in[6];
    const float* vw = (const float*)d_in[7];
    const float* vb = (const float*)d_in[8];
    const float* p1w= (const float*)d_in[9];
    const float* p1b= (const float*)d_in[10];
    const float* p2w= (const float*)d_in[11];
    const float* p2b= (const float*)d_in[12];
    const float* rw = (const float*)d_in[13];
    const float* rb = (const float*)d_in[14];
    const int* img_w= (const int*)d_in[15];

    char* wsb = (char*)d_ws;
    ushort* Tt   = (ushort*)(wsb + 0);           // [NPIX][256] bf16
    char*  tsreg = wsb + 12582912;
    ushort* Ts   = (ushort*)tsreg;               // dead after g_qkv
    ushort* X2   = (ushort*)tsreg;               // aliases Ts
    float*  C1   = (float*)(tsreg + 3145728);
    ushort* Agg  = (ushort*)(tsreg + 6291456);
    ushort* X1   = (ushort*)(wsb + 25165824);    // [NPIX][128] bf16 (q | K)
    ushort* VbT  = (ushort*)(wsb + 31457280);    // [64][NPIX] bf16 (V transposed)
    ushort* NC   = (ushort*)(wsb + 31457280);    // aliases VbT after k_ca
    ushort* Wqkv = (ushort*)(wsb + 34603008);
    float*  bqkv = (float*) (wsb + 34701312);
    ushort* A1   = (ushort*)(wsb + 34702336);
    ushort* A2   = (ushort*)(wsb + 34849792);
    ushort* Ar   = (ushort*)(wsb + 34886656);    // -> end 35,034,112
    if (ws_size < 35034112) return;

    float* xout     = (float*)d_out;                 // [B,256,H,W] f32
    float* cost_out = xout + (size_t)BB*CC*HW;       // [B,32,H,W] f32

    k_prep_feat<<<768, 256, 0, stream>>>(t_feat, s_feat, Tt, Ts);
    k_prep_w  <<<841,  256, 0, stream>>>(qw,qb,kw,kb,vw,vb,p1w,p2w,rw, Wqkv,bqkv,A1,A2,Ar);
    g_qkv     <<<768,  256, 0, stream>>>(Tt, Ts, Wqkv, bqkv, X1, VbT);
    k_ca      <<<768,  512, 0, stream>>>(X1, VbT, directs, img_w, C1, Agg);
    g_conv1   <<<768,  256, 0, stream>>>(X1, Agg, A1, p1b, X2);
    g_conv2   <<<768,  256, 0, stream>>>(X2, A2, p2b, C1, cost_out, NC);
    g_final   <<<768,  256, 0, stream>>>(Tt, NC, Ar, rb, xout);
}

// Round 12
// 104.020 us; speedup vs baseline: 2.3341x; 1.0593x over previous
//
#include <hip/hip_runtime.h>

#define BB 2
#define CC 256
#define CQ 64
#define DD 32
#define HH 64
#define WW 192
#define HW (HH*WW)     // 12288
#define NPIX (BB*HW)   // 24576

typedef __attribute__((ext_vector_type(8))) short bf16x8;
typedef __attribute__((ext_vector_type(4))) float f32x4;

__device__ __forceinline__ float b2f(ushort s){ return __uint_as_float(((uint)s)<<16); }
__device__ __forceinline__ ushort f2b(float f){
    uint u = __float_as_uint(f);
    return (ushort)((u + 0x7fffu + ((u>>16)&1u)) >> 16);
}
__device__ __forceinline__ float eluf(float v){ return v > 0.f ? v : (__expf(v)-1.f); }

// ---------- prep (fused): feat transpose (blocks 0..767) + weights (768..1608) ----------
__global__ __launch_bounds__(256) void k_prep(
    const float* __restrict__ t_feat, const float* __restrict__ s_feat,
    ushort* __restrict__ Tt, ushort* __restrict__ Ts,
    const float* __restrict__ qw, const float* __restrict__ qb,
    const float* __restrict__ kw, const float* __restrict__ kb,
    const float* __restrict__ vw, const float* __restrict__ vb,
    const float* __restrict__ p1w, const float* __restrict__ p2w,
    const float* __restrict__ rw,
    ushort* __restrict__ Wqkv, float* __restrict__ bqkv,
    ushort* __restrict__ A1, ushort* __restrict__ A2, ushort* __restrict__ Ar)
{
    __shared__ ushort sT[64*264];
    int blk = blockIdx.x;
    int tid = threadIdx.x;
    if (blk >= 768){                       // ---- weight prep path ----
        int id = (blk - 768)*256 + tid;
        if (id < 49152) {
            int o = id / 256, c = id % 256;
            float v = (o<64)? qw[o*256+c] : (o<128)? kw[(o-64)*256+c] : vw[(o-128)*256+c];
            Wqkv[id] = f2b(v);
        } else if (id < 49344) {
            int o = id - 49152;
            bqkv[o] = (o<64)? qb[o] : (o<128)? kb[o-64] : vb[o-128];
        } else if (id < 49344+73728) {
            int i = id - 49344;
            int o = i/1152, r = i%1152, t = r/128, ci = r%128;
            A1[i] = f2b(p1w[(size_t)(o*128+ci)*9 + t]);
        } else if (id < 49344+73728+18432) {
            int i = id - (49344+73728);
            int o = i/576, r = i%576, t = r/64, ci = r%64;
            A2[i] = f2b(p2w[(size_t)(o*64+ci)*9 + t]);
        } else if (id < 49344+73728+18432+73728) {
            int i = id - (49344+73728+18432);
            Ar[i] = f2b(rw[i]);
        }
        return;
    }
    // ---- feature transpose path ----
    int which = blk / 384;
    int rem   = blk % 384;
    int b     = rem / 192;
    int tile  = rem % 192;
    int p0    = tile*64;
    const float* src = which ? s_feat : t_feat;
    ushort* dst      = which ? Ts : Tt;

    for (int i = tid; i < 2048; i += 256){
        int px  = i & 63;
        int c16 = i >> 6;
        const float* p = src + ((size_t)(b*CC + c16*8))*HW + p0 + px;
        uint u[4];
        #pragma unroll
        for (int j2=0;j2<4;++j2)
            u[j2] = (uint)f2b(p[(size_t)(2*j2)*HW]) | ((uint)f2b(p[(size_t)(2*j2+1)*HW])<<16);
        uint4 q4; q4.x=u[0]; q4.y=u[1]; q4.z=u[2]; q4.w=u[3];
        *(uint4*)&sT[(px*33 + c16)*8] = q4;
    }
    __syncthreads();
    for (int i = tid; i < 2048; i += 256){
        int c16 = i & 31;
        int px  = i >> 5;
        uint4 v = *(const uint4*)&sT[(px*33 + c16)*8];
        *(uint4*)(dst + ((size_t)(b*HW + p0 + px))*CC + c16*8) = v;
    }
}

// ---------- G1: qkv conv1x1, LDS-staged B; V written TRANSPOSED [64][NPIX] ----------
__global__ __launch_bounds__(256) void g_qkv(
    const ushort* __restrict__ Tt, const ushort* __restrict__ Ts,
    const ushort* __restrict__ Wqkv, const float* __restrict__ bqkv,
    ushort* __restrict__ X1, ushort* __restrict__ VbT)
{
    __shared__ ushort sT[32*264];
    __shared__ ushort sS[32*264];
    int tid = threadIdx.x;
    int bid = blockIdx.x;
    int tile = (bid & 7)*96 + (bid >> 3);
    int p0 = tile * 32;

    for (int i = tid; i < 1024; i += 256){
        int px = i >> 5, c16 = i & 31;
        size_t gsrc = ((size_t)(p0 + px))*CC + c16*8;
        *(uint4*)&sT[(px*33 + c16)*8] = *(const uint4*)(Tt + gsrc);
        *(uint4*)&sS[(px*33 + c16)*8] = *(const uint4*)(Ts + gsrc);
    }
    __syncthreads();

    int wv = tid >> 6, lane = tid & 63;
    int lm = lane & 15, lk = lane >> 4;
    f32x4 acc[3][2];
    #pragma unroll
    for (int g=0;g<3;++g){ acc[g][0]=(f32x4){0.f,0.f,0.f,0.f}; acc[g][1]=(f32x4){0.f,0.f,0.f,0.f}; }
    const ushort* Ap = Wqkv + (size_t)(wv*16 + lm)*CC + lk*8;

    #pragma unroll
    for (int k0=0; k0<CC; k0+=32){
        bf16x8 a0 = *(const bf16x8*)(Ap + k0);
        bf16x8 a1 = *(const bf16x8*)(Ap + 64*CC + k0);
        bf16x8 a2 = *(const bf16x8*)(Ap + 128*CC + k0);
        #pragma unroll
        for (int nt=0; nt<2; ++nt){
            int ch = (nt*16+lm)*33 + (k0>>3) + lk;
            bf16x8 bT = *(const bf16x8*)&sT[ch*8];
            bf16x8 bS = *(const bf16x8*)&sS[ch*8];
            acc[0][nt] = __builtin_amdgcn_mfma_f32_16x16x32_bf16(a0, bT, acc[0][nt], 0,0,0);
            acc[1][nt] = __builtin_amdgcn_mfma_f32_16x16x32_bf16(a1, bS, acc[1][nt], 0,0,0);
            acc[2][nt] = __builtin_amdgcn_mfma_f32_16x16x32_bf16(a2, bS, acc[2][nt], 0,0,0);
        }
    }
    int ol = wv*16 + lk*4;
    #pragma unroll
    for (int nt=0; nt<2; ++nt){
        int p = p0 + nt*16 + lm;
        {
            int ob = ol;
            uint u0 = (uint)f2b(acc[0][nt][0]+bqkv[ob])   | ((uint)f2b(acc[0][nt][1]+bqkv[ob+1])<<16);
            uint u1 = (uint)f2b(acc[0][nt][2]+bqkv[ob+2]) | ((uint)f2b(acc[0][nt][3]+bqkv[ob+3])<<16);
            *(uint2*)(X1 + (size_t)p*128 + ol) = make_uint2(u0, u1);
        }
        {
            int ob = 64 + ol;
            uint u0 = (uint)f2b(acc[1][nt][0]+bqkv[ob])   | ((uint)f2b(acc[1][nt][1]+bqkv[ob+1])<<16);
            uint u1 = (uint)f2b(acc[1][nt][2]+bqkv[ob+2]) | ((uint)f2b(acc[1][nt][3]+bqkv[ob+3])<<16);
            *(uint2*)(X1 + (size_t)p*128 + 64 + ol) = make_uint2(u0, u1);
        }
        #pragma unroll
        for (int j=0;j<4;++j)
            VbT[(size_t)(ol+j)*NPIX + p] = f2b(acc[2][nt][j] + bqkv[128 + ol + j]);
    }
}

// ---------- k_ca: MFMA-banded cost + softmax + aggV, de-staged ----------
// 768 blocks (XCD-swizzled) x 512 thr; 32 px/block; band of 160 px.
// S/PV MFMA fragments read DIRECTLY from global (L2-hot, per-lane 16B);
// LDS only for S^T + scatter buffers -> 33.8 KB -> 4 blocks/CU.
#define BAND 160
#define STS 36     // f32 stride of S^T rows
#define PFS 164    // f32 stride of PC-f32 rows (reuses sF)
#define VTS 168    // ushort stride of sPC rows
__global__ __launch_bounds__(512) void k_ca(
    const ushort* __restrict__ X1, const ushort* __restrict__ VbT,
    const float* __restrict__ directs, const int* __restrict__ img_w_p,
    float* __restrict__ C1, ushort* __restrict__ Agg)
{
    __shared__ float  sF[BAND*STS];     // 22.5 KiB: S^T [x][qpx], then PC-f32 [px][PFS]
    __shared__ ushort sPC[32*VTS];      // 10.5 KiB [px][x]
    int tid = threadIdx.x;
    int j   = blockIdx.x;
    int r8  = j & 7;
    int kk  = j >> 3;
    int sub = kk % 6;
    int rhi = kk / 6;
    int row = rhi*8 + r8;          // b*64 + h
    int b   = row >> 6;
    int h   = row & 63;
    int w0  = sub * 32;
    size_t rowbase = (size_t)b*HW + (size_t)h*WW;

    int w8 = tid >> 6, lane = tid & 63;
    int lm = lane & 15, lk = lane >> 4;

    // ---- S^T = (Q . K_band^T)^T via MFMA; fragments direct from global ----
    {
        int mt = w8 & 1;
        int q  = w0 + mt*16 + lm;
        const ushort* Qp = X1 + (rowbase + q)*128 + lk*8;
        bf16x8 aq0 = *(const bf16x8*)(Qp);
        bf16x8 aq1 = *(const bf16x8*)(Qp + 32);
        for (int nt = (w8 >> 1); nt < 10; nt += 4){
            int xrow = nt*16 + lm;
            int gx = w0 - 64 + xrow;
            bf16x8 b0 = {0,0,0,0,0,0,0,0}, b1 = {0,0,0,0,0,0,0,0};
            if (gx >= 0 && gx < WW){
                const ushort* Kp = X1 + (rowbase + gx)*128 + 64 + lk*8;
                b0 = *(const bf16x8*)(Kp);
                b1 = *(const bf16x8*)(Kp + 32);
            }
            f32x4 acc = {0.f,0.f,0.f,0.f};
            acc = __builtin_amdgcn_mfma_f32_16x16x32_bf16(aq0, b0, acc, 0,0,0);
            acc = __builtin_amdgcn_mfma_f32_16x16x32_bf16(aq1, b1, acc, 0,0,0);
            *(f32x4*)&sF[xrow*STS + mt*16 + lk*4] = acc;
        }
    }
    __syncthreads();

    // ---- cost gather + C1 write + softmax ----
    int px  = tid >> 4;
    int l16 = tid & 15;
    int w   = w0 + px;
    size_t n = rowbase + w;
    int imw = img_w_p[0];
    float rel = (imw != 640) ? (640.0f/(float)imw) : 1.0f;
    float sf = 0.01f * rel * directs[b] * 191.0f;
    float wf = (float)w;

    float cost[2]; int xi0[2], xi1[2]; float frk[2];
    #pragma unroll
    for (int t=0; t<2; ++t){
        int d = l16*2 + t;
        float srcx = fminf(fmaxf(wf + (float)d*sf, 0.f), 191.0f);
        int x0 = (int)floorf(srcx);
        int x1 = min(x0+1, WW-1);
        float fr = srcx - (float)x0;
        int i0 = x0 - w0 + 64;
        int i1 = x1 - w0 + 64;
        xi0[t] = i0; xi1[t] = i1; frk[t] = fr;
        float s0 = sF[i0*STS + px];
        float s1 = sF[i1*STS + px];
        cost[t] = (s0 + fr*(s1-s0)) * 0.125f;
    }
    *(float2*)(C1 + n*DD + l16*2) = make_float2(cost[0], cost[1]);
    float mm = fmaxf(cost[0], cost[1]);
    mm = fmaxf(mm, __shfl_xor(mm, 1));
    mm = fmaxf(mm, __shfl_xor(mm, 2));
    mm = fmaxf(mm, __shfl_xor(mm, 4));
    mm = fmaxf(mm, __shfl_xor(mm, 8));
    float e0 = __expf(cost[0]-mm), e1 = __expf(cost[1]-mm);
    float ss = e0 + e1;
    ss += __shfl_xor(ss, 1);
    ss += __shfl_xor(ss, 2);
    ss += __shfl_xor(ss, 4);
    ss += __shfl_xor(ss, 8);
    float inv = 1.f/ss;
    float p0 = e0*inv, p1 = e1*inv;
    __syncthreads();   // all S reads done

    // ---- zero PC-f32 (reuse sF as [px][PFS]) ----
    for (int i = tid; i < (32*PFS)/4; i += 512)
        *(f32x4*)&sF[i*4] = (f32x4){0.f,0.f,0.f,0.f};
    __syncthreads();

    // ---- scatter p into band coefficients ----
    {
        float w1a = p0*frk[0], w0a = p0 - w1a;
        float w1b = p1*frk[1], w0b = p1 - w1b;
        atomicAdd(&sF[px*PFS + xi0[0]], w0a);
        atomicAdd(&sF[px*PFS + xi1[0]], w1a);
        atomicAdd(&sF[px*PFS + xi0[1]], w0b);
        atomicAdd(&sF[px*PFS + xi1[1]], w1b);
    }
    __syncthreads();

    // ---- convert PC to bf16 ----
    {
        int base = l16*10;
        #pragma unroll
        for (int q=0; q<5; ++q){
            float2 v2 = *(const float2*)&sF[px*PFS + base + q*2];
            *(uint*)&sPC[px*VTS + base + q*2] = (uint)f2b(v2.x) | ((uint)f2b(v2.y)<<16);
        }
    }
    __syncthreads();

    // ---- agg = V^T . PC^T via MFMA (A direct from global VbT, B = sPC) ----
    {
        int mi = w8 & 3;            // c-tile
        int ni = w8 >> 2;           // px-tile
        int c  = mi*16 + lm;
        int wr = ni*16 + lm;
        const ushort* Vp = VbT + (size_t)c*NPIX + rowbase + w0 - 64;
        f32x4 acc = {0.f,0.f,0.f,0.f};
        #pragma unroll
        for (int kt=0; kt<5; ++kt){
            int gx = w0 - 64 + kt*32 + lk*8;
            bf16x8 a = {0,0,0,0,0,0,0,0};
            if (gx >= 0 && gx < WW) a = *(const bf16x8*)(Vp + kt*32 + lk*8);
            bf16x8 bbf = *(const bf16x8*)&sPC[wr*VTS + kt*32 + lk*8];
            acc = __builtin_amdgcn_mfma_f32_16x16x32_bf16(a, bbf, acc, 0,0,0);
        }
        uint u0 = (uint)f2b(acc[0]) | ((uint)f2b(acc[1])<<16);
        uint u1 = (uint)f2b(acc[2]) | ((uint)f2b(acc[3])<<16);
        *(uint2*)(Agg + (rowbase + w0 + wr)*64 + mi*16 + lk*4) = make_uint2(u0, u1);
    }
}

// ---------- G2: conv3x3 p1, LDS-staged implicit GEMM, ELU ----------
__global__ __launch_bounds__(256) void g_conv1(
    const ushort* __restrict__ X1, const ushort* __restrict__ Agg,
    const ushort* __restrict__ A1, const float* __restrict__ p1b,
    ushort* __restrict__ X2)
{
    __shared__ ushort sB[3*16*34*8];
    int tid = threadIdx.x;
    int wv = tid >> 6, lane = tid & 63;
    int lm = lane & 15, lk = lane >> 4;
    int bid = blockIdx.x;
    int tile = (bid & 7)*96 + (bid >> 3);
    int n0 = tile * 32;
    int b  = n0 / HW;
    int pl = n0 % HW;
    int h  = pl / WW, w0 = pl % WW;

    for (int i = tid; i < 1632; i += 256){
        int dh = i / 544, rem2 = i % 544;
        int c16 = rem2 / 34, x = rem2 % 34;
        int hh = h + dh - 1, wx = w0 + x - 1;
        uint4 val = make_uint4(0,0,0,0);
        if (hh >= 0 && hh < HH && wx >= 0 && wx < WW){
            size_t pix = (size_t)b*HW + (size_t)hh*WW + wx;
            val = (c16 < 8) ? *(const uint4*)(X1 + pix*128 + c16*8)
                            : *(const uint4*)(Agg + pix*64 + (c16-8)*8);
        }
        *(uint4*)&sB[((dh*16 + c16)*34 + x)*8] = val;
    }
    __syncthreads();

    int mw = wv & 1, nw = wv >> 1;
    const ushort* Ap = A1 + (size_t)(mw*32 + lm)*1152 + lk*8;
    f32x4 acc0 = {0.f,0.f,0.f,0.f}, acc1 = {0.f,0.f,0.f,0.f};
    int xb = nw*16 + lm;
    #pragma unroll
    for (int t=0; t<9; ++t){
        int dh = t/3, dw = t%3;
        #pragma unroll
        for (int c0=0; c0<128; c0+=32){
            bf16x8 bb = *(const bf16x8*)&sB[((dh*16 + (c0>>3)+lk)*34 + xb + dw)*8];
            bf16x8 a0 = *(const bf16x8*)(Ap + t*128 + c0);
            bf16x8 a1 = *(const bf16x8*)(Ap + (size_t)16*1152 + t*128 + c0);
            acc0 = __builtin_amdgcn_mfma_f32_16x16x32_bf16(a0, bb, acc0, 0,0,0);
            acc1 = __builtin_amdgcn_mfma_f32_16x16x32_bf16(a1, bb, acc1, 0,0,0);
        }
    }
    int pg = n0 + nw*16 + lm;
    int o0 = mw*32 + lk*4;
    {
        uint u0 = (uint)f2b(eluf(acc0[0]+p1b[o0]))   | ((uint)f2b(eluf(acc0[1]+p1b[o0+1]))<<16);
        uint u1 = (uint)f2b(eluf(acc0[2]+p1b[o0+2])) | ((uint)f2b(eluf(acc0[3]+p1b[o0+3]))<<16);
        *(uint2*)(X2 + (size_t)pg*64 + o0) = make_uint2(u0, u1);
        int o1 = o0 + 16;
        uint u2 = (uint)f2b(eluf(acc1[0]+p1b[o1]))   | ((uint)f2b(eluf(acc1[1]+p1b[o1+1]))<<16);
        uint u3 = (uint)f2b(eluf(acc1[2]+p1b[o1+2])) | ((uint)f2b(eluf(acc1[3]+p1b[o1+3]))<<16);
        *(uint2*)(X2 + (size_t)pg*64 + o1) = make_uint2(u2, u3);
    }
}

// ---------- G3+G4 fused: conv3x3 p2 + residual -> cost_out, softmax -> LDS NC,
//            then final conv1x1 on concat(Tt, NC) -> xout ----------
__global__ __launch_bounds__(256) void g_conv2final(
    const ushort* __restrict__ X2, const ushort* __restrict__ A2,
    const float* __restrict__ p2b, const float* __restrict__ C1,
    const ushort* __restrict__ Tt, const ushort* __restrict__ Ar,
    const float* __restrict__ rb,
    float* __restrict__ cost_out, float* __restrict__ xout)
{
    __shared__ ushort sT[32*264];     // 16.5 KiB; first 13 KiB doubles as sB (X2 halo)
    __shared__ float  sO[32*36];      // 4.5 KiB
    __shared__ ushort sN[32*40];      // 2.5 KiB
    ushort* sB = sT;                  // alias: sB dead before sT staged
    int tid = threadIdx.x;
    int wv = tid >> 6, lane = tid & 63;
    int lm = lane & 15, lk = lane >> 4;
    int bid = blockIdx.x;
    int tile = (bid & 7)*96 + (bid >> 3);
    int n0 = tile * 32;
    int b  = n0 / HW;
    int pl = n0 % HW;
    int h  = pl / WW, w0 = pl % WW;

    // phase 1: stage X2 halo
    for (int i = tid; i < 816; i += 256){
        int dh = i / 272, rem2 = i % 272;
        int c16 = rem2 / 34, x = rem2 % 34;
        int hh = h + dh - 1, wx = w0 + x - 1;
        uint4 val = make_uint4(0,0,0,0);
        if (hh >= 0 && hh < HH && wx >= 0 && wx < WW)
            val = *(const uint4*)(X2 + ((size_t)b*HW + (size_t)hh*WW + wx)*64 + c16*8);
        *(uint4*)&sB[((dh*8 + c16)*34 + x)*8] = val;
    }
    __syncthreads();

    // phase 2: conv p2 + residual -> cost_out + sO
    {
        int mw = wv & 1, nw = wv >> 1;
        const ushort* Ap = A2 + (size_t)(mw*16 + lm)*576 + lk*8;
        f32x4 acc = {0.f,0.f,0.f,0.f};
        int xb = nw*16 + lm;
        #pragma unroll
        for (int t=0; t<9; ++t){
            int dh = t/3, dw = t%3;
            #pragma unroll
            for (int c0=0; c0<64; c0+=32){
                bf16x8 bb = *(const bf16x8*)&sB[((dh*8 + (c0>>3)+lk)*34 + xb + dw)*8];
                bf16x8 a  = *(const bf16x8*)(Ap + t*64 + c0);
                acc = __builtin_amdgcn_mfma_f32_16x16x32_bf16(a, bb, acc, 0,0,0);
            }
        }
        int pg = n0 + nw*16 + lm;
        int pll = pg % HW;
        int o = mw*16 + lk*4;
        f32x4 cv = *(const f32x4*)(C1 + (size_t)pg*DD + o);
        f32x4 outv;
        #pragma unroll
        for (int j=0;j<4;++j){
            outv[j] = (cv[j] + acc[j] + p2b[o+j]) * 0.5f;
            cost_out[((size_t)(b*DD + o + j))*HW + pll] = outv[j];
        }
        *(f32x4*)&sO[(nw*16 + lm)*36 + o] = outv;
    }
    __syncthreads();

    // phase 3: softmax -> sN; stage Tt tile -> sT (overwrites dead sB region)
    {
        int px = tid >> 3;
        int g  = tid & 7;
        f32x4 v = *(const f32x4*)&sO[px*36 + g*4];
        float m = fmaxf(fmaxf(v[0],v[1]), fmaxf(v[2],v[3]));
        m = fmaxf(m, __shfl_xor(m, 1));
        m = fmaxf(m, __shfl_xor(m, 2));
        m = fmaxf(m, __shfl_xor(m, 4));
        float e[4]; float s = 0.f;
        #pragma unroll
        for (int j=0;j<4;++j){ e[j] = __expf(v[j]-m); s += e[j]; }
        s += __shfl_xor(s, 1);
        s += __shfl_xor(s, 2);
        s += __shfl_xor(s, 4);
        float invs = 1.f/s;
        uint u0 = (uint)f2b(e[0]*invs) | ((uint)f2b(e[1]*invs)<<16);
        uint u1 = (uint)f2b(e[2]*invs) | ((uint)f2b(e[3]*invs)<<16);
        *(uint2*)&sN[px*40 + g*4] = make_uint2(u0, u1);
    }
    for (int i = tid; i < 1024; i += 256){
        int px = i >> 5, c16 = i & 31;
        *(uint4*)&sT[(px*33 + c16)*8] = *(const uint4*)(Tt + ((size_t)(n0+px))*CC + c16*8);
    }
    __syncthreads();

    // phase 4: final conv1x1 (MFMA) -> xout
    {
        f32x4 acc[4][2];
        #pragma unroll
        for (int mi=0;mi<4;++mi){ acc[mi][0]=(f32x4){0.f,0.f,0.f,0.f}; acc[mi][1]=(f32x4){0.f,0.f,0.f,0.f}; }
        const ushort* Ap = Ar + (size_t)(wv*64 + lm)*288 + lk*8;

        #pragma unroll
        for (int k0=0; k0<288; k0+=32){
            bf16x8 a[4];
            #pragma unroll
            for (int mi=0;mi<4;++mi) a[mi] = *(const bf16x8*)(Ap + (size_t)mi*16*288 + k0);
            #pragma unroll
            for (int nt=0; nt<2; ++nt){
                int prow = nt*16 + lm;
                bf16x8 bb = (k0 < 256) ? *(const bf16x8*)&sT[(prow*33 + (k0>>3) + lk)*8]
                                       : *(const bf16x8*)&sN[(prow*5 + lk)*8];
                #pragma unroll
                for (int mi=0;mi<4;++mi)
                    acc[mi][nt] = __builtin_amdgcn_mfma_f32_16x16x32_bf16(a[mi], bb, acc[mi][nt], 0,0,0);
            }
        }
        #pragma unroll
        for (int mi=0;mi<4;++mi){
            int o = wv*64 + mi*16 + lk*4;
            #pragma unroll
            for (int nt=0; nt<2; ++nt){
                int p = n0 + nt*16 + lm;
                int bb2 = p / HW, pl2 = p % HW;
                #pragma unroll
                for (int j=0;j<4;++j)
                    xout[((size_t)(bb2*CC + o + j))*HW + pl2] = eluf(acc[mi][nt][j] + rb[o+j]);
            }
        }
    }
}

extern "C" void kernel_launch(void* const* d_in, const int* in_sizes, int n_in,
                              void* d_out, int out_size, void* d_ws, size_t ws_size,
                              hipStream_t stream)
{
    const float* t_feat = (const float*)d_in[0];
    const float* s_feat = (const float*)d_in[1];
    const float* directs= (const float*)d_in[2];
    const float* qw = (const float*)d_in[3];
    const float* qb = (const float*)d_in[4];
    const float* kw = (const float*)d_in[5];
    const float* kb = (const float*)d_in[6];
    const float* vw = (const float*)d_in[7];
    const float* vb = (const float*)d_in[8];
    const float* p1w= (const float*)d_in[9];
    const float* p1b= (const float*)d_in[10];
    const float* p2w= (const float*)d_in[11];
    const float* p2b= (const float*)d_in[12];
    const float* rw = (const float*)d_in[13];
    const float* rb = (const float*)d_in[14];
    const int* img_w= (const int*)d_in[15];

    char* wsb = (char*)d_ws;
    ushort* Tt   = (ushort*)(wsb + 0);           // [NPIX][256] bf16
    char*  tsreg = wsb + 12582912;
    ushort* Ts   = (ushort*)tsreg;               // dead after g_qkv
    ushort* X2   = (ushort*)tsreg;               // aliases Ts
    float*  C1   = (float*)(tsreg + 3145728);
    ushort* Agg  = (ushort*)(tsreg + 6291456);
    ushort* X1   = (ushort*)(wsb + 25165824);    // [NPIX][128] bf16 (q | K)
    ushort* VbT  = (ushort*)(wsb + 31457280);    // [64][NPIX] bf16 (V transposed)
    ushort* Wqkv = (ushort*)(wsb + 34603008);
    float*  bqkv = (float*) (wsb + 34701312);
    ushort* A1   = (ushort*)(wsb + 34702336);
    ushort* A2   = (ushort*)(wsb + 34849792);
    ushort* Ar   = (ushort*)(wsb + 34886656);    // -> end 35,034,112
    if (ws_size < 35034112) return;

    float* xout     = (float*)d_out;                 // [B,256,H,W] f32
    float* cost_out = xout + (size_t)BB*CC*HW;       // [B,32,H,W] f32

    k_prep      <<<1609, 256, 0, stream>>>(t_feat, s_feat, Tt, Ts,
                                           qw,qb,kw,kb,vw,vb,p1w,p2w,rw,
                                           Wqkv,bqkv,A1,A2,Ar);
    g_qkv       <<<768,  256, 0, stream>>>(Tt, Ts, Wqkv, bqkv, X1, VbT);
    k_ca        <<<768,  512, 0, stream>>>(X1, VbT, directs, img_w, C1, Agg);
    g_conv1     <<<768,  256, 0, stream>>>(X1, Agg, A1, p1b, X2);
    g_conv2final<<<768,  256, 0, stream>>>(X2, A2, p2b, C1, Tt, Ar, rb,
                                           cost_out, xout);
}

// Round 13
// 96.972 us; speedup vs baseline: 2.5038x; 1.0727x over previous
//
#include <hip/hip_runtime.h>

#define BB 2
#define CC 256
#define CQ 64
#define DD 32
#define HH 64
#define WW 192
#define HW (HH*WW)     // 12288
#define NPIX (BB*HW)   // 24576

typedef __attribute__((ext_vector_type(8))) short bf16x8;
typedef __attribute__((ext_vector_type(4))) float f32x4;

__device__ __forceinline__ float b2f(ushort s){ return __uint_as_float(((uint)s)<<16); }
__device__ __forceinline__ ushort f2b(float f){
    uint u = __float_as_uint(f);
    return (ushort)((u + 0x7fffu + ((u>>16)&1u)) >> 16);
}
__device__ __forceinline__ float eluf(float v){ return v > 0.f ? v : (__expf(v)-1.f); }

// ---------- prep: weights only -> bf16 GEMM-A layouts ----------
__global__ __launch_bounds__(256) void k_prep_w(
    const float* __restrict__ qw, const float* __restrict__ qb,
    const float* __restrict__ kw, const float* __restrict__ kb,
    const float* __restrict__ vw, const float* __restrict__ vb,
    const float* __restrict__ p1w, const float* __restrict__ p2w,
    const float* __restrict__ rw,
    ushort* __restrict__ Wqkv, float* __restrict__ bqkv,
    ushort* __restrict__ A1, ushort* __restrict__ A2, ushort* __restrict__ Ar)
{
    int id = blockIdx.x*256 + threadIdx.x;
    if (id < 49152) {
        int o = id / 256, c = id % 256;
        float v = (o<64)? qw[o*256+c] : (o<128)? kw[(o-64)*256+c] : vw[(o-128)*256+c];
        Wqkv[id] = f2b(v);
    } else if (id < 49344) {
        int o = id - 49152;
        bqkv[o] = (o<64)? qb[o] : (o<128)? kb[o-64] : vb[o-128];
    } else if (id < 49344+73728) {
        int i = id - 49344;
        int o = i/1152, r = i%1152, t = r/128, ci = r%128;
        A1[i] = f2b(p1w[(size_t)(o*128+ci)*9 + t]);
    } else if (id < 49344+73728+18432) {
        int i = id - (49344+73728);
        int o = i/576, r = i%576, t = r/64, ci = r%64;
        A2[i] = f2b(p2w[(size_t)(o*64+ci)*9 + t]);
    } else if (id < 49344+73728+18432+73728) {
        int i = id - (49344+73728+18432);
        Ar[i] = f2b(rw[i]);
    }
}

// ---------- G1: qkv conv1x1; stages DIRECTLY from NCHW f32 (no Tt/Ts) ----------
__global__ __launch_bounds__(256) void g_qkv(
    const float* __restrict__ t_feat, const float* __restrict__ s_feat,
    const ushort* __restrict__ Wqkv, const float* __restrict__ bqkv,
    ushort* __restrict__ X1, ushort* __restrict__ VbT)
{
    __shared__ ushort sT[32*264];
    __shared__ ushort sS[32*264];
    int tid = threadIdx.x;
    int bid = blockIdx.x;
    int tile = (bid & 7)*96 + (bid >> 3);
    int p0 = tile * 32;
    int b0  = p0 / HW;
    int pl0 = p0 % HW;

    for (int i = tid; i < 1024; i += 256){
        int px = i & 31, c8 = i >> 5;      // c8 = 16B chunk (8 channels)
        const float* pt = t_feat + ((size_t)(b0*CC + c8*8))*HW + pl0 + px;
        const float* ps = s_feat + ((size_t)(b0*CC + c8*8))*HW + pl0 + px;
        uint ut[4], us[4];
        #pragma unroll
        for (int j2=0;j2<4;++j2){
            ut[j2] = (uint)f2b(pt[(size_t)(2*j2)*HW]) | ((uint)f2b(pt[(size_t)(2*j2+1)*HW])<<16);
            us[j2] = (uint)f2b(ps[(size_t)(2*j2)*HW]) | ((uint)f2b(ps[(size_t)(2*j2+1)*HW])<<16);
        }
        uint4 qt; qt.x=ut[0]; qt.y=ut[1]; qt.z=ut[2]; qt.w=ut[3];
        uint4 qs; qs.x=us[0]; qs.y=us[1]; qs.z=us[2]; qs.w=us[3];
        *(uint4*)&sT[(px*33 + c8)*8] = qt;
        *(uint4*)&sS[(px*33 + c8)*8] = qs;
    }
    __syncthreads();

    int wv = tid >> 6, lane = tid & 63;
    int lm = lane & 15, lk = lane >> 4;
    f32x4 acc[3][2];
    #pragma unroll
    for (int g=0;g<3;++g){ acc[g][0]=(f32x4){0.f,0.f,0.f,0.f}; acc[g][1]=(f32x4){0.f,0.f,0.f,0.f}; }
    const ushort* Ap = Wqkv + (size_t)(wv*16 + lm)*CC + lk*8;

    #pragma unroll
    for (int k0=0; k0<CC; k0+=32){
        bf16x8 a0 = *(const bf16x8*)(Ap + k0);
        bf16x8 a1 = *(const bf16x8*)(Ap + 64*CC + k0);
        bf16x8 a2 = *(const bf16x8*)(Ap + 128*CC + k0);
        #pragma unroll
        for (int nt=0; nt<2; ++nt){
            int ch = (nt*16+lm)*33 + (k0>>3) + lk;
            bf16x8 bT = *(const bf16x8*)&sT[ch*8];
            bf16x8 bS = *(const bf16x8*)&sS[ch*8];
            acc[0][nt] = __builtin_amdgcn_mfma_f32_16x16x32_bf16(a0, bT, acc[0][nt], 0,0,0);
            acc[1][nt] = __builtin_amdgcn_mfma_f32_16x16x32_bf16(a1, bS, acc[1][nt], 0,0,0);
            acc[2][nt] = __builtin_amdgcn_mfma_f32_16x16x32_bf16(a2, bS, acc[2][nt], 0,0,0);
        }
    }
    int ol = wv*16 + lk*4;
    #pragma unroll
    for (int nt=0; nt<2; ++nt){
        int p = p0 + nt*16 + lm;
        {
            int ob = ol;
            uint u0 = (uint)f2b(acc[0][nt][0]+bqkv[ob])   | ((uint)f2b(acc[0][nt][1]+bqkv[ob+1])<<16);
            uint u1 = (uint)f2b(acc[0][nt][2]+bqkv[ob+2]) | ((uint)f2b(acc[0][nt][3]+bqkv[ob+3])<<16);
            *(uint2*)(X1 + (size_t)p*128 + ol) = make_uint2(u0, u1);
        }
        {
            int ob = 64 + ol;
            uint u0 = (uint)f2b(acc[1][nt][0]+bqkv[ob])   | ((uint)f2b(acc[1][nt][1]+bqkv[ob+1])<<16);
            uint u1 = (uint)f2b(acc[1][nt][2]+bqkv[ob+2]) | ((uint)f2b(acc[1][nt][3]+bqkv[ob+3])<<16);
            *(uint2*)(X1 + (size_t)p*128 + 64 + ol) = make_uint2(u0, u1);
        }
        #pragma unroll
        for (int j=0;j<4;++j)
            VbT[(size_t)(ol+j)*NPIX + p] = f2b(acc[2][nt][j] + bqkv[128 + ol + j]);
    }
}

// ---------- k_ca: MFMA-banded (96-col one-sided band) cost + softmax + aggV ----------
// 768 blocks (XCD-swizzled) x 512 thr; 32 px/block; band = 96 px on the shift side.
#define BANDC 96
#define STS 36     // f32 stride of S^T rows
#define PFS 100    // f32 stride of PC-f32 rows (reuses sF)
#define VTS2 104   // ushort stride of sPC rows
__global__ __launch_bounds__(512) void k_ca(
    const ushort* __restrict__ X1, const ushort* __restrict__ VbT,
    const float* __restrict__ directs, const int* __restrict__ img_w_p,
    float* __restrict__ C1, ushort* __restrict__ Agg)
{
    __shared__ float  sF[BANDC*STS];    // 13.5 KiB: S^T [x][qpx]; then PC-f32 [32][PFS]
    __shared__ ushort sPC[32*VTS2];     // 6.5 KiB [px][x]
    int tid = threadIdx.x;
    int j   = blockIdx.x;
    int r8  = j & 7;
    int kk  = j >> 3;
    int sub = kk % 6;
    int rhi = kk / 6;
    int row = rhi*8 + r8;          // b*64 + h
    int b   = row >> 6;
    int h   = row & 63;
    int w0  = sub * 32;
    size_t rowbase = (size_t)b*HW + (size_t)h*WW;

    int imw = img_w_p[0];
    float rel = (imw != 640) ? (640.0f/(float)imw) : 1.0f;
    float sf = 0.01f * rel * directs[b] * 191.0f;
    int bl = (sf < 0.f) ? (w0 - 64) : w0;   // one-sided 96-px band

    int w8 = tid >> 6, lane = tid & 63;
    int lm = lane & 15, lk = lane >> 4;

    // ---- S^T = (Q . K_band^T)^T via MFMA; fragments direct from global ----
    {
        int mt = w8 & 1;
        int q  = w0 + mt*16 + lm;
        const ushort* Qp = X1 + (rowbase + q)*128 + lk*8;
        bf16x8 aq0 = *(const bf16x8*)(Qp);
        bf16x8 aq1 = *(const bf16x8*)(Qp + 32);
        for (int nt = (w8 >> 1); nt < 6; nt += 4){
            int xrow = nt*16 + lm;
            int gx = bl + xrow;
            bf16x8 b0 = {0,0,0,0,0,0,0,0}, b1 = {0,0,0,0,0,0,0,0};
            if (gx >= 0 && gx < WW){
                const ushort* Kp = X1 + (rowbase + gx)*128 + 64 + lk*8;
                b0 = *(const bf16x8*)(Kp);
                b1 = *(const bf16x8*)(Kp + 32);
            }
            f32x4 acc = {0.f,0.f,0.f,0.f};
            acc = __builtin_amdgcn_mfma_f32_16x16x32_bf16(aq0, b0, acc, 0,0,0);
            acc = __builtin_amdgcn_mfma_f32_16x16x32_bf16(aq1, b1, acc, 0,0,0);
            *(f32x4*)&sF[xrow*STS + mt*16 + lk*4] = acc;
        }
    }
    __syncthreads();

    // ---- cost gather + C1 write + softmax ----
    int px  = tid >> 4;
    int l16 = tid & 15;
    int w   = w0 + px;
    size_t n = rowbase + w;
    float wf = (float)w;

    float cost[2]; int xi0[2], xi1[2]; float frk[2];
    #pragma unroll
    for (int t=0; t<2; ++t){
        int d = l16*2 + t;
        float srcx = fminf(fmaxf(wf + (float)d*sf, 0.f), 191.0f);
        int x0 = (int)floorf(srcx);
        int x1 = min(x0+1, WW-1);
        float fr = srcx - (float)x0;
        // in-band indices; overflow only possible at fr==0 (zero weight) -> safe clamp
        int i0 = min(max(x0 - bl, 0), BANDC-1);
        int i1 = min(max(x1 - bl, 0), BANDC-1);
        xi0[t] = i0; xi1[t] = i1; frk[t] = fr;
        float s0 = sF[i0*STS + px];
        float s1 = sF[i1*STS + px];
        cost[t] = (s0 + fr*(s1-s0)) * 0.125f;
    }
    *(float2*)(C1 + n*DD + l16*2) = make_float2(cost[0], cost[1]);
    float mm = fmaxf(cost[0], cost[1]);
    mm = fmaxf(mm, __shfl_xor(mm, 1));
    mm = fmaxf(mm, __shfl_xor(mm, 2));
    mm = fmaxf(mm, __shfl_xor(mm, 4));
    mm = fmaxf(mm, __shfl_xor(mm, 8));
    float e0 = __expf(cost[0]-mm), e1 = __expf(cost[1]-mm);
    float ss = e0 + e1;
    ss += __shfl_xor(ss, 1);
    ss += __shfl_xor(ss, 2);
    ss += __shfl_xor(ss, 4);
    ss += __shfl_xor(ss, 8);
    float inv = 1.f/ss;
    float p0 = e0*inv, p1 = e1*inv;
    __syncthreads();   // all S reads done

    // ---- zero PC-f32 (reuse sF as [px][PFS]) ----
    for (int i = tid; i < (32*PFS)/4; i += 512)
        *(f32x4*)&sF[i*4] = (f32x4){0.f,0.f,0.f,0.f};
    __syncthreads();

    // ---- scatter p into band coefficients ----
    {
        float w1a = p0*frk[0], w0a = p0 - w1a;
        float w1b = p1*frk[1], w0b = p1 - w1b;
        atomicAdd(&sF[px*PFS + xi0[0]], w0a);
        atomicAdd(&sF[px*PFS + xi1[0]], w1a);
        atomicAdd(&sF[px*PFS + xi0[1]], w0b);
        atomicAdd(&sF[px*PFS + xi1[1]], w1b);
    }
    __syncthreads();

    // ---- convert PC to bf16 (6 entries per (px,l16)) ----
    {
        int base = l16*6;
        #pragma unroll
        for (int q=0; q<3; ++q){
            float2 v2 = *(const float2*)&sF[px*PFS + base + q*2];
            *(uint*)&sPC[px*VTS2 + base + q*2] = (uint)f2b(v2.x) | ((uint)f2b(v2.y)<<16);
        }
    }
    __syncthreads();

    // ---- agg = V^T . PC^T via MFMA (A direct from global VbT, B = sPC) ----
    {
        int mi = w8 & 3;            // c-tile
        int ni = w8 >> 2;           // px-tile
        int c  = mi*16 + lm;
        int wr = ni*16 + lm;
        const ushort* Vp = VbT + (size_t)c*NPIX + rowbase + bl;
        f32x4 acc = {0.f,0.f,0.f,0.f};
        #pragma unroll
        for (int kt=0; kt<3; ++kt){
            int gx = bl + kt*32 + lk*8;
            bf16x8 a = {0,0,0,0,0,0,0,0};
            if (gx >= 0 && gx < WW) a = *(const bf16x8*)(Vp + kt*32 + lk*8);
            bf16x8 bbf = *(const bf16x8*)&sPC[wr*VTS2 + kt*32 + lk*8];
            acc = __builtin_amdgcn_mfma_f32_16x16x32_bf16(a, bbf, acc, 0,0,0);
        }
        uint u0 = (uint)f2b(acc[0]) | ((uint)f2b(acc[1])<<16);
        uint u1 = (uint)f2b(acc[2]) | ((uint)f2b(acc[3])<<16);
        *(uint2*)(Agg + (rowbase + w0 + wr)*64 + mi*16 + lk*4) = make_uint2(u0, u1);
    }
}

// ---------- G2: conv3x3 p1, LDS-staged implicit GEMM, ELU ----------
__global__ __launch_bounds__(256) void g_conv1(
    const ushort* __restrict__ X1, const ushort* __restrict__ Agg,
    const ushort* __restrict__ A1, const float* __restrict__ p1b,
    ushort* __restrict__ X2)
{
    __shared__ ushort sB[3*16*34*8];
    int tid = threadIdx.x;
    int wv = tid >> 6, lane = tid & 63;
    int lm = lane & 15, lk = lane >> 4;
    int bid = blockIdx.x;
    int tile = (bid & 7)*96 + (bid >> 3);
    int n0 = tile * 32;
    int b  = n0 / HW;
    int pl = n0 % HW;
    int h  = pl / WW, w0 = pl % WW;

    for (int i = tid; i < 1632; i += 256){
        int dh = i / 544, rem2 = i % 544;
        int c16 = rem2 / 34, x = rem2 % 34;
        int hh = h + dh - 1, wx = w0 + x - 1;
        uint4 val = make_uint4(0,0,0,0);
        if (hh >= 0 && hh < HH && wx >= 0 && wx < WW){
            size_t pix = (size_t)b*HW + (size_t)hh*WW + wx;
            val = (c16 < 8) ? *(const uint4*)(X1 + pix*128 + c16*8)
                            : *(const uint4*)(Agg + pix*64 + (c16-8)*8);
        }
        *(uint4*)&sB[((dh*16 + c16)*34 + x)*8] = val;
    }
    __syncthreads();

    int mw = wv & 1, nw = wv >> 1;
    const ushort* Ap = A1 + (size_t)(mw*32 + lm)*1152 + lk*8;
    f32x4 acc0 = {0.f,0.f,0.f,0.f}, acc1 = {0.f,0.f,0.f,0.f};
    int xb = nw*16 + lm;
    #pragma unroll
    for (int t=0; t<9; ++t){
        int dh = t/3, dw = t%3;
        #pragma unroll
        for (int c0=0; c0<128; c0+=32){
            bf16x8 bb = *(const bf16x8*)&sB[((dh*16 + (c0>>3)+lk)*34 + xb + dw)*8];
            bf16x8 a0 = *(const bf16x8*)(Ap + t*128 + c0);
            bf16x8 a1 = *(const bf16x8*)(Ap + (size_t)16*1152 + t*128 + c0);
            acc0 = __builtin_amdgcn_mfma_f32_16x16x32_bf16(a0, bb, acc0, 0,0,0);
            acc1 = __builtin_amdgcn_mfma_f32_16x16x32_bf16(a1, bb, acc1, 0,0,0);
        }
    }
    int pg = n0 + nw*16 + lm;
    int o0 = mw*32 + lk*4;
    {
        uint u0 = (uint)f2b(eluf(acc0[0]+p1b[o0]))   | ((uint)f2b(eluf(acc0[1]+p1b[o0+1]))<<16);
        uint u1 = (uint)f2b(eluf(acc0[2]+p1b[o0+2])) | ((uint)f2b(eluf(acc0[3]+p1b[o0+3]))<<16);
        *(uint2*)(X2 + (size_t)pg*64 + o0) = make_uint2(u0, u1);
        int o1 = o0 + 16;
        uint u2 = (uint)f2b(eluf(acc1[0]+p1b[o1]))   | ((uint)f2b(eluf(acc1[1]+p1b[o1+1]))<<16);
        uint u3 = (uint)f2b(eluf(acc1[2]+p1b[o1+2])) | ((uint)f2b(eluf(acc1[3]+p1b[o1+3]))<<16);
        *(uint2*)(X2 + (size_t)pg*64 + o1) = make_uint2(u2, u3);
    }
}

// ---------- G3+G4 fused: conv p2 + residual -> cost_out, softmax -> NC(LDS),
//            final conv1x1 on concat(t_feat, NC) -> xout; stages t_feat f32 direct ----------
__global__ __launch_bounds__(256) void g_conv2final(
    const ushort* __restrict__ X2, const ushort* __restrict__ A2,
    const float* __restrict__ p2b, const float* __restrict__ C1,
    const float* __restrict__ t_feat, const ushort* __restrict__ Ar,
    const float* __restrict__ rb,
    float* __restrict__ cost_out, float* __restrict__ xout)
{
    __shared__ ushort sT[32*264];     // 16.5 KiB; first 13 KiB doubles as sB (X2 halo)
    __shared__ float  sO[32*36];      // 4.5 KiB
    __shared__ ushort sN[32*40];      // 2.5 KiB
    ushort* sB = sT;                  // alias: sB dead before sT staged
    int tid = threadIdx.x;
    int wv = tid >> 6, lane = tid & 63;
    int lm = lane & 15, lk = lane >> 4;
    int bid = blockIdx.x;
    int tile = (bid & 7)*96 + (bid >> 3);
    int n0 = tile * 32;
    int b  = n0 / HW;
    int pl = n0 % HW;
    int h  = pl / WW, w0 = pl % WW;

    // phase 1: stage X2 halo
    for (int i = tid; i < 816; i += 256){
        int dh = i / 272, rem2 = i % 272;
        int c16 = rem2 / 34, x = rem2 % 34;
        int hh = h + dh - 1, wx = w0 + x - 1;
        uint4 val = make_uint4(0,0,0,0);
        if (hh >= 0 && hh < HH && wx >= 0 && wx < WW)
            val = *(const uint4*)(X2 + ((size_t)b*HW + (size_t)hh*WW + wx)*64 + c16*8);
        *(uint4*)&sB[((dh*8 + c16)*34 + x)*8] = val;
    }
    __syncthreads();

    // phase 2: conv p2 + residual -> cost_out + sO
    {
        int mw = wv & 1, nw = wv >> 1;
        const ushort* Ap = A2 + (size_t)(mw*16 + lm)*576 + lk*8;
        f32x4 acc = {0.f,0.f,0.f,0.f};
        int xb = nw*16 + lm;
        #pragma unroll
        for (int t=0; t<9; ++t){
            int dh = t/3, dw = t%3;
            #pragma unroll
            for (int c0=0; c0<64; c0+=32){
                bf16x8 bb = *(const bf16x8*)&sB[((dh*8 + (c0>>3)+lk)*34 + xb + dw)*8];
                bf16x8 a  = *(const bf16x8*)(Ap + t*64 + c0);
                acc = __builtin_amdgcn_mfma_f32_16x16x32_bf16(a, bb, acc, 0,0,0);
            }
        }
        int pg = n0 + nw*16 + lm;
        int pll = pg % HW;
        int o = mw*16 + lk*4;
        f32x4 cv = *(const f32x4*)(C1 + (size_t)pg*DD + o);
        f32x4 outv;
        #pragma unroll
        for (int j=0;j<4;++j){
            outv[j] = (cv[j] + acc[j] + p2b[o+j]) * 0.5f;
            cost_out[((size_t)(b*DD + o + j))*HW + pll] = outv[j];
        }
        *(f32x4*)&sO[(nw*16 + lm)*36 + o] = outv;
    }
    __syncthreads();

    // phase 3: softmax -> sN; stage t_feat f32 tile -> sT (overwrites dead sB)
    {
        int px = tid >> 3;
        int g  = tid & 7;
        f32x4 v = *(const f32x4*)&sO[px*36 + g*4];
        float m = fmaxf(fmaxf(v[0],v[1]), fmaxf(v[2],v[3]));
        m = fmaxf(m, __shfl_xor(m, 1));
        m = fmaxf(m, __shfl_xor(m, 2));
        m = fmaxf(m, __shfl_xor(m, 4));
        float e[4]; float s = 0.f;
        #pragma unroll
        for (int j=0;j<4;++j){ e[j] = __expf(v[j]-m); s += e[j]; }
        s += __shfl_xor(s, 1);
        s += __shfl_xor(s, 2);
        s += __shfl_xor(s, 4);
        float invs = 1.f/s;
        uint u0 = (uint)f2b(e[0]*invs) | ((uint)f2b(e[1]*invs)<<16);
        uint u1 = (uint)f2b(e[2]*invs) | ((uint)f2b(e[3]*invs)<<16);
        *(uint2*)&sN[px*40 + g*4] = make_uint2(u0, u1);
    }
    for (int i = tid; i < 1024; i += 256){
        int px = i & 31, c8 = i >> 5;
        const float* pt = t_feat + ((size_t)(b*CC + c8*8))*HW + pl + px;
        uint u[4];
        #pragma unroll
        for (int j2=0;j2<4;++j2)
            u[j2] = (uint)f2b(pt[(size_t)(2*j2)*HW]) | ((uint)f2b(pt[(size_t)(2*j2+1)*HW])<<16);
        uint4 q4; q4.x=u[0]; q4.y=u[1]; q4.z=u[2]; q4.w=u[3];
        *(uint4*)&sT[(px*33 + c8)*8] = q4;
    }
    __syncthreads();

    // phase 4: final conv1x1 (MFMA) -> xout
    {
        f32x4 acc[4][2];
        #pragma unroll
        for (int mi=0;mi<4;++mi){ acc[mi][0]=(f32x4){0.f,0.f,0.f,0.f}; acc[mi][1]=(f32x4){0.f,0.f,0.f,0.f}; }
        const ushort* Ap = Ar + (size_t)(wv*64 + lm)*288 + lk*8;

        #pragma unroll
        for (int k0=0; k0<288; k0+=32){
            bf16x8 a[4];
            #pragma unroll
            for (int mi=0;mi<4;++mi) a[mi] = *(const bf16x8*)(Ap + (size_t)mi*16*288 + k0);
            #pragma unroll
            for (int nt=0; nt<2; ++nt){
                int prow = nt*16 + lm;
                bf16x8 bb = (k0 < 256) ? *(const bf16x8*)&sT[(prow*33 + (k0>>3) + lk)*8]
                                       : *(const bf16x8*)&sN[(prow*5 + lk)*8];
                #pragma unroll
                for (int mi=0;mi<4;++mi)
                    acc[mi][nt] = __builtin_amdgcn_mfma_f32_16x16x32_bf16(a[mi], bb, acc[mi][nt], 0,0,0);
            }
        }
        #pragma unroll
        for (int mi=0;mi<4;++mi){
            int o = wv*64 + mi*16 + lk*4;
            #pragma unroll
            for (int nt=0; nt<2; ++nt){
                int p = n0 + nt*16 + lm;
                int bb2 = p / HW, pl2 = p % HW;
                #pragma unroll
                for (int j=0;j<4;++j)
                    xout[((size_t)(bb2*CC + o + j))*HW + pl2] = eluf(acc[mi][nt][j] + rb[o+j]);
            }
        }
    }
}

extern "C" void kernel_launch(void* const* d_in, const int* in_sizes, int n_in,
                              void* d_out, int out_size, void* d_ws, size_t ws_size,
                              hipStream_t stream)
{
    const float* t_feat = (const float*)d_in[0];
    const float* s_feat = (const float*)d_in[1];
    const float* directs= (const float*)d_in[2];
    const float* qw = (const float*)d_in[3];
    const float* qb = (const float*)d_in[4];
    const float* kw = (const float*)d_in[5];
    const float* kb = (const float*)d_in[6];
    const float* vw = (const float*)d_in[7];
    const float* vb = (const float*)d_in[8];
    const float* p1w= (const float*)d_in[9];
    const float* p1b= (const float*)d_in[10];
    const float* p2w= (const float*)d_in[11];
    const float* p2b= (const float*)d_in[12];
    const float* rw = (const float*)d_in[13];
    const float* rb = (const float*)d_in[14];
    const int* img_w= (const int*)d_in[15];

    char* wsb = (char*)d_ws;
    // (Tt/Ts eliminated; region offsets kept for layout stability)
    char*  tsreg = wsb + 12582912;
    ushort* X2   = (ushort*)tsreg;
    float*  C1   = (float*)(tsreg + 3145728);
    ushort* Agg  = (ushort*)(tsreg + 6291456);
    ushort* X1   = (ushort*)(wsb + 25165824);    // [NPIX][128] bf16 (q | K)
    ushort* VbT  = (ushort*)(wsb + 31457280);    // [64][NPIX] bf16 (V transposed)
    ushort* Wqkv = (ushort*)(wsb + 34603008);
    float*  bqkv = (float*) (wsb + 34701312);
    ushort* A1   = (ushort*)(wsb + 34702336);
    ushort* A2   = (ushort*)(wsb + 34849792);
    ushort* Ar   = (ushort*)(wsb + 34886656);    // -> end 35,034,112
    if (ws_size < 35034112) return;

    float* xout     = (float*)d_out;                 // [B,256,H,W] f32
    float* cost_out = xout + (size_t)BB*CC*HW;       // [B,32,H,W] f32

    k_prep_w    <<<841,  256, 0, stream>>>(qw,qb,kw,kb,vw,vb,p1w,p2w,rw,
                                           Wqkv,bqkv,A1,A2,Ar);
    g_qkv       <<<768,  256, 0, stream>>>(t_feat, s_feat, Wqkv, bqkv, X1, VbT);
    k_ca        <<<768,  512, 0, stream>>>(X1, VbT, directs, img_w, C1, Agg);
    g_conv1     <<<768,  256, 0, stream>>>(X1, Agg, A1, p1b, X2);
    g_conv2final<<<768,  256, 0, stream>>>(X2, A2, p2b, C1, t_feat, Ar, rb,
                                           cost_out, xout);
}

// Round 14
// 95.545 us; speedup vs baseline: 2.5411x; 1.0149x over previous
//
#include <hip/hip_runtime.h>

#define BB 2
#define CC 256
#define CQ 64
#define DD 32
#define HH 64
#define WW 192
#define HW (HH*WW)     // 12288
#define NPIX (BB*HW)   // 24576

typedef __attribute__((ext_vector_type(8))) short bf16x8;
typedef __attribute__((ext_vector_type(4))) float f32x4;

__device__ __forceinline__ float b2f(ushort s){ return __uint_as_float(((uint)s)<<16); }
__device__ __forceinline__ ushort f2b(float f){
    uint u = __float_as_uint(f);
    return (ushort)((u + 0x7fffu + ((u>>16)&1u)) >> 16);
}
__device__ __forceinline__ float eluf(float v){ return v > 0.f ? v : (__expf(v)-1.f); }

// ---------- prep: weights only -> bf16 GEMM-A layouts ----------
__global__ __launch_bounds__(256) void k_prep_w(
    const float* __restrict__ qw, const float* __restrict__ qb,
    const float* __restrict__ kw, const float* __restrict__ kb,
    const float* __restrict__ vw, const float* __restrict__ vb,
    const float* __restrict__ p1w, const float* __restrict__ p2w,
    const float* __restrict__ rw,
    ushort* __restrict__ Wqkv, float* __restrict__ bqkv,
    ushort* __restrict__ A1, ushort* __restrict__ A2, ushort* __restrict__ Ar)
{
    int id = blockIdx.x*256 + threadIdx.x;
    if (id < 49152) {
        int o = id / 256, c = id % 256;
        float v = (o<64)? qw[o*256+c] : (o<128)? kw[(o-64)*256+c] : vw[(o-128)*256+c];
        Wqkv[id] = f2b(v);
    } else if (id < 49344) {
        int o = id - 49152;
        bqkv[o] = (o<64)? qb[o] : (o<128)? kb[o-64] : vb[o-128];
    } else if (id < 49344+73728) {
        int i = id - 49344;
        int o = i/1152, r = i%1152, t = r/128, ci = r%128;
        A1[i] = f2b(p1w[(size_t)(o*128+ci)*9 + t]);
    } else if (id < 49344+73728+18432) {
        int i = id - (49344+73728);
        int o = i/576, r = i%576, t = r/64, ci = r%64;
        A2[i] = f2b(p2w[(size_t)(o*64+ci)*9 + t]);
    } else if (id < 49344+73728+18432+73728) {
        int i = id - (49344+73728+18432);
        Ar[i] = f2b(rw[i]);
    }
}

// ---------- G1: qkv conv1x1; stages DIRECTLY from NCHW f32 ----------
__global__ __launch_bounds__(256) void g_qkv(
    const float* __restrict__ t_feat, const float* __restrict__ s_feat,
    const ushort* __restrict__ Wqkv, const float* __restrict__ bqkv,
    ushort* __restrict__ X1, ushort* __restrict__ VbT)
{
    __shared__ ushort sT[32*264];
    __shared__ ushort sS[32*264];
    int tid = threadIdx.x;
    int bid = blockIdx.x;
    int tile = (bid & 7)*96 + (bid >> 3);
    int p0 = tile * 32;
    int b0  = p0 / HW;
    int pl0 = p0 % HW;

    for (int i = tid; i < 1024; i += 256){
        int px = i & 31, c8 = i >> 5;
        const float* pt = t_feat + ((size_t)(b0*CC + c8*8))*HW + pl0 + px;
        const float* ps = s_feat + ((size_t)(b0*CC + c8*8))*HW + pl0 + px;
        uint ut[4], us[4];
        #pragma unroll
        for (int j2=0;j2<4;++j2){
            ut[j2] = (uint)f2b(pt[(size_t)(2*j2)*HW]) | ((uint)f2b(pt[(size_t)(2*j2+1)*HW])<<16);
            us[j2] = (uint)f2b(ps[(size_t)(2*j2)*HW]) | ((uint)f2b(ps[(size_t)(2*j2+1)*HW])<<16);
        }
        uint4 qt; qt.x=ut[0]; qt.y=ut[1]; qt.z=ut[2]; qt.w=ut[3];
        uint4 qs; qs.x=us[0]; qs.y=us[1]; qs.z=us[2]; qs.w=us[3];
        *(uint4*)&sT[(px*33 + c8)*8] = qt;
        *(uint4*)&sS[(px*33 + c8)*8] = qs;
    }
    __syncthreads();

    int wv = tid >> 6, lane = tid & 63;
    int lm = lane & 15, lk = lane >> 4;
    f32x4 acc[3][2];
    #pragma unroll
    for (int g=0;g<3;++g){ acc[g][0]=(f32x4){0.f,0.f,0.f,0.f}; acc[g][1]=(f32x4){0.f,0.f,0.f,0.f}; }
    const ushort* Ap = Wqkv + (size_t)(wv*16 + lm)*CC + lk*8;

    #pragma unroll
    for (int k0=0; k0<CC; k0+=32){
        bf16x8 a0 = *(const bf16x8*)(Ap + k0);
        bf16x8 a1 = *(const bf16x8*)(Ap + 64*CC + k0);
        bf16x8 a2 = *(const bf16x8*)(Ap + 128*CC + k0);
        #pragma unroll
        for (int nt=0; nt<2; ++nt){
            int ch = (nt*16+lm)*33 + (k0>>3) + lk;
            bf16x8 bT = *(const bf16x8*)&sT[ch*8];
            bf16x8 bS = *(const bf16x8*)&sS[ch*8];
            acc[0][nt] = __builtin_amdgcn_mfma_f32_16x16x32_bf16(a0, bT, acc[0][nt], 0,0,0);
            acc[1][nt] = __builtin_amdgcn_mfma_f32_16x16x32_bf16(a1, bS, acc[1][nt], 0,0,0);
            acc[2][nt] = __builtin_amdgcn_mfma_f32_16x16x32_bf16(a2, bS, acc[2][nt], 0,0,0);
        }
    }
    int ol = wv*16 + lk*4;
    #pragma unroll
    for (int nt=0; nt<2; ++nt){
        int p = p0 + nt*16 + lm;
        {
            int ob = ol;
            uint u0 = (uint)f2b(acc[0][nt][0]+bqkv[ob])   | ((uint)f2b(acc[0][nt][1]+bqkv[ob+1])<<16);
            uint u1 = (uint)f2b(acc[0][nt][2]+bqkv[ob+2]) | ((uint)f2b(acc[0][nt][3]+bqkv[ob+3])<<16);
            *(uint2*)(X1 + (size_t)p*128 + ol) = make_uint2(u0, u1);
        }
        {
            int ob = 64 + ol;
            uint u0 = (uint)f2b(acc[1][nt][0]+bqkv[ob])   | ((uint)f2b(acc[1][nt][1]+bqkv[ob+1])<<16);
            uint u1 = (uint)f2b(acc[1][nt][2]+bqkv[ob+2]) | ((uint)f2b(acc[1][nt][3]+bqkv[ob+3])<<16);
            *(uint2*)(X1 + (size_t)p*128 + 64 + ol) = make_uint2(u0, u1);
        }
        #pragma unroll
        for (int j=0;j<4;++j)
            VbT[(size_t)(ol+j)*NPIX + p] = f2b(acc[2][nt][j] + bqkv[128 + ol + j]);
    }
}

// ---------- k_ca: MFMA-banded, 2-barrier, 16px/block, 256 thr ----------
// 1536 blocks (XCD-swizzled, 12 sub-tiles/row); band = 96 px one-sided.
// Phase A: zero scatter buf + S^T MFMA (direct-global fragments) | bar |
// Phase B: gather+softmax+C1+scatter | bar | Phase C: PV MFMA (in-reg convert).
#define BANDC 96
#define STS2 20    // f32 stride of S^T rows [96][20] (16 qpx + pad)
#define PFS2 100   // f32 stride of scatter rows [16][100]
__global__ __launch_bounds__(256) void k_ca(
    const ushort* __restrict__ X1, const ushort* __restrict__ VbT,
    const float* __restrict__ directs, const int* __restrict__ img_w_p,
    float* __restrict__ C1, ushort* __restrict__ Agg)
{
    __shared__ float sS[BANDC*STS2];   // 7.5 KiB  S^T [x][qpx]
    __shared__ float sPCf[16*PFS2];    // 6.25 KiB scatter buffer [px][bandcol]
    int tid = threadIdx.x;
    int j   = blockIdx.x;
    int r8  = j & 7;
    int kk  = j >> 3;            // 0..191
    int sub = kk % 12;
    int rhi = kk / 12;           // 0..15
    int row = rhi*8 + r8;        // b*64 + h
    int b   = row >> 6;
    int h   = row & 63;
    int w0  = sub * 16;
    size_t rowbase = (size_t)b*HW + (size_t)h*WW;

    int imw = img_w_p[0];
    float rel = (imw != 640) ? (640.0f/(float)imw) : 1.0f;
    float sf = 0.01f * rel * directs[b] * 191.0f;
    int bl = (sf < 0.f) ? (w0 - 64) : w0;   // one-sided 96-px band

    int wv = tid >> 6, lane = tid & 63;
    int lm = lane & 15, lk = lane >> 4;

    // ---- phase A1: zero scatter buffer (separate region; ordered by bar 1) ----
    for (int i = tid; i < 400; i += 256)
        *(f32x4*)&sPCf[i*4] = (f32x4){0.f,0.f,0.f,0.f};

    // ---- phase A2: S^T = (Q . K_band^T)^T via MFMA, direct-global fragments ----
    {
        const ushort* Qp = X1 + (rowbase + w0 + lm)*128 + lk*8;
        bf16x8 aq0 = *(const bf16x8*)(Qp);
        bf16x8 aq1 = *(const bf16x8*)(Qp + 32);
        for (int xt = wv; xt < 6; xt += 4){
            int xrow = xt*16 + lm;
            int gx = bl + xrow;
            bf16x8 b0 = {0,0,0,0,0,0,0,0}, b1 = {0,0,0,0,0,0,0,0};
            if (gx >= 0 && gx < WW){
                const ushort* Kp = X1 + (rowbase + gx)*128 + 64 + lk*8;
                b0 = *(const bf16x8*)(Kp);
                b1 = *(const bf16x8*)(Kp + 32);
            }
            f32x4 acc = {0.f,0.f,0.f,0.f};
            acc = __builtin_amdgcn_mfma_f32_16x16x32_bf16(aq0, b0, acc, 0,0,0);
            acc = __builtin_amdgcn_mfma_f32_16x16x32_bf16(aq1, b1, acc, 0,0,0);
            *(f32x4*)&sS[xrow*STS2 + lk*4] = acc;
        }
    }
    __syncthreads();   // [bar 1]

    // ---- phase B: gather + C1 + softmax + scatter ----
    int px  = tid >> 4;          // 0..15
    int l16 = tid & 15;
    int w   = w0 + px;
    size_t n = rowbase + w;
    float wf = (float)w;

    float cost[2]; int xi0[2], xi1[2]; float frk[2];
    #pragma unroll
    for (int t=0; t<2; ++t){
        int d = l16*2 + t;
        float srcx = fminf(fmaxf(wf + (float)d*sf, 0.f), 191.0f);
        int x0 = (int)floorf(srcx);
        int x1 = min(x0+1, WW-1);
        float fr = srcx - (float)x0;
        int i0 = min(max(x0 - bl, 0), BANDC-1);
        int i1 = min(max(x1 - bl, 0), BANDC-1);
        xi0[t] = i0; xi1[t] = i1; frk[t] = fr;
        float s0 = sS[i0*STS2 + px];
        float s1 = sS[i1*STS2 + px];
        cost[t] = (s0 + fr*(s1-s0)) * 0.125f;
    }
    *(float2*)(C1 + n*DD + l16*2) = make_float2(cost[0], cost[1]);
    float mm = fmaxf(cost[0], cost[1]);
    mm = fmaxf(mm, __shfl_xor(mm, 1));
    mm = fmaxf(mm, __shfl_xor(mm, 2));
    mm = fmaxf(mm, __shfl_xor(mm, 4));
    mm = fmaxf(mm, __shfl_xor(mm, 8));
    float e0 = __expf(cost[0]-mm), e1 = __expf(cost[1]-mm);
    float ss = e0 + e1;
    ss += __shfl_xor(ss, 1);
    ss += __shfl_xor(ss, 2);
    ss += __shfl_xor(ss, 4);
    ss += __shfl_xor(ss, 8);
    float inv = 1.f/ss;
    float p0 = e0*inv, p1 = e1*inv;
    {
        float w1a = p0*frk[0], w0a = p0 - w1a;
        float w1b = p1*frk[1], w0b = p1 - w1b;
        atomicAdd(&sPCf[px*PFS2 + xi0[0]], w0a);
        atomicAdd(&sPCf[px*PFS2 + xi1[0]], w1a);
        atomicAdd(&sPCf[px*PFS2 + xi0[1]], w0b);
        atomicAdd(&sPCf[px*PFS2 + xi1[1]], w1b);
    }
    __syncthreads();   // [bar 2]

    // ---- phase C: agg = V^T . PC^T via MFMA; B converted in-register ----
    {
        int mi = wv;                 // c-tile 0..3
        int c  = mi*16 + lm;
        const ushort* Vp = VbT + (size_t)c*NPIX + rowbase + bl;
        f32x4 acc = {0.f,0.f,0.f,0.f};
        #pragma unroll
        for (int kt=0; kt<3; ++kt){
            int gx = bl + kt*32 + lk*8;
            bf16x8 a = {0,0,0,0,0,0,0,0};
            if (gx >= 0 && gx < WW) a = *(const bf16x8*)(Vp + kt*32 + lk*8);
            f32x4 v0 = *(const f32x4*)&sPCf[lm*PFS2 + kt*32 + lk*8];
            f32x4 v1 = *(const f32x4*)&sPCf[lm*PFS2 + kt*32 + lk*8 + 4];
            bf16x8 bbf;
            #pragma unroll
            for (int jj=0;jj<4;++jj){
                bbf[jj]   = (short)f2b(v0[jj]);
                bbf[jj+4] = (short)f2b(v1[jj]);
            }
            acc = __builtin_amdgcn_mfma_f32_16x16x32_bf16(a, bbf, acc, 0,0,0);
        }
        uint u0 = (uint)f2b(acc[0]) | ((uint)f2b(acc[1])<<16);
        uint u1 = (uint)f2b(acc[2]) | ((uint)f2b(acc[3])<<16);
        *(uint2*)(Agg + (rowbase + w0 + lm)*64 + mi*16 + lk*4) = make_uint2(u0, u1);
    }
}

// ---------- G2: conv3x3 p1, LDS-staged implicit GEMM, ELU ----------
__global__ __launch_bounds__(256) void g_conv1(
    const ushort* __restrict__ X1, const ushort* __restrict__ Agg,
    const ushort* __restrict__ A1, const float* __restrict__ p1b,
    ushort* __restrict__ X2)
{
    __shared__ ushort sB[3*16*34*8];
    int tid = threadIdx.x;
    int wv = tid >> 6, lane = tid & 63;
    int lm = lane & 15, lk = lane >> 4;
    int bid = blockIdx.x;
    int tile = (bid & 7)*96 + (bid >> 3);
    int n0 = tile * 32;
    int b  = n0 / HW;
    int pl = n0 % HW;
    int h  = pl / WW, w0 = pl % WW;

    for (int i = tid; i < 1632; i += 256){
        int dh = i / 544, rem2 = i % 544;
        int c16 = rem2 / 34, x = rem2 % 34;
        int hh = h + dh - 1, wx = w0 + x - 1;
        uint4 val = make_uint4(0,0,0,0);
        if (hh >= 0 && hh < HH && wx >= 0 && wx < WW){
            size_t pix = (size_t)b*HW + (size_t)hh*WW + wx;
            val = (c16 < 8) ? *(const uint4*)(X1 + pix*128 + c16*8)
                            : *(const uint4*)(Agg + pix*64 + (c16-8)*8);
        }
        *(uint4*)&sB[((dh*16 + c16)*34 + x)*8] = val;
    }
    __syncthreads();

    int mw = wv & 1, nw = wv >> 1;
    const ushort* Ap = A1 + (size_t)(mw*32 + lm)*1152 + lk*8;
    f32x4 acc0 = {0.f,0.f,0.f,0.f}, acc1 = {0.f,0.f,0.f,0.f};
    int xb = nw*16 + lm;
    #pragma unroll
    for (int t=0; t<9; ++t){
        int dh = t/3, dw = t%3;
        #pragma unroll
        for (int c0=0; c0<128; c0+=32){
            bf16x8 bb = *(const bf16x8*)&sB[((dh*16 + (c0>>3)+lk)*34 + xb + dw)*8];
            bf16x8 a0 = *(const bf16x8*)(Ap + t*128 + c0);
            bf16x8 a1 = *(const bf16x8*)(Ap + (size_t)16*1152 + t*128 + c0);
            acc0 = __builtin_amdgcn_mfma_f32_16x16x32_bf16(a0, bb, acc0, 0,0,0);
            acc1 = __builtin_amdgcn_mfma_f32_16x16x32_bf16(a1, bb, acc1, 0,0,0);
        }
    }
    int pg = n0 + nw*16 + lm;
    int o0 = mw*32 + lk*4;
    {
        uint u0 = (uint)f2b(eluf(acc0[0]+p1b[o0]))   | ((uint)f2b(eluf(acc0[1]+p1b[o0+1]))<<16);
        uint u1 = (uint)f2b(eluf(acc0[2]+p1b[o0+2])) | ((uint)f2b(eluf(acc0[3]+p1b[o0+3]))<<16);
        *(uint2*)(X2 + (size_t)pg*64 + o0) = make_uint2(u0, u1);
        int o1 = o0 + 16;
        uint u2 = (uint)f2b(eluf(acc1[0]+p1b[o1]))   | ((uint)f2b(eluf(acc1[1]+p1b[o1+1]))<<16);
        uint u3 = (uint)f2b(eluf(acc1[2]+p1b[o1+2])) | ((uint)f2b(eluf(acc1[3]+p1b[o1+3]))<<16);
        *(uint2*)(X2 + (size_t)pg*64 + o1) = make_uint2(u2, u3);
    }
}

// ---------- G3+G4 fused: conv p2 + residual -> cost_out, softmax -> NC(LDS),
//            final conv1x1 on concat(t_feat, NC) -> xout ----------
__global__ __launch_bounds__(256) void g_conv2final(
    const ushort* __restrict__ X2, const ushort* __restrict__ A2,
    const float* __restrict__ p2b, const float* __restrict__ C1,
    const float* __restrict__ t_feat, const ushort* __restrict__ Ar,
    const float* __restrict__ rb,
    float* __restrict__ cost_out, float* __restrict__ xout)
{
    __shared__ ushort sT[32*264];
    __shared__ float  sO[32*36];
    __shared__ ushort sN[32*40];
    ushort* sB = sT;
    int tid = threadIdx.x;
    int wv = tid >> 6, lane = tid & 63;
    int lm = lane & 15, lk = lane >> 4;
    int bid = blockIdx.x;
    int tile = (bid & 7)*96 + (bid >> 3);
    int n0 = tile * 32;
    int b  = n0 / HW;
    int pl = n0 % HW;
    int h  = pl / WW, w0 = pl % WW;

    for (int i = tid; i < 816; i += 256){
        int dh = i / 272, rem2 = i % 272;
        int c16 = rem2 / 34, x = rem2 % 34;
        int hh = h + dh - 1, wx = w0 + x - 1;
        uint4 val = make_uint4(0,0,0,0);
        if (hh >= 0 && hh < HH && wx >= 0 && wx < WW)
            val = *(const uint4*)(X2 + ((size_t)b*HW + (size_t)hh*WW + wx)*64 + c16*8);
        *(uint4*)&sB[((dh*8 + c16)*34 + x)*8] = val;
    }
    __syncthreads();

    {
        int mw = wv & 1, nw = wv >> 1;
        const ushort* Ap = A2 + (size_t)(mw*16 + lm)*576 + lk*8;
        f32x4 acc = {0.f,0.f,0.f,0.f};
        int xb = nw*16 + lm;
        #pragma unroll
        for (int t=0; t<9; ++t){
            int dh = t/3, dw = t%3;
            #pragma unroll
            for (int c0=0; c0<64; c0+=32){
                bf16x8 bb = *(const bf16x8*)&sB[((dh*8 + (c0>>3)+lk)*34 + xb + dw)*8];
                bf16x8 a  = *(const bf16x8*)(Ap + t*64 + c0);
                acc = __builtin_amdgcn_mfma_f32_16x16x32_bf16(a, bb, acc, 0,0,0);
            }
        }
        int pg = n0 + nw*16 + lm;
        int pll = pg % HW;
        int o = mw*16 + lk*4;
        f32x4 cv = *(const f32x4*)(C1 + (size_t)pg*DD + o);
        f32x4 outv;
        #pragma unroll
        for (int j=0;j<4;++j){
            outv[j] = (cv[j] + acc[j] + p2b[o+j]) * 0.5f;
            cost_out[((size_t)(b*DD + o + j))*HW + pll] = outv[j];
        }
        *(f32x4*)&sO[(nw*16 + lm)*36 + o] = outv;
    }
    __syncthreads();

    {
        int px = tid >> 3;
        int g  = tid & 7;
        f32x4 v = *(const f32x4*)&sO[px*36 + g*4];
        float m = fmaxf(fmaxf(v[0],v[1]), fmaxf(v[2],v[3]));
        m = fmaxf(m, __shfl_xor(m, 1));
        m = fmaxf(m, __shfl_xor(m, 2));
        m = fmaxf(m, __shfl_xor(m, 4));
        float e[4]; float s = 0.f;
        #pragma unroll
        for (int j=0;j<4;++j){ e[j] = __expf(v[j]-m); s += e[j]; }
        s += __shfl_xor(s, 1);
        s += __shfl_xor(s, 2);
        s += __shfl_xor(s, 4);
        float invs = 1.f/s;
        uint u0 = (uint)f2b(e[0]*invs) | ((uint)f2b(e[1]*invs)<<16);
        uint u1 = (uint)f2b(e[2]*invs) | ((uint)f2b(e[3]*invs)<<16);
        *(uint2*)&sN[px*40 + g*4] = make_uint2(u0, u1);
    }
    for (int i = tid; i < 1024; i += 256){
        int px = i & 31, c8 = i >> 5;
        const float* pt = t_feat + ((size_t)(b*CC + c8*8))*HW + pl + px;
        uint u[4];
        #pragma unroll
        for (int j2=0;j2<4;++j2)
            u[j2] = (uint)f2b(pt[(size_t)(2*j2)*HW]) | ((uint)f2b(pt[(size_t)(2*j2+1)*HW])<<16);
        uint4 q4; q4.x=u[0]; q4.y=u[1]; q4.z=u[2]; q4.w=u[3];
        *(uint4*)&sT[(px*33 + c8)*8] = q4;
    }
    __syncthreads();

    {
        f32x4 acc[4][2];
        #pragma unroll
        for (int mi=0;mi<4;++mi){ acc[mi][0]=(f32x4){0.f,0.f,0.f,0.f}; acc[mi][1]=(f32x4){0.f,0.f,0.f,0.f}; }
        const ushort* Ap = Ar + (size_t)(wv*64 + lm)*288 + lk*8;

        #pragma unroll
        for (int k0=0; k0<288; k0+=32){
            bf16x8 a[4];
            #pragma unroll
            for (int mi=0;mi<4;++mi) a[mi] = *(const bf16x8*)(Ap + (size_t)mi*16*288 + k0);
            #pragma unroll
            for (int nt=0; nt<2; ++nt){
                int prow = nt*16 + lm;
                bf16x8 bb = (k0 < 256) ? *(const bf16x8*)&sT[(prow*33 + (k0>>3) + lk)*8]
                                       : *(const bf16x8*)&sN[(prow*5 + lk)*8];
                #pragma unroll
                for (int mi=0;mi<4;++mi)
                    acc[mi][nt] = __builtin_amdgcn_mfma_f32_16x16x32_bf16(a[mi], bb, acc[mi][nt], 0,0,0);
            }
        }
        #pragma unroll
        for (int mi=0;mi<4;++mi){
            int o = wv*64 + mi*16 + lk*4;
            #pragma unroll
            for (int nt=0; nt<2; ++nt){
                int p = n0 + nt*16 + lm;
                int bb2 = p / HW, pl2 = p % HW;
                #pragma unroll
                for (int j=0;j<4;++j)
                    xout[((size_t)(bb2*CC + o + j))*HW + pl2] = eluf(acc[mi][nt][j] + rb[o+j]);
            }
        }
    }
}

extern "C" void kernel_launch(void* const* d_in, const int* in_sizes, int n_in,
                              void* d_out, int out_size, void* d_ws, size_t ws_size,
                              hipStream_t stream)
{
    const float* t_feat = (const float*)d_in[0];
    const float* s_feat = (const float*)d_in[1];
    const float* directs= (const float*)d_in[2];
    const float* qw = (const float*)d_in[3];
    const float* qb = (const float*)d_in[4];
    const float* kw = (const float*)d_in[5];
    const float* kb = (const float*)d_in[6];
    const float* vw = (const float*)d_in[7];
    const float* vb = (const float*)d_in[8];
    const float* p1w= (const float*)d_in[9];
    const float* p1b= (const float*)d_in[10];
    const float* p2w= (const float*)d_in[11];
    const float* p2b= (const float*)d_in[12];
    const float* rw = (const float*)d_in[13];
    const float* rb = (const float*)d_in[14];
    const int* img_w= (const int*)d_in[15];

    char* wsb = (char*)d_ws;
    char*  tsreg = wsb + 12582912;
    ushort* X2   = (ushort*)tsreg;
    float*  C1   = (float*)(tsreg + 3145728);
    ushort* Agg  = (ushort*)(tsreg + 6291456);
    ushort* X1   = (ushort*)(wsb + 25165824);    // [NPIX][128] bf16 (q | K)
    ushort* VbT  = (ushort*)(wsb + 31457280);    // [64][NPIX] bf16 (V transposed)
    ushort* Wqkv = (ushort*)(wsb + 34603008);
    float*  bqkv = (float*) (wsb + 34701312);
    ushort* A1   = (ushort*)(wsb + 34702336);
    ushort* A2   = (ushort*)(wsb + 34849792);
    ushort* Ar   = (ushort*)(wsb + 34886656);    // -> end 35,034,112
    if (ws_size < 35034112) return;

    float* xout     = (float*)d_out;                 // [B,256,H,W] f32
    float* cost_out = xout + (size_t)BB*CC*HW;       // [B,32,H,W] f32

    k_prep_w    <<<841,  256, 0, stream>>>(qw,qb,kw,kb,vw,vb,p1w,p2w,rw,
                                           Wqkv,bqkv,A1,A2,Ar);
    g_qkv       <<<768,  256, 0, stream>>>(t_feat, s_feat, Wqkv, bqkv, X1, VbT);
    k_ca        <<<1536, 256, 0, stream>>>(X1, VbT, directs, img_w, C1, Agg);
    g_conv1     <<<768,  256, 0, stream>>>(X1, Agg, A1, p1b, X2);
    g_conv2final<<<768,  256, 0, stream>>>(X2, A2, p2b, C1, t_feat, Ar, rb,
                                           cost_out, xout);
}